// Round 2
// baseline (5919.678 us; speedup 1.0000x reference)
//
#include <hip/hip_runtime.h>
#include <math.h>

#define SZ    100
#define FILT  51
#define DIM   256
#define MED   512
#define NBLK  8
#define BSZ   64
#define NPOS  80000     // 8*100*100 rows

// ---------------- table init: Tc[m]=cos(2pi m/100), Ts[m]=sin(2pi m/100) ----------------
__global__ void init_tables(float* __restrict__ Tc, float* __restrict__ Ts) {
    const int i = threadIdx.x;
    if (i < SZ) {
        const double th = (2.0 * 3.14159265358979323846 / (double)SZ) * (double)i;
        Tc[i] = (float)cos(th);
        Ts[i] = (float)sin(th);
    }
}

// ---------------- LayerNorm over last dim = 256, one block per row ----------------
__global__ __launch_bounds__(256) void ln_kernel(const float* __restrict__ x,
        const float* __restrict__ g, const float* __restrict__ b, float* __restrict__ y)
{
    const int row = blockIdx.x;
    const int t = threadIdx.x;
    const size_t base = (size_t)row * DIM + t;
    const float v = x[base];
    __shared__ float red[256];
    red[t] = v; __syncthreads();
    for (int s = 128; s > 0; s >>= 1) { if (t < s) red[t] += red[t + s]; __syncthreads(); }
    const float mu = red[0] * (1.0f / DIM);
    __syncthreads();
    const float d = v - mu;
    red[t] = d * d; __syncthreads();
    for (int s = 128; s > 0; s >>= 1) { if (t < s) red[t] += red[t + s]; __syncthreads(); }
    const float var = red[0] * (1.0f / DIM);
    y[base] = d * rsqrtf(var + 1e-5f) * g[t] + b[t];
}

// ---------------- generic fp32 tiled GEMM, row-major C[M,N] = A[M,K] @ B[K,N] ----------------
// EPI: 0 none, 1 star_relu (s*relu^2+b scalars), 2 add residual R (may alias C)
template<int EPI>
__global__ __launch_bounds__(256) void gemm64(
        const float* __restrict__ A, const float* __restrict__ Bm, float* __restrict__ C,
        const float* __restrict__ R, const float* __restrict__ sp, const float* __restrict__ bp,
        int M, int N, int K)
{
    __shared__ float As[16][65];
    __shared__ float Bs[16][68];
    const int t = threadIdx.x;
    const int n0 = blockIdx.x * 64;
    const int m0 = blockIdx.y * 64;
    const int tx = t & 15, ty = t >> 4;
    const int arow = t >> 2, acol = (t & 3) * 4;
    const int brow = t >> 4, bcol = (t & 15) * 4;
    float acc[4][4] = {};
    for (int k0 = 0; k0 < K; k0 += 16) {
        const float4 av = *(const float4*)(A + (size_t)(m0 + arow) * K + k0 + acol);
        const float4 bv = *(const float4*)(Bm + (size_t)(k0 + brow) * N + n0 + bcol);
        As[acol + 0][arow] = av.x;
        As[acol + 1][arow] = av.y;
        As[acol + 2][arow] = av.z;
        As[acol + 3][arow] = av.w;
        *(float4*)(&Bs[brow][bcol]) = bv;
        __syncthreads();
        #pragma unroll
        for (int kk = 0; kk < 16; ++kk) {
            const float a0 = As[kk][ty * 4 + 0];
            const float a1 = As[kk][ty * 4 + 1];
            const float a2 = As[kk][ty * 4 + 2];
            const float a3 = As[kk][ty * 4 + 3];
            const float4 bq = *(const float4*)(&Bs[kk][tx * 4]);
            acc[0][0] += a0 * bq.x; acc[0][1] += a0 * bq.y; acc[0][2] += a0 * bq.z; acc[0][3] += a0 * bq.w;
            acc[1][0] += a1 * bq.x; acc[1][1] += a1 * bq.y; acc[1][2] += a1 * bq.z; acc[1][3] += a1 * bq.w;
            acc[2][0] += a2 * bq.x; acc[2][1] += a2 * bq.y; acc[2][2] += a2 * bq.z; acc[2][3] += a2 * bq.w;
            acc[3][0] += a3 * bq.x; acc[3][1] += a3 * bq.y; acc[3][2] += a3 * bq.z; acc[3][3] += a3 * bq.w;
        }
        __syncthreads();
    }
    float s = 0.f, bb = 0.f;
    if (EPI == 1) { s = sp[0]; bb = bp[0]; }
    #pragma unroll
    for (int i = 0; i < 4; ++i) {
        const size_t off = (size_t)(m0 + ty * 4 + i) * N + n0 + tx * 4;
        float4 v;
        v.x = acc[i][0]; v.y = acc[i][1]; v.z = acc[i][2]; v.w = acc[i][3];
        if (EPI == 1) {
            float r0 = fmaxf(v.x, 0.f), r1 = fmaxf(v.y, 0.f), r2 = fmaxf(v.z, 0.f), r3 = fmaxf(v.w, 0.f);
            v.x = s * r0 * r0 + bb; v.y = s * r1 * r1 + bb; v.z = s * r2 * r2 + bb; v.w = s * r3 * r3 + bb;
        } else if (EPI == 2) {
            const float4 rv = *(const float4*)(R + off);
            v.x += rv.x; v.y += rv.y; v.z += rv.z; v.w += rv.w;
        }
        *(float4*)(C + off) = v;
    }
}

// ---------------- stage B: rfft along W.  fw[z,f,c] = 0.01 * sum_w h[z,w,c] e^{-2pi i f w/100} ----------------
// chunked over batch: pointers are chunk-relative, z = blockIdx.y in [0, CB*100)
__global__ __launch_bounds__(256) void dftw_kernel(const float* __restrict__ hin,
        float* __restrict__ fwr, float* __restrict__ fwi,
        const float* __restrict__ Tcg, const float* __restrict__ Tsg)
{
    __shared__ float hs[SZ][64];
    __shared__ float tc[SZ], ts[SZ];
    const int z = blockIdx.y;      // (b_local*100 + hrow)
    const int ct = blockIdx.x;     // channel tile (8 x 64)
    const int t = threadIdx.x;
    const int c = t & 63, fg = t >> 6;
    if (t < SZ) { tc[t] = Tcg[t]; ts[t] = Tsg[t]; }
    const size_t base = (size_t)z * (SZ * MED) + ct * 64 + c;
    for (int w = fg; w < SZ; w += 4) hs[w][c] = hin[base + (size_t)w * MED];
    __syncthreads();
    const int nj = (fg < 3) ? 13 : 12;   // f = fg + 4j <= 50
    float accR[13] = {}, accI[13] = {};
    int m[13];
    #pragma unroll
    for (int j = 0; j < 13; ++j) m[j] = 0;
    for (int w = 0; w < SZ; ++w) {
        const float hv = hs[w][c];
        #pragma unroll
        for (int j = 0; j < 13; ++j) {
            if (j < nj) {
                accR[j] += hv * tc[m[j]];
                accI[j] += hv * ts[m[j]];
                m[j] += fg + 4 * j;
                if (m[j] >= SZ) m[j] -= SZ;
            }
        }
    }
    const size_t ob = (size_t)z * (FILT * MED) + ct * 64 + c;
    for (int j = 0; j < nj; ++j) {
        const int f = fg + 4 * j;
        fwr[ob + (size_t)f * MED] =  0.01f * accR[j];
        fwi[ob + (size_t)f * MED] = -0.01f * accI[j];
    }
}

// ---------------- stage C/E: full FFT along H (INV=0: e^{-i}, INV=1: e^{+i}) ----------------
// layout in/out: [b_local, h_or_k (100), f (51), c (512)], z = b_local*51+f
template<int INV>
__global__ __launch_bounds__(256) void ffth_kernel(
        const float* __restrict__ inR, const float* __restrict__ inI,
        float* __restrict__ outR, float* __restrict__ outI,
        const float* __restrict__ Tcg, const float* __restrict__ Tsg)
{
    __shared__ float lr[SZ][64], li[SZ][64];
    __shared__ float tc[SZ], ts[SZ];
    const int z = blockIdx.y;      // b_local*51 + f
    const int ct = blockIdx.x;
    const int t = threadIdx.x;
    const int c = t & 63, kg = t >> 6;
    const int b = z / FILT, f = z % FILT;
    if (t < SZ) { tc[t] = Tcg[t]; ts[t] = Tsg[t]; }
    const size_t base = ((size_t)(b * SZ) * FILT + f) * MED + ct * 64 + c;
    for (int h = kg; h < SZ; h += 4) {
        lr[h][c] = inR[base + (size_t)h * (FILT * MED)];
        li[h][c] = inI[base + (size_t)h * (FILT * MED)];
    }
    __syncthreads();
    float accR[25] = {}, accI[25] = {};
    int m[25];
    #pragma unroll
    for (int j = 0; j < 25; ++j) m[j] = 0;
    for (int h = 0; h < SZ; ++h) {
        const float rv = lr[h][c], iv = li[h][c];
        #pragma unroll
        for (int j = 0; j < 25; ++j) {
            const float cv = tc[m[j]], sv = ts[m[j]];
            if (INV) { accR[j] += rv * cv - iv * sv; accI[j] += iv * cv + rv * sv; }
            else     { accR[j] += rv * cv + iv * sv; accI[j] += iv * cv - rv * sv; }
            m[j] += kg + 4 * j;
            if (m[j] >= SZ) m[j] -= SZ;
        }
    }
    #pragma unroll
    for (int j = 0; j < 25; ++j) {
        const int k = kg + 4 * j;
        const size_t ob = ((size_t)(b * SZ + k) * FILT + f) * MED + ct * 64 + c;
        outR[ob] = accR[j];
        outI[ob] = accI[j];
    }
}

// ---------------- stage F: irfft along W + skip (in-place into hbuf chunk) ----------------
__global__ __launch_bounds__(256) void irfftw_kernel(
        const float* __restrict__ Hr, const float* __restrict__ Hi,
        float* __restrict__ hbuf,
        const float* __restrict__ Tcg, const float* __restrict__ Tsg)
{
    __shared__ float lr[FILT][64], li[FILT][64];
    __shared__ float tc[SZ], ts[SZ];
    const int z = blockIdx.y;      // b_local*100 + hrow
    const int ct = blockIdx.x;
    const int t = threadIdx.x;
    const int c = t & 63, wg = t >> 6;
    if (t < SZ) { tc[t] = Tcg[t]; ts[t] = Tsg[t]; }
    const size_t fbase = (size_t)z * (FILT * MED) + ct * 64 + c;
    for (int f = wg; f < FILT; f += 4) {
        const float wgt = (f == 0 || f == FILT - 1) ? 0.01f : 0.02f;
        lr[f][c] = Hr[fbase + (size_t)f * MED] * wgt;
        li[f][c] = Hi[fbase + (size_t)f * MED] * wgt;
    }
    __syncthreads();
    float acc[25] = {};
    int m[25];
    #pragma unroll
    for (int j = 0; j < 25; ++j) m[j] = 0;
    for (int f = 0; f < FILT; ++f) {
        const float rv = lr[f][c], iv = li[f][c];
        #pragma unroll
        for (int j = 0; j < 25; ++j) {
            acc[j] += rv * tc[m[j]] - iv * ts[m[j]];
            m[j] += wg + 4 * j;
            if (m[j] >= SZ) m[j] -= SZ;
        }
    }
    const size_t ob = (size_t)z * (SZ * MED) + ct * 64 + c;
    #pragma unroll
    for (int j = 0; j < 25; ++j) {
        const int w = wg + 4 * j;
        const size_t a = ob + (size_t)w * MED;
        hbuf[a] = acc[j] + hbuf[a];
    }
}

// ---------------- stage D: block-diagonal complex MLP layer (row-guarded) ----------------
template<int SECOND>
__global__ __launch_bounds__(256) void bmm_kernel(
        const float* __restrict__ inR, const float* __restrict__ inI,
        const float* __restrict__ Wa, const float* __restrict__ Wb,
        const float* __restrict__ bias,
        const float* __restrict__ sRp, const float* __restrict__ bRp,
        const float* __restrict__ sIp, const float* __restrict__ bIp,
        const float* __restrict__ mulR, const float* __restrict__ mulI,
        float* __restrict__ outR, float* __restrict__ outI, int nrows)
{
    __shared__ float wS[2][BSZ * BSZ];
    __shared__ float frS[16][BSZ], fiS[16][BSZ];
    const int n = blockIdx.y;
    const int r0 = blockIdx.x * 16;
    const int t = threadIdx.x;
    const int o = t & 63, rg = t >> 6;
    for (int idx = t; idx < 16 * BSZ; idx += 256) {
        const int rr = idx >> 6, cc = idx & 63;
        const bool ok = (r0 + rr) < nrows;
        frS[rr][cc] = ok ? inR[(size_t)(r0 + rr) * MED + n * BSZ + cc] : 0.f;
        fiS[rr][cc] = ok ? inI[(size_t)(r0 + rr) * MED + n * BSZ + cc] : 0.f;
    }
    float accR[4], accI[4];
    const float b0 = bias[n * BSZ + o];
    const float b1 = bias[NBLK * BSZ + n * BSZ + o];
    #pragma unroll
    for (int q = 0; q < 4; ++q) { accR[q] = b0; accI[q] = b1; }
    for (int idx = t; idx < BSZ * BSZ; idx += 256) {
        wS[0][idx] = Wa[(size_t)n * (BSZ * BSZ) + idx];
        wS[1][idx] = Wb[(size_t)n * (BSZ * BSZ) + idx];
    }
    __syncthreads();
    for (int i = 0; i < BSZ; ++i) {
        const float wa = wS[0][i * BSZ + o], wb = wS[1][i * BSZ + o];
        #pragma unroll
        for (int q = 0; q < 4; ++q) {
            const int r = rg * 4 + q;
            accR[q] += frS[r][i] * wa;
            accI[q] += fiS[r][i] * wb;
        }
    }
    __syncthreads();
    for (int idx = t; idx < BSZ * BSZ; idx += 256) {
        wS[0][idx] = Wa[(size_t)(NBLK * BSZ * BSZ) + (size_t)n * (BSZ * BSZ) + idx];
        wS[1][idx] = Wb[(size_t)(NBLK * BSZ * BSZ) + (size_t)n * (BSZ * BSZ) + idx];
    }
    __syncthreads();
    for (int i = 0; i < BSZ; ++i) {
        const float wa = wS[0][i * BSZ + o], wb = wS[1][i * BSZ + o];
        #pragma unroll
        for (int q = 0; q < 4; ++q) {
            const int r = rg * 4 + q;
            accR[q] += fiS[r][i] * wa;   // second matrix multiplies the swapped operand
            accI[q] += frS[r][i] * wb;
        }
    }
    #pragma unroll
    for (int q = 0; q < 4; ++q) {
        const int r = r0 + rg * 4 + q;
        if (r >= nrows) continue;
        const size_t a = (size_t)r * MED + n * BSZ + o;
        if (!SECOND) {
            const float sR = sRp[0], bR = bRp[0], sI = sIp[0], bI = bIp[0];
            const float xr = fmaxf(accR[q], 0.f);
            const float xi = fmaxf(accI[q], 0.f);
            outR[a] = sR * xr * xr + bR;
            outI[a] = sI * xi * xi + bI;
        } else {
            outR[a] = accR[q] * mulR[a];
            outI[a] = accI[q] * mulI[a];
        }
    }
}

// ---------------- launcher ----------------
extern "C" void kernel_launch(void* const* d_in, const int* in_sizes, int n_in,
                              void* d_out, int out_size, void* d_ws, size_t ws_size,
                              hipStream_t stream) {
    (void)in_sizes; (void)n_in; (void)out_size;
    const float* x        = (const float*)d_in[0];
    const float* ln1_g    = (const float*)d_in[1];
    const float* ln1_b    = (const float*)d_in[2];
    const float* pw1_w    = (const float*)d_in[3];
    const float* act1_s   = (const float*)d_in[4];
    const float* act1_b   = (const float*)d_in[5];
    const float* w1       = (const float*)d_in[6];
    const float* w11      = (const float*)d_in[7];
    const float* b1       = (const float*)d_in[8];
    const float* w2       = (const float*)d_in[9];
    const float* w22      = (const float*)d_in[10];
    const float* b2       = (const float*)d_in[11];
    const float* actr_s   = (const float*)d_in[12];
    const float* actr_b   = (const float*)d_in[13];
    const float* acti_s   = (const float*)d_in[14];
    const float* acti_b   = (const float*)d_in[15];
    const float* pw2_w    = (const float*)d_in[16];
    const float* ln2_g    = (const float*)d_in[17];
    const float* ln2_b    = (const float*)d_in[18];
    const float* fc1_w    = (const float*)d_in[19];
    const float* mlp_s    = (const float*)d_in[20];
    const float* mlp_b    = (const float*)d_in[21];
    const float* fc2_w    = (const float*)d_in[22];
    float* out = (float*)d_out;
    float* ws  = (float*)d_ws;

    // ---- adaptive workspace layout (floats) ----
    const size_t HBUF_F   = 40960000ull;            // [80000,512]
    const size_t PERB_F   = 2611200ull;             // [100,51,512] one batch, one buffer
    const size_t ws_floats = ws_size / 4;
    int CB = 4;                                     // batches per chunk (capped at 4)
    while (CB > 1 && HBUF_F + 4ull * (size_t)CB * PERB_F + 512ull > ws_floats) CB >>= 1;

    float* hbuf = ws;
    const size_t chunkf = (size_t)CB * PERB_F;
    float* tAr = ws + HBUF_F;
    float* tAi = tAr + chunkf;
    float* tBr = tAi + chunkf;
    float* tBi = tBr + chunkf;
    float* Tc  = tBi + chunkf;
    float* Ts  = Tc + 128;
    float* ybuf = out;                              // stage-1 LN output (out is scratch here)

    init_tables<<<1, 128, 0, stream>>>(Tc, Ts);

    // token-mixer branch
    ln_kernel<<<NPOS, 256, 0, stream>>>(x, ln1_g, ln1_b, ybuf);
    gemm64<1><<<dim3(MED / 64, NPOS / 64), 256, 0, stream>>>(ybuf, pw1_w, hbuf,
            nullptr, act1_s, act1_b, NPOS, MED, DIM);

    for (int b0 = 0; b0 < 8; b0 += CB) {
        float* hchunk = hbuf + (size_t)b0 * (SZ * SZ * MED);
        const int nzh = CB * SZ;          // (b_local, hrow) batches
        const int nzf = CB * FILT;        // (b_local, f) batches
        const int nrows = CB * SZ * FILT; // rows for bmm
        dftw_kernel<<<dim3(8, nzh), 256, 0, stream>>>(hchunk, tAr, tAi, Tc, Ts);
        ffth_kernel<0><<<dim3(8, nzf), 256, 0, stream>>>(tAr, tAi, tBr, tBi, Tc, Ts);
        bmm_kernel<0><<<dim3((nrows + 15) / 16, NBLK), 256, 0, stream>>>(tBr, tBi, w1, w11, b1,
                actr_s, actr_b, acti_s, acti_b, nullptr, nullptr, tAr, tAi, nrows);
        bmm_kernel<1><<<dim3((nrows + 15) / 16, NBLK), 256, 0, stream>>>(tAr, tAi, w2, w22, b2,
                nullptr, nullptr, nullptr, nullptr, tBr, tBi, tBr, tBi, nrows);
        ffth_kernel<1><<<dim3(8, nzf), 256, 0, stream>>>(tBr, tBi, tAr, tAi, Tc, Ts);
        irfftw_kernel<<<dim3(8, nzh), 256, 0, stream>>>(tAr, tAi, hchunk, Tc, Ts);
    }

    gemm64<2><<<dim3(DIM / 64, NPOS / 64), 256, 0, stream>>>(hbuf, pw2_w, out,
            x, nullptr, nullptr, NPOS, DIM, MED);

    // MLP branch: y2 -> hbuf (dead), hidden chunk -> freq-temp region (>= 8000*1024 floats)
    float* y2 = hbuf;
    float* m1 = tAr;
    ln_kernel<<<NPOS, 256, 0, stream>>>(out, ln2_g, ln2_b, y2);
    for (int ch = 0; ch < 10; ++ch) {
        const float* yc = y2 + (size_t)ch * 8000 * DIM;
        float* oc = out + (size_t)ch * 8000 * DIM;
        gemm64<1><<<dim3(1024 / 64, 8000 / 64), 256, 0, stream>>>(yc, fc1_w, m1,
                nullptr, mlp_s, mlp_b, 8000, 1024, DIM);
        gemm64<2><<<dim3(DIM / 64, 8000 / 64), 256, 0, stream>>>(m1, fc2_w, oc,
                oc, nullptr, nullptr, 8000, DIM, 1024);
    }
}

// Round 3
// 4002.382 us; speedup vs baseline: 1.4790x; 1.4790x over previous
//
#include <hip/hip_runtime.h>
#include <math.h>

#define SZ    100
#define FILT  51
#define DIM   256
#define MED   512
#define NBLK  8
#define BSZ   64
#define NPOS  80000     // 8*100*100 rows

typedef __attribute__((ext_vector_type(8))) short short8v;   // 8 bf16 (4 VGPRs)
typedef __attribute__((ext_vector_type(4))) float f32x4;     // MFMA acc

__device__ __forceinline__ ushort f2b(float f) {
    union { float f; unsigned u; } x; x.f = f;
    unsigned r = (x.u + 0x7fffu + ((x.u >> 16) & 1u)) >> 16;
    return (ushort)r;
}

// ---------------- table init ----------------
__global__ void init_tables(float* __restrict__ Tc, float* __restrict__ Ts) {
    const int i = threadIdx.x;
    if (i < SZ) {
        const double th = (2.0 * 3.14159265358979323846 / (double)SZ) * (double)i;
        Tc[i] = (float)cos(th);
        Ts[i] = (float)sin(th);
    }
}

// ---------------- weight transpose + cast: Wt[n][k] = W[k][n] ----------------
__global__ void wtrans(const float* __restrict__ W, ushort* __restrict__ Wt, int K, int N) {
    const int idx = blockIdx.x * 256 + threadIdx.x;
    if (idx < N * K) {
        const int n = idx / K, k = idx % K;
        Wt[idx] = f2b(W[(size_t)k * N + n]);
    }
}

// ---------------- LayerNorm over last dim = 256 -> bf16 output ----------------
__global__ __launch_bounds__(256) void ln_kernel(const float* __restrict__ x,
        const float* __restrict__ g, const float* __restrict__ b, ushort* __restrict__ y)
{
    const int row = blockIdx.x;
    const int t = threadIdx.x;
    const size_t base = (size_t)row * DIM + t;
    const float v = x[base];
    __shared__ float red[256];
    red[t] = v; __syncthreads();
    for (int s = 128; s > 0; s >>= 1) { if (t < s) red[t] += red[t + s]; __syncthreads(); }
    const float mu = red[0] * (1.0f / DIM);
    __syncthreads();
    const float d = v - mu;
    red[t] = d * d; __syncthreads();
    for (int s = 128; s > 0; s >>= 1) { if (t < s) red[t] += red[t + s]; __syncthreads(); }
    const float var = red[0] * (1.0f / DIM);
    y[base] = f2b(d * rsqrtf(var + 1e-5f) * g[t] + b[t]);
}

// ---------------- bf16 MFMA GEMM: C[M,N] = A[M,K] @ Bt[N,K]^T ----------------
// EPI: 1 star_relu -> fp32 C, 2 +R -> fp32 C, 3 star_relu -> bf16 C
// ABF16: 1 A is bf16[M][K], 0 A is fp32[M][K] (converted during staging)
template<int EPI, int ABF16>
__global__ __launch_bounds__(256) void gemm_mfma(
        const void* __restrict__ Av, const ushort* __restrict__ Bt,
        float* __restrict__ Cf, ushort* __restrict__ Cb,
        const float* __restrict__ R, const float* __restrict__ sp, const float* __restrict__ bp,
        int M, int N, int K)
{
    __shared__ ushort As[128][72];   // pad to 72: 144B row stride, 16B aligned, 2-way banks
    __shared__ ushort Bs[128][72];
    const int t = threadIdx.x;
    // bijective XCD swizzle (m204): contiguous wg chunk per XCD -> A-row L2 reuse
    const int nwg = gridDim.x;
    const int orig = blockIdx.x;
    const int q = nwg >> 3, rr8 = nwg & 7;
    const int xcd = orig & 7, lo = orig >> 3;
    const int wg = (xcd < rr8 ? xcd * (q + 1) : rr8 * (q + 1) + (xcd - rr8) * q) + lo;
    const int NX = N >> 7;
    const int by = wg / NX, bx = wg % NX;
    const int m0 = by * 128, n0 = bx * 128;

    const ushort* A16 = (const ushort*)Av;
    const float*  A32 = (const float*)Av;

    const int lane = t & 63;
    const int wid = t >> 6;
    const int wr = (wid >> 1) * 64, wc = (wid & 1) * 64;
    const int fr = lane & 15, fg = lane >> 4;       // fragment row/col + k-group

    f32x4 acc[4][4];
    #pragma unroll
    for (int i = 0; i < 4; ++i)
        #pragma unroll
        for (int j = 0; j < 4; ++j) acc[i][j] = (f32x4){0.f, 0.f, 0.f, 0.f};

    for (int k0 = 0; k0 < K; k0 += 64) {
        // ---- stage A,B tiles: 1024 16B-segments each, 4 per thread ----
        #pragma unroll
        for (int i = 0; i < 4; ++i) {
            const int seg = t + 256 * i;
            const int row = seg >> 3, off = (seg & 7) * 8;
            if (ABF16) {
                const short8v av = *(const short8v*)(A16 + (size_t)(m0 + row) * K + k0 + off);
                *(short8v*)&As[row][off] = av;
            } else {
                const float* src = A32 + (size_t)(m0 + row) * K + k0 + off;
                const float4 f0 = *(const float4*)(src);
                const float4 f1 = *(const float4*)(src + 4);
                short8v v;
                v[0] = (short)f2b(f0.x); v[1] = (short)f2b(f0.y);
                v[2] = (short)f2b(f0.z); v[3] = (short)f2b(f0.w);
                v[4] = (short)f2b(f1.x); v[5] = (short)f2b(f1.y);
                v[6] = (short)f2b(f1.z); v[7] = (short)f2b(f1.w);
                *(short8v*)&As[row][off] = v;
            }
            const short8v bv = *(const short8v*)(Bt + (size_t)(n0 + row) * K + k0 + off);
            *(short8v*)&Bs[row][off] = bv;
        }
        __syncthreads();
        // ---- MFMA: 2 k-halves of 32 ----
        #pragma unroll
        for (int ks = 0; ks < 2; ++ks) {
            const int koff = ks * 32 + fg * 8;
            short8v a[4], b[4];
            #pragma unroll
            for (int mi = 0; mi < 4; ++mi)
                a[mi] = *(const short8v*)&As[wr + mi * 16 + fr][koff];
            #pragma unroll
            for (int ni = 0; ni < 4; ++ni)
                b[ni] = *(const short8v*)&Bs[wc + ni * 16 + fr][koff];
            #pragma unroll
            for (int mi = 0; mi < 4; ++mi)
                #pragma unroll
                for (int ni = 0; ni < 4; ++ni)
                    acc[mi][ni] = __builtin_amdgcn_mfma_f32_16x16x32_bf16(
                            a[mi], b[ni], acc[mi][ni], 0, 0, 0);
        }
        __syncthreads();
    }

    // ---- epilogue: C[(fg*4+r)][fr] per 16x16 fragment ----
    float s = 0.f, bb = 0.f;
    if (EPI == 1 || EPI == 3) { s = sp[0]; bb = bp[0]; }
    #pragma unroll
    for (int mi = 0; mi < 4; ++mi) {
        #pragma unroll
        for (int r = 0; r < 4; ++r) {
            const int row = m0 + wr + mi * 16 + fg * 4 + r;
            #pragma unroll
            for (int ni = 0; ni < 4; ++ni) {
                const int col = n0 + wc + ni * 16 + fr;
                float v = acc[mi][ni][r];
                const size_t off = (size_t)row * N + col;
                if (EPI == 1) {
                    const float rl = fmaxf(v, 0.f);
                    Cf[off] = s * rl * rl + bb;
                } else if (EPI == 2) {
                    Cf[off] = v + R[off];
                } else {
                    const float rl = fmaxf(v, 0.f);
                    Cb[off] = f2b(s * rl * rl + bb);
                }
            }
        }
    }
}

// ---------------- stage B: rfft along W ----------------
__global__ __launch_bounds__(256) void dftw_kernel(const float* __restrict__ hin,
        float* __restrict__ fwr, float* __restrict__ fwi,
        const float* __restrict__ Tcg, const float* __restrict__ Tsg)
{
    __shared__ float hs[SZ][64];
    __shared__ float tc[SZ], ts[SZ];
    const int z = blockIdx.y;
    const int ct = blockIdx.x;
    const int t = threadIdx.x;
    const int c = t & 63, fg = t >> 6;
    if (t < SZ) { tc[t] = Tcg[t]; ts[t] = Tsg[t]; }
    const size_t base = (size_t)z * (SZ * MED) + ct * 64 + c;
    for (int w = fg; w < SZ; w += 4) hs[w][c] = hin[base + (size_t)w * MED];
    __syncthreads();
    const int nj = (fg < 3) ? 13 : 12;
    float accR[13] = {}, accI[13] = {};
    int m[13];
    #pragma unroll
    for (int j = 0; j < 13; ++j) m[j] = 0;
    for (int w = 0; w < SZ; ++w) {
        const float hv = hs[w][c];
        #pragma unroll
        for (int j = 0; j < 13; ++j) {
            if (j < nj) {
                accR[j] += hv * tc[m[j]];
                accI[j] += hv * ts[m[j]];
                m[j] += fg + 4 * j;
                if (m[j] >= SZ) m[j] -= SZ;
            }
        }
    }
    const size_t ob = (size_t)z * (FILT * MED) + ct * 64 + c;
    for (int j = 0; j < nj; ++j) {
        const int f = fg + 4 * j;
        fwr[ob + (size_t)f * MED] =  0.01f * accR[j];
        fwi[ob + (size_t)f * MED] = -0.01f * accI[j];
    }
}

// ---------------- stage C/E: full FFT along H ----------------
template<int INV>
__global__ __launch_bounds__(256) void ffth_kernel(
        const float* __restrict__ inR, const float* __restrict__ inI,
        float* __restrict__ outR, float* __restrict__ outI,
        const float* __restrict__ Tcg, const float* __restrict__ Tsg)
{
    __shared__ float lr[SZ][64], li[SZ][64];
    __shared__ float tc[SZ], ts[SZ];
    const int z = blockIdx.y;
    const int ct = blockIdx.x;
    const int t = threadIdx.x;
    const int c = t & 63, kg = t >> 6;
    const int b = z / FILT, f = z % FILT;
    if (t < SZ) { tc[t] = Tcg[t]; ts[t] = Tsg[t]; }
    const size_t base = ((size_t)(b * SZ) * FILT + f) * MED + ct * 64 + c;
    for (int h = kg; h < SZ; h += 4) {
        lr[h][c] = inR[base + (size_t)h * (FILT * MED)];
        li[h][c] = inI[base + (size_t)h * (FILT * MED)];
    }
    __syncthreads();
    float accR[25] = {}, accI[25] = {};
    int m[25];
    #pragma unroll
    for (int j = 0; j < 25; ++j) m[j] = 0;
    for (int h = 0; h < SZ; ++h) {
        const float rv = lr[h][c], iv = li[h][c];
        #pragma unroll
        for (int j = 0; j < 25; ++j) {
            const float cv = tc[m[j]], sv = ts[m[j]];
            if (INV) { accR[j] += rv * cv - iv * sv; accI[j] += iv * cv + rv * sv; }
            else     { accR[j] += rv * cv + iv * sv; accI[j] += iv * cv - rv * sv; }
            m[j] += kg + 4 * j;
            if (m[j] >= SZ) m[j] -= SZ;
        }
    }
    #pragma unroll
    for (int j = 0; j < 25; ++j) {
        const int k = kg + 4 * j;
        const size_t ob = ((size_t)(b * SZ + k) * FILT + f) * MED + ct * 64 + c;
        outR[ob] = accR[j];
        outI[ob] = accI[j];
    }
}

// ---------------- stage F: irfft along W + skip (in-place into hbuf chunk) ----------------
__global__ __launch_bounds__(256) void irfftw_kernel(
        const float* __restrict__ Hr, const float* __restrict__ Hi,
        float* __restrict__ hbuf,
        const float* __restrict__ Tcg, const float* __restrict__ Tsg)
{
    __shared__ float lr[FILT][64], li[FILT][64];
    __shared__ float tc[SZ], ts[SZ];
    const int z = blockIdx.y;
    const int ct = blockIdx.x;
    const int t = threadIdx.x;
    const int c = t & 63, wg = t >> 6;
    if (t < SZ) { tc[t] = Tcg[t]; ts[t] = Tsg[t]; }
    const size_t fbase = (size_t)z * (FILT * MED) + ct * 64 + c;
    for (int f = wg; f < FILT; f += 4) {
        const float wgt = (f == 0 || f == FILT - 1) ? 0.01f : 0.02f;
        lr[f][c] = Hr[fbase + (size_t)f * MED] * wgt;
        li[f][c] = Hi[fbase + (size_t)f * MED] * wgt;
    }
    __syncthreads();
    float acc[25] = {};
    int m[25];
    #pragma unroll
    for (int j = 0; j < 25; ++j) m[j] = 0;
    for (int f = 0; f < FILT; ++f) {
        const float rv = lr[f][c], iv = li[f][c];
        #pragma unroll
        for (int j = 0; j < 25; ++j) {
            acc[j] += rv * tc[m[j]] - iv * ts[m[j]];
            m[j] += wg + 4 * j;
            if (m[j] >= SZ) m[j] -= SZ;
        }
    }
    const size_t ob = (size_t)z * (SZ * MED) + ct * 64 + c;
    #pragma unroll
    for (int j = 0; j < 25; ++j) {
        const int w = wg + 4 * j;
        const size_t a = ob + (size_t)w * MED;
        hbuf[a] = acc[j] + hbuf[a];
    }
}

// ---------------- stage D: block-diagonal complex MLP layer ----------------
template<int SECOND>
__global__ __launch_bounds__(256) void bmm_kernel(
        const float* __restrict__ inR, const float* __restrict__ inI,
        const float* __restrict__ Wa, const float* __restrict__ Wb,
        const float* __restrict__ bias,
        const float* __restrict__ sRp, const float* __restrict__ bRp,
        const float* __restrict__ sIp, const float* __restrict__ bIp,
        const float* __restrict__ mulR, const float* __restrict__ mulI,
        float* __restrict__ outR, float* __restrict__ outI, int nrows)
{
    __shared__ float wS[2][BSZ * BSZ];
    __shared__ float frS[16][BSZ], fiS[16][BSZ];
    const int n = blockIdx.y;
    const int r0 = blockIdx.x * 16;
    const int t = threadIdx.x;
    const int o = t & 63, rg = t >> 6;
    for (int idx = t; idx < 16 * BSZ; idx += 256) {
        const int rr = idx >> 6, cc = idx & 63;
        const bool ok = (r0 + rr) < nrows;
        frS[rr][cc] = ok ? inR[(size_t)(r0 + rr) * MED + n * BSZ + cc] : 0.f;
        fiS[rr][cc] = ok ? inI[(size_t)(r0 + rr) * MED + n * BSZ + cc] : 0.f;
    }
    float accR[4], accI[4];
    const float b0 = bias[n * BSZ + o];
    const float b1 = bias[NBLK * BSZ + n * BSZ + o];
    #pragma unroll
    for (int q = 0; q < 4; ++q) { accR[q] = b0; accI[q] = b1; }
    for (int idx = t; idx < BSZ * BSZ; idx += 256) {
        wS[0][idx] = Wa[(size_t)n * (BSZ * BSZ) + idx];
        wS[1][idx] = Wb[(size_t)n * (BSZ * BSZ) + idx];
    }
    __syncthreads();
    for (int i = 0; i < BSZ; ++i) {
        const float wa = wS[0][i * BSZ + o], wb = wS[1][i * BSZ + o];
        #pragma unroll
        for (int q = 0; q < 4; ++q) {
            const int r = rg * 4 + q;
            accR[q] += frS[r][i] * wa;
            accI[q] += fiS[r][i] * wb;
        }
    }
    __syncthreads();
    for (int idx = t; idx < BSZ * BSZ; idx += 256) {
        wS[0][idx] = Wa[(size_t)(NBLK * BSZ * BSZ) + (size_t)n * (BSZ * BSZ) + idx];
        wS[1][idx] = Wb[(size_t)(NBLK * BSZ * BSZ) + (size_t)n * (BSZ * BSZ) + idx];
    }
    __syncthreads();
    for (int i = 0; i < BSZ; ++i) {
        const float wa = wS[0][i * BSZ + o], wb = wS[1][i * BSZ + o];
        #pragma unroll
        for (int q = 0; q < 4; ++q) {
            const int r = rg * 4 + q;
            accR[q] += fiS[r][i] * wa;
            accI[q] += frS[r][i] * wb;
        }
    }
    #pragma unroll
    for (int q = 0; q < 4; ++q) {
        const int r = r0 + rg * 4 + q;
        if (r >= nrows) continue;
        const size_t a = (size_t)r * MED + n * BSZ + o;
        if (!SECOND) {
            const float sR = sRp[0], bR = bRp[0], sI = sIp[0], bI = bIp[0];
            const float xr = fmaxf(accR[q], 0.f);
            const float xi = fmaxf(accI[q], 0.f);
            outR[a] = sR * xr * xr + bR;
            outI[a] = sI * xi * xi + bI;
        } else {
            outR[a] = accR[q] * mulR[a];
            outI[a] = accI[q] * mulI[a];
        }
    }
}

// ---------------- launcher ----------------
extern "C" void kernel_launch(void* const* d_in, const int* in_sizes, int n_in,
                              void* d_out, int out_size, void* d_ws, size_t ws_size,
                              hipStream_t stream) {
    (void)in_sizes; (void)n_in; (void)out_size;
    const float* x        = (const float*)d_in[0];
    const float* ln1_g    = (const float*)d_in[1];
    const float* ln1_b    = (const float*)d_in[2];
    const float* pw1_w    = (const float*)d_in[3];
    const float* act1_s   = (const float*)d_in[4];
    const float* act1_b   = (const float*)d_in[5];
    const float* w1       = (const float*)d_in[6];
    const float* w11      = (const float*)d_in[7];
    const float* b1       = (const float*)d_in[8];
    const float* w2       = (const float*)d_in[9];
    const float* w22      = (const float*)d_in[10];
    const float* b2       = (const float*)d_in[11];
    const float* actr_s   = (const float*)d_in[12];
    const float* actr_b   = (const float*)d_in[13];
    const float* acti_s   = (const float*)d_in[14];
    const float* acti_b   = (const float*)d_in[15];
    const float* pw2_w    = (const float*)d_in[16];
    const float* ln2_g    = (const float*)d_in[17];
    const float* ln2_b    = (const float*)d_in[18];
    const float* fc1_w    = (const float*)d_in[19];
    const float* mlp_s    = (const float*)d_in[20];
    const float* mlp_b    = (const float*)d_in[21];
    const float* fc2_w    = (const float*)d_in[22];
    float* out = (float*)d_out;
    float* ws  = (float*)d_ws;

    // ---- adaptive workspace layout (floats) ----
    const size_t HBUF_F = 40960000ull;            // [80000,512] fp32
    const size_t PERB_F = 2611200ull;             // [100,51,512] one batch, one buffer
    const size_t WT_F   = 393216ull;              // 786,432 bf16 weights
    const size_t ws_floats = ws_size / 4;
    int CB = 4;
    while (CB > 1 && HBUF_F + 4ull * (size_t)CB * PERB_F + WT_F + 512ull > ws_floats) CB >>= 1;

    float* hbuf = ws;
    const size_t chunkf = (size_t)CB * PERB_F;
    float* tAr = ws + HBUF_F;
    float* tAi = tAr + chunkf;
    float* tBr = tAi + chunkf;
    float* tBi = tBr + chunkf;
    ushort* wt1  = (ushort*)(tBi + chunkf);       // [512][256]
    ushort* wt2  = wt1 + 131072;                  // [256][512]
    ushort* wtf1 = wt2 + 131072;                  // [1024][256]
    ushort* wtf2 = wtf1 + 262144;                 // [256][1024]
    float* Tc = (float*)(wtf2 + 262144);
    float* Ts = Tc + 128;

    ushort* y16 = (ushort*)out;                   // LN1 out (out is scratch until pw2)
    ushort* y2  = (ushort*)hbuf;                  // LN2 out (hbuf dead after pw2)
    ushort* m1h = (ushort*)tAr;                   // MLP hidden chunk bf16 (freq temps dead)

    init_tables<<<1, 128, 0, stream>>>(Tc, Ts);
    wtrans<<<(131072 + 255) / 256, 256, 0, stream>>>(pw1_w, wt1, DIM, MED);
    wtrans<<<(131072 + 255) / 256, 256, 0, stream>>>(pw2_w, wt2, MED, DIM);
    wtrans<<<(262144 + 255) / 256, 256, 0, stream>>>(fc1_w, wtf1, DIM, 1024);
    wtrans<<<(262144 + 255) / 256, 256, 0, stream>>>(fc2_w, wtf2, 1024, DIM);

    // token-mixer branch
    ln_kernel<<<NPOS, 256, 0, stream>>>(x, ln1_g, ln1_b, y16);
    gemm_mfma<1, 1><<<(NPOS / 128) * (MED / 128), 256, 0, stream>>>(
            y16, wt1, hbuf, nullptr, nullptr, act1_s, act1_b, NPOS, MED, DIM);

    for (int b0 = 0; b0 < 8; b0 += CB) {
        float* hchunk = hbuf + (size_t)b0 * (SZ * SZ * MED);
        const int nzh = CB * SZ;
        const int nzf = CB * FILT;
        const int nrows = CB * SZ * FILT;
        dftw_kernel<<<dim3(8, nzh), 256, 0, stream>>>(hchunk, tAr, tAi, Tc, Ts);
        ffth_kernel<0><<<dim3(8, nzf), 256, 0, stream>>>(tAr, tAi, tBr, tBi, Tc, Ts);
        bmm_kernel<0><<<dim3((nrows + 15) / 16, NBLK), 256, 0, stream>>>(tBr, tBi, w1, w11, b1,
                actr_s, actr_b, acti_s, acti_b, nullptr, nullptr, tAr, tAi, nrows);
        bmm_kernel<1><<<dim3((nrows + 15) / 16, NBLK), 256, 0, stream>>>(tAr, tAi, w2, w22, b2,
                nullptr, nullptr, nullptr, nullptr, tBr, tBi, tBr, tBi, nrows);
        ffth_kernel<1><<<dim3(8, nzf), 256, 0, stream>>>(tBr, tBi, tAr, tAi, Tc, Ts);
        irfftw_kernel<<<dim3(8, nzh), 256, 0, stream>>>(tAr, tAi, hchunk, Tc, Ts);
    }

    gemm_mfma<2, 0><<<(NPOS / 128) * (DIM / 128), 256, 0, stream>>>(
            hbuf, wt2, out, nullptr, x, nullptr, nullptr, NPOS, DIM, MED);

    // MLP branch
    ln_kernel<<<NPOS, 256, 0, stream>>>(out, ln2_g, ln2_b, y2);
    for (int ch = 0; ch < 5; ++ch) {
        const ushort* yc = y2 + (size_t)ch * 16000 * DIM;
        float* oc = out + (size_t)ch * 16000 * DIM;
        gemm_mfma<3, 1><<<(16000 / 128) * (1024 / 128), 256, 0, stream>>>(
                yc, wtf1, nullptr, m1h, nullptr, mlp_s, mlp_b, 16000, 1024, DIM);
        gemm_mfma<2, 1><<<(16000 / 128) * (DIM / 128), 256, 0, stream>>>(
                m1h, wtf2, oc, nullptr, oc, nullptr, nullptr, 16000, DIM, 1024);
    }
}

// Round 4
// 1190.609 us; speedup vs baseline: 4.9720x; 3.3616x over previous
//
#include <hip/hip_runtime.h>
#include <math.h>

#define SZ    100
#define FILT  51
#define DIM   256
#define MED   512
#define NPOS  80000

#define PERB2 5222400ll          // 2*100*51*512 floats per batch (stacked R/I)
#define PL    2611200ll          // plane stride (100*51*512)
#define HROW  26112              // 51*512

typedef __attribute__((ext_vector_type(8))) short short8v;
typedef __attribute__((ext_vector_type(4))) float f32x4;

__device__ __forceinline__ ushort f2b(float f) {
    union { float f; unsigned u; } x; x.f = f;
    unsigned r = (x.u + 0x7fffu + ((x.u >> 16) & 1u)) >> 16;
    return (ushort)r;
}

#define DPI 3.14159265358979323846

// ================= builders =================
__global__ void build_A1(ushort* __restrict__ A) {          // [128][128]
    const int id = blockIdx.x * 256 + threadIdx.x;
    const int rho = id >> 7, w = id & 127;
    float v = 0.f;
    if (w < SZ) {
        if (rho < FILT)          { int m = (rho * w) % SZ;          v =  0.01f * (float)cos(2.0 * DPI * m / SZ); }
        else if (rho < 2 * FILT) { int m = ((rho - FILT) * w) % SZ; v = -0.01f * (float)sin(2.0 * DPI * m / SZ); }
    }
    A[id] = f2b(v);
}

template<int INV>
__global__ void build_A2(ushort* __restrict__ A) {          // [256][256]
    const int id = blockIdx.x * 256 + threadIdx.x;
    const int rho = id >> 8, kk = id & 255;
    float v = 0.f;
    const double sgn = INV ? -1.0 : 1.0;
    if (rho < SZ) {
        if (kk < SZ)           { int m = (rho * kk) % SZ;        v = (float)cos(2.0 * DPI * m / SZ); }
        else if (kk < 2 * SZ)  { int m = (rho * (kk - SZ)) % SZ; v = (float)(sgn * sin(2.0 * DPI * m / SZ)); }
    } else if (rho < 2 * SZ) {
        const int i = rho - SZ;
        if (kk < SZ)           { int m = (i * kk) % SZ;          v = (float)(-sgn * sin(2.0 * DPI * m / SZ)); }
        else if (kk < 2 * SZ)  { int m = (i * (kk - SZ)) % SZ;   v = (float)cos(2.0 * DPI * m / SZ); }
    }
    A[id] = f2b(v);
}

__global__ void build_A5(ushort* __restrict__ A) {          // [128][128]
    const int id = blockIdx.x * 256 + threadIdx.x;
    const int w = id >> 7, kk = id & 127;
    float v = 0.f;
    if (w < SZ) {
        if (kk < FILT) {
            const float wgt = (kk == 0 || kk == FILT - 1) ? 0.01f : 0.02f;
            int m = (w * kk) % SZ; v = wgt * (float)cos(2.0 * DPI * m / SZ);
        } else if (kk < 2 * FILT) {
            const int f = kk - FILT;
            const float wgt = (f == 0 || f == FILT - 1) ? 0.01f : 0.02f;
            int m = (w * f) % SZ; v = -wgt * (float)sin(2.0 * DPI * m / SZ);
        }
    }
    A[id] = f2b(v);
}

// combined block weights, out-major: Wc[n][j(out 0..127)][i(in 0..127)]
__global__ void build_wc(const float* __restrict__ wA, const float* __restrict__ wB,
                         ushort* __restrict__ Wc) {
    const int id = blockIdx.x * 256 + threadIdx.x;          // 131072
    const int n = id >> 14, j = (id >> 7) & 127, i = id & 127;
    float v;
    if (j < 64) v = (i < 64) ? wA[((0 * 8 + n) * 64 + i) * 64 + j]
                             : wA[((1 * 8 + n) * 64 + (i - 64)) * 64 + j];
    else {
        const int jp = j - 64;
        v = (i < 64) ? wB[((1 * 8 + n) * 64 + i) * 64 + jp]
                     : wB[((0 * 8 + n) * 64 + (i - 64)) * 64 + jp];
    }
    Wc[id] = f2b(v);
}

__global__ void wtrans(const float* __restrict__ W, ushort* __restrict__ Wt, int K, int N) {
    const int idx = blockIdx.x * 256 + threadIdx.x;
    if (idx < N * K) {
        const int n = idx / K, k = idx % K;
        Wt[idx] = f2b(W[(size_t)k * N + n]);
    }
}

// ================= LayerNorm (dim 256) -> bf16 =================
__global__ __launch_bounds__(256) void ln_kernel(const float* __restrict__ x,
        const float* __restrict__ g, const float* __restrict__ b, ushort* __restrict__ y)
{
    const int row = blockIdx.x;
    const int t = threadIdx.x;
    const size_t base = (size_t)row * DIM + t;
    const float v = x[base];
    __shared__ float red[256];
    red[t] = v; __syncthreads();
    for (int s = 128; s > 0; s >>= 1) { if (t < s) red[t] += red[t + s]; __syncthreads(); }
    const float mu = red[0] * (1.0f / DIM);
    __syncthreads();
    const float d = v - mu;
    red[t] = d * d; __syncthreads();
    for (int s = 128; s > 0; s >>= 1) { if (t < s) red[t] += red[t + s]; __syncthreads(); }
    const float var = red[0] * (1.0f / DIM);
    y[base] = f2b(d * rsqrtf(var + 1e-5f) * g[t] + b[t]);
}

// ================= dense bf16 MFMA GEMM (round-3 verified) =================
template<int EPI, int ABF16>
__global__ __launch_bounds__(256) void gemm_mfma(
        const void* __restrict__ Av, const ushort* __restrict__ Bt,
        float* __restrict__ Cf, ushort* __restrict__ Cb,
        const float* __restrict__ R, const float* __restrict__ sp, const float* __restrict__ bp,
        int M, int N, int K)
{
    __shared__ ushort As[128][72];
    __shared__ ushort Bs[128][72];
    const int t = threadIdx.x;
    const int nwg = gridDim.x;
    const int orig = blockIdx.x;
    const int q = nwg >> 3, rr8 = nwg & 7;
    const int xcd = orig & 7, lo = orig >> 3;
    const int wg = (xcd < rr8 ? xcd * (q + 1) : rr8 * (q + 1) + (xcd - rr8) * q) + lo;
    const int NX = N >> 7;
    const int by = wg / NX, bx = wg % NX;
    const int m0 = by * 128, n0 = bx * 128;

    const ushort* A16 = (const ushort*)Av;
    const float*  A32 = (const float*)Av;
    const int lane = t & 63;
    const int wid = t >> 6;
    const int wr = (wid >> 1) * 64, wc = (wid & 1) * 64;
    const int fr = lane & 15, fg = lane >> 4;

    f32x4 acc[4][4];
    #pragma unroll
    for (int i = 0; i < 4; ++i)
        #pragma unroll
        for (int j = 0; j < 4; ++j) acc[i][j] = (f32x4){0.f, 0.f, 0.f, 0.f};

    for (int k0 = 0; k0 < K; k0 += 64) {
        #pragma unroll
        for (int i = 0; i < 4; ++i) {
            const int seg = t + 256 * i;
            const int row = seg >> 3, off = (seg & 7) * 8;
            if (ABF16) {
                *(short8v*)&As[row][off] = *(const short8v*)(A16 + (size_t)(m0 + row) * K + k0 + off);
            } else {
                const float* src = A32 + (size_t)(m0 + row) * K + k0 + off;
                const float4 f0 = *(const float4*)(src);
                const float4 f1 = *(const float4*)(src + 4);
                short8v v;
                v[0] = (short)f2b(f0.x); v[1] = (short)f2b(f0.y);
                v[2] = (short)f2b(f0.z); v[3] = (short)f2b(f0.w);
                v[4] = (short)f2b(f1.x); v[5] = (short)f2b(f1.y);
                v[6] = (short)f2b(f1.z); v[7] = (short)f2b(f1.w);
                *(short8v*)&As[row][off] = v;
            }
            *(short8v*)&Bs[row][off] = *(const short8v*)(Bt + (size_t)(n0 + row) * K + k0 + off);
        }
        __syncthreads();
        #pragma unroll
        for (int ks = 0; ks < 2; ++ks) {
            const int koff = ks * 32 + fg * 8;
            short8v a[4], b[4];
            #pragma unroll
            for (int mi = 0; mi < 4; ++mi) a[mi] = *(const short8v*)&As[wr + mi * 16 + fr][koff];
            #pragma unroll
            for (int ni = 0; ni < 4; ++ni) b[ni] = *(const short8v*)&Bs[wc + ni * 16 + fr][koff];
            #pragma unroll
            for (int mi = 0; mi < 4; ++mi)
                #pragma unroll
                for (int ni = 0; ni < 4; ++ni)
                    acc[mi][ni] = __builtin_amdgcn_mfma_f32_16x16x32_bf16(
                            a[mi], b[ni], acc[mi][ni], 0, 0, 0);
        }
        __syncthreads();
    }
    float s = 0.f, bb = 0.f;
    if (EPI == 1 || EPI == 3) { s = sp[0]; bb = bp[0]; }
    #pragma unroll
    for (int mi = 0; mi < 4; ++mi) {
        #pragma unroll
        for (int r = 0; r < 4; ++r) {
            const int row = m0 + wr + mi * 16 + fg * 4 + r;
            #pragma unroll
            for (int ni = 0; ni < 4; ++ni) {
                const int col = n0 + wc + ni * 16 + fr;
                float v = acc[mi][ni][r];
                const size_t off = (size_t)row * N + col;
                if (EPI == 1) {
                    const float rl = fmaxf(v, 0.f);
                    Cf[off] = s * rl * rl + bb;
                } else if (EPI == 2) {
                    Cf[off] = v + R[off];
                } else {
                    const float rl = fmaxf(v, 0.f);
                    Cb[off] = f2b(s * rl * rl + bb);
                }
            }
        }
    }
}

// ================= small-A MFMA GEMM for DFT stages =================
// C[rho][n] = sum_k A[rho][k] * B[k][n], A bf16 prebuilt (shared), B fp32 (cvt on stage)
// B rows mapped via (Bsplit, BplOff); C rows via (Csplit, CplOff); EPI: 0 write, 1 +=
template<int EPI>
__global__ __launch_bounds__(256) void gemm_dft(
        const ushort* __restrict__ Ag, int Apitch,
        const float* __restrict__ Bb, int BzDiv, long BzA, long BzB, int Brs,
        int Bsplit, long BplOff, int Kreal, int Ksteps,
        float* __restrict__ Cb, int CzDiv, long CzA, long CzB, int Crs,
        int Csplit, long CplOff, int Climit, int ntiles, int mtiles)
{
    __shared__ ushort As[128][72];
    __shared__ ushort Bs[128][72];
    const int t = threadIdx.x;
    const int per_z = ntiles * mtiles;
    const int z = blockIdx.x / per_z;
    const int rem = blockIdx.x % per_z;
    const int mt = rem % mtiles;
    const int nt = rem / mtiles;
    const int col0 = nt * 128;
    const long Bzbase = (long)(z / BzDiv) * BzA + (long)(z % BzDiv) * BzB;
    const long Czbase = (long)(z / CzDiv) * CzA + (long)(z % CzDiv) * CzB;
    const int lane = t & 63, wid = t >> 6;
    const int wr = (wid >> 1) * 64, wc = (wid & 1) * 64;
    const int fr = lane & 15, fg = lane >> 4;

    f32x4 acc[4][4];
    #pragma unroll
    for (int i = 0; i < 4; ++i)
        #pragma unroll
        for (int j = 0; j < 4; ++j) acc[i][j] = (f32x4){0.f, 0.f, 0.f, 0.f};

    for (int step = 0; step < Ksteps; ++step) {
        const int k0 = step * 64;
        // stage A slice [128][64] (bf16, natural rows)
        #pragma unroll
        for (int i = 0; i < 4; ++i) {
            const int id = t + 256 * i;
            const int r = id >> 3, j = (id & 7) * 8;
            *(short8v*)&As[r][j] = *(const short8v*)(Ag + (size_t)(mt * 128 + r) * Apitch + k0 + j);
        }
        // stage B slice transposed into Bs[n][k], kblk XOR-swizzled by (n>>3)&7
        #pragma unroll
        for (int i = 0; i < 2; ++i) {
            const int kp = (t >> 4) + 16 * i;     // k-pair 0..31
            const int np = t & 15;                // n-chunk (8 cols)
            const int kg0 = k0 + 2 * kp;
            float v0[8] = {0,0,0,0,0,0,0,0}, v1[8] = {0,0,0,0,0,0,0,0};
            if (kg0 < Kreal) {
                const float* s0 = Bb + Bzbase
                        + (kg0 < Bsplit ? (long)kg0 * Brs : BplOff + (long)(kg0 - Bsplit) * Brs)
                        + col0 + np * 8;
                const float4 a0 = *(const float4*)s0;
                const float4 a1 = *(const float4*)(s0 + 4);
                v0[0]=a0.x; v0[1]=a0.y; v0[2]=a0.z; v0[3]=a0.w;
                v0[4]=a1.x; v0[5]=a1.y; v0[6]=a1.z; v0[7]=a1.w;
            }
            if (kg0 + 1 < Kreal) {
                const int kg1 = kg0 + 1;
                const float* s1 = Bb + Bzbase
                        + (kg1 < Bsplit ? (long)kg1 * Brs : BplOff + (long)(kg1 - Bsplit) * Brs)
                        + col0 + np * 8;
                const float4 a0 = *(const float4*)s1;
                const float4 a1 = *(const float4*)(s1 + 4);
                v1[0]=a0.x; v1[1]=a0.y; v1[2]=a0.z; v1[3]=a0.w;
                v1[4]=a1.x; v1[5]=a1.y; v1[6]=a1.z; v1[7]=a1.w;
            }
            const int blk = (kp >> 2) ^ (np & 7);
            #pragma unroll
            for (int jj = 0; jj < 8; ++jj) {
                const int n = np * 8 + jj;
                ushort2 pr; pr.x = f2b(v0[jj]); pr.y = f2b(v1[jj]);
                *(ushort2*)&Bs[n][blk * 8 + ((2 * kp) & 7)] = pr;
            }
        }
        __syncthreads();
        #pragma unroll
        for (int ks = 0; ks < 2; ++ks) {
            const int koff = ks * 32 + fg * 8;
            short8v a[4], b[4];
            #pragma unroll
            for (int mi = 0; mi < 4; ++mi) a[mi] = *(const short8v*)&As[wr + mi * 16 + fr][koff];
            #pragma unroll
            for (int ni = 0; ni < 4; ++ni) {
                const int n = wc + ni * 16 + fr;
                const int blk = (koff >> 3) ^ ((n >> 3) & 7);
                b[ni] = *(const short8v*)&Bs[n][blk * 8];
            }
            #pragma unroll
            for (int mi = 0; mi < 4; ++mi)
                #pragma unroll
                for (int ni = 0; ni < 4; ++ni)
                    acc[mi][ni] = __builtin_amdgcn_mfma_f32_16x16x32_bf16(
                            a[mi], b[ni], acc[mi][ni], 0, 0, 0);
        }
        __syncthreads();
    }
    // epilogue
    #pragma unroll
    for (int mi = 0; mi < 4; ++mi) {
        #pragma unroll
        for (int rq = 0; rq < 4; ++rq) {
            const int rho = mt * 128 + wr + mi * 16 + fg * 4 + rq;
            if (rho >= Climit) continue;
            const long rbase = Czbase
                    + (rho < Csplit ? (long)rho * Crs : CplOff + (long)(rho - Csplit) * Crs);
            #pragma unroll
            for (int ni = 0; ni < 4; ++ni) {
                const long caddr = rbase + col0 + wc + ni * 16 + fr;
                float v = acc[mi][ni][rq];
                if (EPI == 1) v += Cb[caddr];
                Cb[caddr] = v;
            }
        }
    }
}

// ================= block-diagonal complex MLP via MFMA =================
// SECOND=0: [o1r|o1i] = star_relu([fr|fi] @ Wc1 + b1) -> G1[b][n][r][128]
// SECOND=1: o2 = ([o1r|o1i] @ Wc2 + b2) * F2  -> F2 in place
template<int SECOND>
__global__ __launch_bounds__(256) void gemm_bmm(
        float* __restrict__ F2, float* __restrict__ G1,
        const ushort* __restrict__ Wc, const float* __restrict__ bias,
        const float* __restrict__ s0p, const float* __restrict__ b0p,
        const float* __restrict__ s1p, const float* __restrict__ b1p)
{
    const int MT = 40;
    const int wg = blockIdx.x;
    const int mt = wg % MT;
    const int n  = (wg / MT) & 7;
    const int bl = wg / (MT * 8);
    const long FB = (long)bl * PERB2;
    const long GB = ((long)(bl * 8 + n)) * 5100 * 128;
    const int r0 = mt * 128;
    __shared__ ushort As[128][72];
    __shared__ ushort Ws[128][72];
    const int t = threadIdx.x;
    const int lane = t & 63, wid = t >> 6;
    const int wr = (wid >> 1) * 64, wc = (wid & 1) * 64;
    const int fr = lane & 15, fg = lane >> 4;

    f32x4 acc[4][4];
    #pragma unroll
    for (int i = 0; i < 4; ++i)
        #pragma unroll
        for (int j = 0; j < 4; ++j) acc[i][j] = (f32x4){0.f, 0.f, 0.f, 0.f};

    for (int step = 0; step < 2; ++step) {
        #pragma unroll
        for (int i = 0; i < 4; ++i) {
            const int id = t + 256 * i;
            const int r = id >> 3, j = (id & 7) * 8;
            short8v v = {0,0,0,0,0,0,0,0};
            if (r0 + r < 5100) {
                const float* src = SECOND
                    ? (G1 + GB + (long)(r0 + r) * 128 + step * 64 + j)
                    : (F2 + FB + (step ? PL : 0) + (long)(r0 + r) * 512 + n * 64 + j);
                const float4 f0 = *(const float4*)src;
                const float4 f1 = *(const float4*)(src + 4);
                v[0] = (short)f2b(f0.x); v[1] = (short)f2b(f0.y);
                v[2] = (short)f2b(f0.z); v[3] = (short)f2b(f0.w);
                v[4] = (short)f2b(f1.x); v[5] = (short)f2b(f1.y);
                v[6] = (short)f2b(f1.z); v[7] = (short)f2b(f1.w);
            }
            *(short8v*)&As[r][j] = v;
        }
        #pragma unroll
        for (int i = 0; i < 4; ++i) {
            const int id = t + 256 * i;
            const int r = id >> 3, j = (id & 7) * 8;
            *(short8v*)&Ws[r][j] = *(const short8v*)(Wc + ((long)n << 14) + r * 128 + step * 64 + j);
        }
        __syncthreads();
        #pragma unroll
        for (int ks = 0; ks < 2; ++ks) {
            const int koff = ks * 32 + fg * 8;
            short8v a[4], b[4];
            #pragma unroll
            for (int mi = 0; mi < 4; ++mi) a[mi] = *(const short8v*)&As[wr + mi * 16 + fr][koff];
            #pragma unroll
            for (int ni = 0; ni < 4; ++ni) b[ni] = *(const short8v*)&Ws[wc + ni * 16 + fr][koff];
            #pragma unroll
            for (int mi = 0; mi < 4; ++mi)
                #pragma unroll
                for (int ni = 0; ni < 4; ++ni)
                    acc[mi][ni] = __builtin_amdgcn_mfma_f32_16x16x32_bf16(
                            a[mi], b[ni], acc[mi][ni], 0, 0, 0);
        }
        __syncthreads();
    }
    #pragma unroll
    for (int mi = 0; mi < 4; ++mi) {
        #pragma unroll
        for (int rq = 0; rq < 4; ++rq) {
            const int r = r0 + wr + mi * 16 + fg * 4 + rq;
            if (r >= 5100) continue;
            #pragma unroll
            for (int ni = 0; ni < 4; ++ni) {
                const int j = wc + ni * 16 + fr;
                float u = acc[mi][ni][rq] + bias[(j < 64 ? 0 : 512) + n * 64 + (j & 63)];
                if (!SECOND) {
                    const float s  = (j < 64) ? s0p[0] : s1p[0];
                    const float bb = (j < 64) ? b0p[0] : b1p[0];
                    const float rl = fmaxf(u, 0.f);
                    G1[GB + (long)r * 128 + j] = s * rl * rl + bb;
                } else {
                    const long ma = FB + (j < 64 ? 0 : PL) + (long)r * 512 + n * 64 + (j & 63);
                    F2[ma] = u * F2[ma];
                }
            }
        }
    }
}

// ================= launcher =================
extern "C" void kernel_launch(void* const* d_in, const int* in_sizes, int n_in,
                              void* d_out, int out_size, void* d_ws, size_t ws_size,
                              hipStream_t stream) {
    (void)in_sizes; (void)n_in; (void)out_size;
    const float* x        = (const float*)d_in[0];
    const float* ln1_g    = (const float*)d_in[1];
    const float* ln1_b    = (const float*)d_in[2];
    const float* pw1_w    = (const float*)d_in[3];
    const float* act1_s   = (const float*)d_in[4];
    const float* act1_b   = (const float*)d_in[5];
    const float* w1       = (const float*)d_in[6];
    const float* w11      = (const float*)d_in[7];
    const float* b1       = (const float*)d_in[8];
    const float* w2       = (const float*)d_in[9];
    const float* w22      = (const float*)d_in[10];
    const float* b2       = (const float*)d_in[11];
    const float* actr_s   = (const float*)d_in[12];
    const float* actr_b   = (const float*)d_in[13];
    const float* acti_s   = (const float*)d_in[14];
    const float* acti_b   = (const float*)d_in[15];
    const float* pw2_w    = (const float*)d_in[16];
    const float* ln2_g    = (const float*)d_in[17];
    const float* ln2_b    = (const float*)d_in[18];
    const float* fc1_w    = (const float*)d_in[19];
    const float* mlp_s    = (const float*)d_in[20];
    const float* mlp_b    = (const float*)d_in[21];
    const float* fc2_w    = (const float*)d_in[22];
    float* out = (float*)d_out;
    float* ws  = (float*)d_ws;

    const size_t HBUF_F = 40960000ull;
    const size_t MATS_F = 610000ull;          // bf16 matrices region (floats, padded)
    const size_t ws_floats = ws_size / 4;
    int CB = 4;
    while (CB > 1 && HBUF_F + 2ull * (size_t)CB * (size_t)PERB2 + MATS_F > ws_floats) CB >>= 1;

    float* hbuf = ws;
    float* tA = ws + HBUF_F;
    float* tB = tA + (size_t)CB * PERB2;
    ushort* mats = (ushort*)(tB + (size_t)CB * PERB2);
    ushort* A1m  = mats;                 // 16384
    ushort* A2m  = A1m + 16384;          // 65536
    ushort* A4m  = A2m + 65536;          // 65536
    ushort* A5m  = A4m + 65536;          // 16384
    ushort* Wc1  = A5m + 16384;          // 131072
    ushort* Wc2  = Wc1 + 131072;         // 131072
    ushort* wt1  = Wc2 + 131072;         // 131072
    ushort* wt2  = wt1 + 131072;         // 131072
    ushort* wtf1 = wt2 + 131072;         // 262144
    ushort* wtf2 = wtf1 + 262144;        // 262144

    ushort* y16 = (ushort*)out;                          // LN1 out (scratch until pw2)
    ushort* y2  = (ushort*)hbuf;                         // LN2 out (hbuf dead after pw2)
    ushort* m1h = (ushort*)(hbuf + 10240000ull);         // MLP hidden (after y2's 10.24M floats)

    build_A1<<<64, 256, 0, stream>>>(A1m);
    build_A2<0><<<256, 256, 0, stream>>>(A2m);
    build_A2<1><<<256, 256, 0, stream>>>(A4m);
    build_A5<<<64, 256, 0, stream>>>(A5m);
    build_wc<<<512, 256, 0, stream>>>(w1, w11, Wc1);
    build_wc<<<512, 256, 0, stream>>>(w2, w22, Wc2);
    wtrans<<<(131072 + 255) / 256, 256, 0, stream>>>(pw1_w, wt1, DIM, MED);
    wtrans<<<(131072 + 255) / 256, 256, 0, stream>>>(pw2_w, wt2, MED, DIM);
    wtrans<<<(262144 + 255) / 256, 256, 0, stream>>>(fc1_w, wtf1, DIM, 1024);
    wtrans<<<(262144 + 255) / 256, 256, 0, stream>>>(fc2_w, wtf2, 1024, DIM);

    // ---- token mixer ----
    ln_kernel<<<NPOS, 256, 0, stream>>>(x, ln1_g, ln1_b, y16);
    gemm_mfma<1, 1><<<(NPOS / 128) * (MED / 128), 256, 0, stream>>>(
            y16, wt1, hbuf, nullptr, nullptr, act1_s, act1_b, NPOS, MED, DIM);

    for (int b0 = 0; b0 < 8; b0 += CB) {
        float* hchunk = hbuf + (size_t)b0 * (SZ * SZ * MED);
        // K1: rfft along W  -> tA (F1)
        gemm_dft<0><<<CB * 100 * 4, 256, 0, stream>>>(
                A1m, 128, hchunk, 1, 51200, 0, 512, 100, 0, 100, 2,
                tA, 100, PERB2, HROW, 512, 51, PL, 102, 4, 1);
        // K2: forward DFT along H (stacked complex) tA -> tB (F2)
        gemm_dft<0><<<CB * 408, 256, 0, stream>>>(
                A2m, 256, tA, 1, PERB2, 0, HROW, 100, PL, 200, 4,
                tB, 1, PERB2, 0, HROW, 100, PL, 200, 204, 2);
        // bmm layer 1: F2 -> G1 (=tA)
        gemm_bmm<0><<<CB * 320, 256, 0, stream>>>(
                tB, tA, Wc1, b1, actr_s, actr_b, acti_s, acti_b);
        // bmm layer 2: G1, x F2 -> F2 in place
        gemm_bmm<1><<<CB * 320, 256, 0, stream>>>(
                tB, tA, Wc2, b2, nullptr, nullptr, nullptr, nullptr);
        // K4: inverse DFT along H: tB -> tA (F4)
        gemm_dft<0><<<CB * 408, 256, 0, stream>>>(
                A4m, 256, tB, 1, PERB2, 0, HROW, 100, PL, 200, 4,
                tA, 1, PERB2, 0, HROW, 100, PL, 200, 204, 2);
        // K5: irfft along W + skip: tA -> hchunk (+=)
        gemm_dft<1><<<CB * 100 * 4, 256, 0, stream>>>(
                A5m, 128, tA, 100, PERB2, HROW, 512, 51, PL, 102, 2,
                hchunk, 1, 51200, 0, 512, 100, 0, 100, 4, 1);
    }

    gemm_mfma<2, 0><<<(NPOS / 128) * (DIM / 128), 256, 0, stream>>>(
            hbuf, wt2, out, nullptr, x, nullptr, nullptr, NPOS, DIM, MED);

    // ---- MLP branch ----
    ln_kernel<<<NPOS, 256, 0, stream>>>(out, ln2_g, ln2_b, y2);
    for (int ch = 0; ch < 5; ++ch) {
        const ushort* yc = y2 + (size_t)ch * 16000 * DIM;
        float* oc = out + (size_t)ch * 16000 * DIM;
        gemm_mfma<3, 1><<<(16000 / 128) * (1024 / 128), 256, 0, stream>>>(
                yc, wtf1, nullptr, m1h, nullptr, mlp_s, mlp_b, 16000, 1024, DIM);
        gemm_mfma<2, 1><<<(16000 / 128) * (DIM / 128), 256, 0, stream>>>(
                m1h, wtf2, oc, nullptr, oc, nullptr, nullptr, 16000, DIM, 1024);
    }
}

// Round 5
// 1040.858 us; speedup vs baseline: 5.6873x; 1.1439x over previous
//
#include <hip/hip_runtime.h>
#include <math.h>

#define SZ    100
#define FILT  51
#define DIM   256
#define MED   512
#define NPOS  80000

#define PERB2 5222400ll          // 2*100*51*512 floats per batch (stacked R/I)
#define PL    2611200ll          // plane stride (100*51*512)
#define HROW  26112              // 51*512

typedef __attribute__((ext_vector_type(8))) short short8v;
typedef __attribute__((ext_vector_type(4))) float f32x4;

__device__ __forceinline__ ushort f2b(float f) {
    union { float f; unsigned u; } x; x.f = f;
    unsigned r = (x.u + 0x7fffu + ((x.u >> 16) & 1u)) >> 16;
    return (ushort)r;
}
__device__ __forceinline__ float b2f(ushort u) {
    union { float f; unsigned u; } x; x.u = ((unsigned)u) << 16;
    return x.f;
}

#define DPI 3.14159265358979323846

// ================= builders =================
__global__ void build_A1(ushort* __restrict__ A) {          // [128][128]
    const int id = blockIdx.x * 256 + threadIdx.x;
    const int rho = id >> 7, w = id & 127;
    float v = 0.f;
    if (w < SZ) {
        if (rho < FILT)          { int m = (rho * w) % SZ;          v =  0.01f * (float)cos(2.0 * DPI * m / SZ); }
        else if (rho < 2 * FILT) { int m = ((rho - FILT) * w) % SZ; v = -0.01f * (float)sin(2.0 * DPI * m / SZ); }
    }
    A[id] = f2b(v);
}

template<int INV>
__global__ void build_A2(ushort* __restrict__ A) {          // [256][256]
    const int id = blockIdx.x * 256 + threadIdx.x;
    const int rho = id >> 8, kk = id & 255;
    float v = 0.f;
    const double sgn = INV ? -1.0 : 1.0;
    if (rho < SZ) {
        if (kk < SZ)           { int m = (rho * kk) % SZ;        v = (float)cos(2.0 * DPI * m / SZ); }
        else if (kk < 2 * SZ)  { int m = (rho * (kk - SZ)) % SZ; v = (float)(sgn * sin(2.0 * DPI * m / SZ)); }
    } else if (rho < 2 * SZ) {
        const int i = rho - SZ;
        if (kk < SZ)           { int m = (i * kk) % SZ;          v = (float)(-sgn * sin(2.0 * DPI * m / SZ)); }
        else if (kk < 2 * SZ)  { int m = (i * (kk - SZ)) % SZ;   v = (float)cos(2.0 * DPI * m / SZ); }
    }
    A[id] = f2b(v);
}

__global__ void build_A5(ushort* __restrict__ A) {          // [128][128]
    const int id = blockIdx.x * 256 + threadIdx.x;
    const int w = id >> 7, kk = id & 127;
    float v = 0.f;
    if (w < SZ) {
        if (kk < FILT) {
            const float wgt = (kk == 0 || kk == FILT - 1) ? 0.01f : 0.02f;
            int m = (w * kk) % SZ; v = wgt * (float)cos(2.0 * DPI * m / SZ);
        } else if (kk < 2 * FILT) {
            const int f = kk - FILT;
            const float wgt = (f == 0 || f == FILT - 1) ? 0.01f : 0.02f;
            int m = (w * f) % SZ; v = -wgt * (float)sin(2.0 * DPI * m / SZ);
        }
    }
    A[id] = f2b(v);
}

// combined block weights, out-major: Wc[n][j(out 0..127)][i(in 0..127)]
__global__ void build_wc(const float* __restrict__ wA, const float* __restrict__ wB,
                         ushort* __restrict__ Wc) {
    const int id = blockIdx.x * 256 + threadIdx.x;          // 131072
    const int n = id >> 14, j = (id >> 7) & 127, i = id & 127;
    float v;
    if (j < 64) v = (i < 64) ? wA[((0 * 8 + n) * 64 + i) * 64 + j]
                             : wA[((1 * 8 + n) * 64 + (i - 64)) * 64 + j];
    else {
        const int jp = j - 64;
        v = (i < 64) ? wB[((1 * 8 + n) * 64 + i) * 64 + jp]
                     : wB[((0 * 8 + n) * 64 + (i - 64)) * 64 + jp];
    }
    Wc[id] = f2b(v);
}

__global__ void wtrans(const float* __restrict__ W, ushort* __restrict__ Wt, int K, int N) {
    const int idx = blockIdx.x * 256 + threadIdx.x;
    if (idx < N * K) {
        const int n = idx / K, k = idx % K;
        Wt[idx] = f2b(W[(size_t)k * N + n]);
    }
}

// ================= fast LayerNorm: one wave per 256-elem row =================
__global__ __launch_bounds__(256) void ln_fast(const float* __restrict__ x,
        const float* __restrict__ g, const float* __restrict__ b, ushort* __restrict__ y)
{
    const int row = blockIdx.x * 4 + (threadIdx.x >> 6);
    const int lane = threadIdx.x & 63;
    const float4 v = *(const float4*)(x + (size_t)row * DIM + lane * 4);
    float s  = v.x + v.y + v.z + v.w;
    float s2 = v.x * v.x + v.y * v.y + v.z * v.z + v.w * v.w;
    #pragma unroll
    for (int off = 32; off > 0; off >>= 1) {
        s  += __shfl_xor(s, off, 64);
        s2 += __shfl_xor(s2, off, 64);
    }
    const float mu  = s * (1.0f / DIM);
    const float var = s2 * (1.0f / DIM) - mu * mu;
    const float rs  = rsqrtf(var + 1e-5f);
    const float4 gv = *(const float4*)(g + lane * 4);
    const float4 bv = *(const float4*)(b + lane * 4);
    ushort4 o;
    o.x = f2b((v.x - mu) * rs * gv.x + bv.x);
    o.y = f2b((v.y - mu) * rs * gv.y + bv.y);
    o.z = f2b((v.z - mu) * rs * gv.z + bv.z);
    o.w = f2b((v.w - mu) * rs * gv.w + bv.w);
    *(ushort4*)(y + (size_t)row * DIM + lane * 4) = o;
}

// ================= dense bf16 MFMA GEMM =================
// EPI: 1 star_relu -> fp32, 2 +R -> fp32, 3 star_relu -> bf16
template<int EPI, int ABF16>
__global__ __launch_bounds__(256) void gemm_mfma(
        const void* __restrict__ Av, const ushort* __restrict__ Bt,
        float* __restrict__ Cf, ushort* __restrict__ Cb,
        const float* __restrict__ R, const float* __restrict__ sp, const float* __restrict__ bp,
        int M, int N, int K)
{
    __shared__ ushort As[128][72];
    __shared__ ushort Bs[128][72];
    const int t = threadIdx.x;
    const int nwg = gridDim.x;
    const int orig = blockIdx.x;
    const int q = nwg >> 3, rr8 = nwg & 7;
    const int xcd = orig & 7, lo = orig >> 3;
    const int wg = (xcd < rr8 ? xcd * (q + 1) : rr8 * (q + 1) + (xcd - rr8) * q) + lo;
    const int NX = N >> 7;
    const int by = wg / NX, bx = wg % NX;
    const int m0 = by * 128, n0 = bx * 128;

    const ushort* A16 = (const ushort*)Av;
    const float*  A32 = (const float*)Av;
    const int lane = t & 63;
    const int wid = t >> 6;
    const int wr = (wid >> 1) * 64, wc = (wid & 1) * 64;
    const int fr = lane & 15, fg = lane >> 4;

    f32x4 acc[4][4];
    #pragma unroll
    for (int i = 0; i < 4; ++i)
        #pragma unroll
        for (int j = 0; j < 4; ++j) acc[i][j] = (f32x4){0.f, 0.f, 0.f, 0.f};

    for (int k0 = 0; k0 < K; k0 += 64) {
        #pragma unroll
        for (int i = 0; i < 4; ++i) {
            const int seg = t + 256 * i;
            const int row = seg >> 3, off = (seg & 7) * 8;
            if (ABF16) {
                *(short8v*)&As[row][off] = *(const short8v*)(A16 + (size_t)(m0 + row) * K + k0 + off);
            } else {
                const float* src = A32 + (size_t)(m0 + row) * K + k0 + off;
                const float4 f0 = *(const float4*)(src);
                const float4 f1 = *(const float4*)(src + 4);
                short8v v;
                v[0] = (short)f2b(f0.x); v[1] = (short)f2b(f0.y);
                v[2] = (short)f2b(f0.z); v[3] = (short)f2b(f0.w);
                v[4] = (short)f2b(f1.x); v[5] = (short)f2b(f1.y);
                v[6] = (short)f2b(f1.z); v[7] = (short)f2b(f1.w);
                *(short8v*)&As[row][off] = v;
            }
            *(short8v*)&Bs[row][off] = *(const short8v*)(Bt + (size_t)(n0 + row) * K + k0 + off);
        }
        __syncthreads();
        #pragma unroll
        for (int ks = 0; ks < 2; ++ks) {
            const int koff = ks * 32 + fg * 8;
            short8v a[4], b[4];
            #pragma unroll
            for (int mi = 0; mi < 4; ++mi) a[mi] = *(const short8v*)&As[wr + mi * 16 + fr][koff];
            #pragma unroll
            for (int ni = 0; ni < 4; ++ni) b[ni] = *(const short8v*)&Bs[wc + ni * 16 + fr][koff];
            #pragma unroll
            for (int mi = 0; mi < 4; ++mi)
                #pragma unroll
                for (int ni = 0; ni < 4; ++ni)
                    acc[mi][ni] = __builtin_amdgcn_mfma_f32_16x16x32_bf16(
                            a[mi], b[ni], acc[mi][ni], 0, 0, 0);
        }
        __syncthreads();
    }
    float s = 0.f, bb = 0.f;
    if (EPI == 1 || EPI == 3) { s = sp[0]; bb = bp[0]; }
    #pragma unroll
    for (int mi = 0; mi < 4; ++mi) {
        #pragma unroll
        for (int r = 0; r < 4; ++r) {
            const int row = m0 + wr + mi * 16 + fg * 4 + r;
            #pragma unroll
            for (int ni = 0; ni < 4; ++ni) {
                const int col = n0 + wc + ni * 16 + fr;
                float v = acc[mi][ni][r];
                const size_t off = (size_t)row * N + col;
                if (EPI == 1) {
                    const float rl = fmaxf(v, 0.f);
                    Cf[off] = s * rl * rl + bb;
                } else if (EPI == 2) {
                    Cf[off] = v + R[off];
                } else {
                    const float rl = fmaxf(v, 0.f);
                    Cb[off] = f2b(s * rl * rl + bb);
                }
            }
        }
    }
}

// ================= small-A MFMA GEMM for DFT stages =================
// C[rho][n] = sum_k A[rho][k] * B[k][n]; A bf16 prebuilt; B fp32 or bf16 (BBF16);
// C fp32 or bf16 (CBF16); EPI: 0 write, 1 accumulate (C += result)
template<int EPI, int BBF16, int CBF16>
__global__ __launch_bounds__(256) void gemm_dft(
        const ushort* __restrict__ Ag, int Apitch,
        const void* __restrict__ Bv, int BzDiv, long BzA, long BzB, int Brs,
        int Bsplit, long BplOff, int Kreal, int Ksteps,
        void* __restrict__ Cv, int CzDiv, long CzA, long CzB, int Crs,
        int Csplit, long CplOff, int Climit, int ntiles, int mtiles)
{
    __shared__ ushort As[128][72];
    __shared__ ushort Bs[128][72];
    const int t = threadIdx.x;
    const int per_z = ntiles * mtiles;
    const int z = blockIdx.x / per_z;
    const int rem = blockIdx.x % per_z;
    const int mt = rem % mtiles;
    const int nt = rem / mtiles;
    const int col0 = nt * 128;
    const long Bzbase = (long)(z / BzDiv) * BzA + (long)(z % BzDiv) * BzB;
    const long Czbase = (long)(z / CzDiv) * CzA + (long)(z % CzDiv) * CzB;
    const int lane = t & 63, wid = t >> 6;
    const int wr = (wid >> 1) * 64, wc = (wid & 1) * 64;
    const int fr = lane & 15, fg = lane >> 4;
    const float* B32 = (const float*)Bv;
    const ushort* B16 = (const ushort*)Bv;

    f32x4 acc[4][4];
    #pragma unroll
    for (int i = 0; i < 4; ++i)
        #pragma unroll
        for (int j = 0; j < 4; ++j) acc[i][j] = (f32x4){0.f, 0.f, 0.f, 0.f};

    for (int step = 0; step < Ksteps; ++step) {
        const int k0 = step * 64;
        #pragma unroll
        for (int i = 0; i < 4; ++i) {
            const int id = t + 256 * i;
            const int r = id >> 3, j = (id & 7) * 8;
            *(short8v*)&As[r][j] = *(const short8v*)(Ag + (size_t)(mt * 128 + r) * Apitch + k0 + j);
        }
        // stage B slice transposed into Bs[n][k], kblk XOR-swizzled by (n>>3)&7
        #pragma unroll
        for (int i = 0; i < 2; ++i) {
            const int kp = (t >> 4) + 16 * i;     // k-pair 0..31
            const int np = t & 15;                // n-chunk (8 cols)
            const int kg0 = k0 + 2 * kp;
            ushort u0[8] = {0,0,0,0,0,0,0,0}, u1[8] = {0,0,0,0,0,0,0,0};
            if (kg0 < Kreal) {
                const long roff = Bzbase
                        + (kg0 < Bsplit ? (long)kg0 * Brs : BplOff + (long)(kg0 - Bsplit) * Brs)
                        + col0 + np * 8;
                if (BBF16) {
                    const short8v tv = *(const short8v*)(B16 + roff);
                    #pragma unroll
                    for (int jj = 0; jj < 8; ++jj) u0[jj] = (ushort)tv[jj];
                } else {
                    const float4 a0 = *(const float4*)(B32 + roff);
                    const float4 a1 = *(const float4*)(B32 + roff + 4);
                    u0[0]=f2b(a0.x); u0[1]=f2b(a0.y); u0[2]=f2b(a0.z); u0[3]=f2b(a0.w);
                    u0[4]=f2b(a1.x); u0[5]=f2b(a1.y); u0[6]=f2b(a1.z); u0[7]=f2b(a1.w);
                }
            }
            if (kg0 + 1 < Kreal) {
                const int kg1 = kg0 + 1;
                const long roff = Bzbase
                        + (kg1 < Bsplit ? (long)kg1 * Brs : BplOff + (long)(kg1 - Bsplit) * Brs)
                        + col0 + np * 8;
                if (BBF16) {
                    const short8v tv = *(const short8v*)(B16 + roff);
                    #pragma unroll
                    for (int jj = 0; jj < 8; ++jj) u1[jj] = (ushort)tv[jj];
                } else {
                    const float4 a0 = *(const float4*)(B32 + roff);
                    const float4 a1 = *(const float4*)(B32 + roff + 4);
                    u1[0]=f2b(a0.x); u1[1]=f2b(a0.y); u1[2]=f2b(a0.z); u1[3]=f2b(a0.w);
                    u1[4]=f2b(a1.x); u1[5]=f2b(a1.y); u1[6]=f2b(a1.z); u1[7]=f2b(a1.w);
                }
            }
            const int blk = (kp >> 2) ^ (np & 7);
            #pragma unroll
            for (int jj = 0; jj < 8; ++jj) {
                const int n = np * 8 + jj;
                ushort2 pr; pr.x = u0[jj]; pr.y = u1[jj];
                *(ushort2*)&Bs[n][blk * 8 + ((2 * kp) & 7)] = pr;
            }
        }
        __syncthreads();
        #pragma unroll
        for (int ks = 0; ks < 2; ++ks) {
            const int koff = ks * 32 + fg * 8;
            short8v a[4], b[4];
            #pragma unroll
            for (int mi = 0; mi < 4; ++mi) a[mi] = *(const short8v*)&As[wr + mi * 16 + fr][koff];
            #pragma unroll
            for (int ni = 0; ni < 4; ++ni) {
                const int n = wc + ni * 16 + fr;
                const int blk = (koff >> 3) ^ ((n >> 3) & 7);
                b[ni] = *(const short8v*)&Bs[n][blk * 8];
            }
            #pragma unroll
            for (int mi = 0; mi < 4; ++mi)
                #pragma unroll
                for (int ni = 0; ni < 4; ++ni)
                    acc[mi][ni] = __builtin_amdgcn_mfma_f32_16x16x32_bf16(
                            a[mi], b[ni], acc[mi][ni], 0, 0, 0);
        }
        __syncthreads();
    }
    // epilogue
    float* C32 = (float*)Cv;
    ushort* C16 = (ushort*)Cv;
    #pragma unroll
    for (int mi = 0; mi < 4; ++mi) {
        #pragma unroll
        for (int rq = 0; rq < 4; ++rq) {
            const int rho = mt * 128 + wr + mi * 16 + fg * 4 + rq;
            if (rho >= Climit) continue;
            const long rbase = Czbase
                    + (rho < Csplit ? (long)rho * Crs : CplOff + (long)(rho - Csplit) * Crs);
            #pragma unroll
            for (int ni = 0; ni < 4; ++ni) {
                const long caddr = rbase + col0 + wc + ni * 16 + fr;
                float v = acc[mi][ni][rq];
                if (CBF16) {
                    if (EPI == 1) v += b2f(C16[caddr]);
                    C16[caddr] = f2b(v);
                } else {
                    if (EPI == 1) v += C32[caddr];
                    C32[caddr] = v;
                }
            }
        }
    }
}

// ================= block-diagonal complex MLP via MFMA =================
template<int SECOND>
__global__ __launch_bounds__(256) void gemm_bmm(
        float* __restrict__ F2, float* __restrict__ G1,
        const ushort* __restrict__ Wc, const float* __restrict__ bias,
        const float* __restrict__ s0p, const float* __restrict__ b0p,
        const float* __restrict__ s1p, const float* __restrict__ b1p)
{
    const int MT = 40;
    const int wg = blockIdx.x;
    const int mt = wg % MT;
    const int n  = (wg / MT) & 7;
    const int bl = wg / (MT * 8);
    const long FB = (long)bl * PERB2;
    const long GB = ((long)(bl * 8 + n)) * 5100 * 128;
    const int r0 = mt * 128;
    __shared__ ushort As[128][72];
    __shared__ ushort Ws[128][72];
    const int t = threadIdx.x;
    const int lane = t & 63, wid = t >> 6;
    const int wr = (wid >> 1) * 64, wc = (wid & 1) * 64;
    const int fr = lane & 15, fg = lane >> 4;

    f32x4 acc[4][4];
    #pragma unroll
    for (int i = 0; i < 4; ++i)
        #pragma unroll
        for (int j = 0; j < 4; ++j) acc[i][j] = (f32x4){0.f, 0.f, 0.f, 0.f};

    for (int step = 0; step < 2; ++step) {
        #pragma unroll
        for (int i = 0; i < 4; ++i) {
            const int id = t + 256 * i;
            const int r = id >> 3, j = (id & 7) * 8;
            short8v v = {0,0,0,0,0,0,0,0};
            if (r0 + r < 5100) {
                const float* src = SECOND
                    ? (G1 + GB + (long)(r0 + r) * 128 + step * 64 + j)
                    : (F2 + FB + (step ? PL : 0) + (long)(r0 + r) * 512 + n * 64 + j);
                const float4 f0 = *(const float4*)src;
                const float4 f1 = *(const float4*)(src + 4);
                v[0] = (short)f2b(f0.x); v[1] = (short)f2b(f0.y);
                v[2] = (short)f2b(f0.z); v[3] = (short)f2b(f0.w);
                v[4] = (short)f2b(f1.x); v[5] = (short)f2b(f1.y);
                v[6] = (short)f2b(f1.z); v[7] = (short)f2b(f1.w);
            }
            *(short8v*)&As[r][j] = v;
        }
        #pragma unroll
        for (int i = 0; i < 4; ++i) {
            const int id = t + 256 * i;
            const int r = id >> 3, j = (id & 7) * 8;
            *(short8v*)&Ws[r][j] = *(const short8v*)(Wc + ((long)n << 14) + r * 128 + step * 64 + j);
        }
        __syncthreads();
        #pragma unroll
        for (int ks = 0; ks < 2; ++ks) {
            const int koff = ks * 32 + fg * 8;
            short8v a[4], b[4];
            #pragma unroll
            for (int mi = 0; mi < 4; ++mi) a[mi] = *(const short8v*)&As[wr + mi * 16 + fr][koff];
            #pragma unroll
            for (int ni = 0; ni < 4; ++ni) b[ni] = *(const short8v*)&Ws[wc + ni * 16 + fr][koff];
            #pragma unroll
            for (int mi = 0; mi < 4; ++mi)
                #pragma unroll
                for (int ni = 0; ni < 4; ++ni)
                    acc[mi][ni] = __builtin_amdgcn_mfma_f32_16x16x32_bf16(
                            a[mi], b[ni], acc[mi][ni], 0, 0, 0);
        }
        __syncthreads();
    }
    #pragma unroll
    for (int mi = 0; mi < 4; ++mi) {
        #pragma unroll
        for (int rq = 0; rq < 4; ++rq) {
            const int r = r0 + wr + mi * 16 + fg * 4 + rq;
            if (r >= 5100) continue;
            #pragma unroll
            for (int ni = 0; ni < 4; ++ni) {
                const int j = wc + ni * 16 + fr;
                float u = acc[mi][ni][rq] + bias[(j < 64 ? 0 : 512) + n * 64 + (j & 63)];
                if (!SECOND) {
                    const float s  = (j < 64) ? s0p[0] : s1p[0];
                    const float bb = (j < 64) ? b0p[0] : b1p[0];
                    const float rl = fmaxf(u, 0.f);
                    G1[GB + (long)r * 128 + j] = s * rl * rl + bb;
                } else {
                    const long ma = FB + (j < 64 ? 0 : PL) + (long)r * 512 + n * 64 + (j & 63);
                    F2[ma] = u * F2[ma];
                }
            }
        }
    }
}

// ================= launcher =================
extern "C" void kernel_launch(void* const* d_in, const int* in_sizes, int n_in,
                              void* d_out, int out_size, void* d_ws, size_t ws_size,
                              hipStream_t stream) {
    (void)in_sizes; (void)n_in; (void)out_size;
    const float* x        = (const float*)d_in[0];
    const float* ln1_g    = (const float*)d_in[1];
    const float* ln1_b    = (const float*)d_in[2];
    const float* pw1_w    = (const float*)d_in[3];
    const float* act1_s   = (const float*)d_in[4];
    const float* act1_b   = (const float*)d_in[5];
    const float* w1       = (const float*)d_in[6];
    const float* w11      = (const float*)d_in[7];
    const float* b1       = (const float*)d_in[8];
    const float* w2       = (const float*)d_in[9];
    const float* w22      = (const float*)d_in[10];
    const float* b2       = (const float*)d_in[11];
    const float* actr_s   = (const float*)d_in[12];
    const float* actr_b   = (const float*)d_in[13];
    const float* acti_s   = (const float*)d_in[14];
    const float* acti_b   = (const float*)d_in[15];
    const float* pw2_w    = (const float*)d_in[16];
    const float* ln2_g    = (const float*)d_in[17];
    const float* ln2_b    = (const float*)d_in[18];
    const float* fc1_w    = (const float*)d_in[19];
    const float* mlp_s    = (const float*)d_in[20];
    const float* mlp_b    = (const float*)d_in[21];
    const float* fc2_w    = (const float*)d_in[22];
    float* out = (float*)d_out;
    float* ws  = (float*)d_ws;

    const size_t HBUF_F = 40960000ull;          // region reserved (hbuf now bf16, uses half)
    const size_t MATS_F = 610000ull;
    const size_t ws_floats = ws_size / 4;
    int CB = 4;
    while (CB > 1 && HBUF_F + 2ull * (size_t)CB * (size_t)PERB2 + MATS_F > ws_floats) CB >>= 1;

    float* hbuf = ws;
    ushort* h16 = (ushort*)hbuf;                 // [80000][512] bf16
    float* tA = ws + HBUF_F;
    float* tB = tA + (size_t)CB * PERB2;
    ushort* mats = (ushort*)(tB + (size_t)CB * PERB2);
    ushort* A1m  = mats;
    ushort* A2m  = A1m + 16384;
    ushort* A4m  = A2m + 65536;
    ushort* A5m  = A4m + 65536;
    ushort* Wc1  = A5m + 16384;
    ushort* Wc2  = Wc1 + 131072;
    ushort* wt1  = Wc2 + 131072;
    ushort* wt2  = wt1 + 131072;
    ushort* wtf1 = wt2 + 131072;
    ushort* wtf2 = wtf1 + 262144;

    ushort* y16 = (ushort*)out;                          // LN1 out (scratch until pw2)
    ushort* y2  = (ushort*)hbuf;                         // LN2 out (h16 dead after pw2)
    ushort* m1h = (ushort*)(hbuf + 10240000ull);         // MLP hidden

    build_A1<<<64, 256, 0, stream>>>(A1m);
    build_A2<0><<<256, 256, 0, stream>>>(A2m);
    build_A2<1><<<256, 256, 0, stream>>>(A4m);
    build_A5<<<64, 256, 0, stream>>>(A5m);
    build_wc<<<512, 256, 0, stream>>>(w1, w11, Wc1);
    build_wc<<<512, 256, 0, stream>>>(w2, w22, Wc2);
    wtrans<<<(131072 + 255) / 256, 256, 0, stream>>>(pw1_w, wt1, DIM, MED);
    wtrans<<<(131072 + 255) / 256, 256, 0, stream>>>(pw2_w, wt2, MED, DIM);
    wtrans<<<(262144 + 255) / 256, 256, 0, stream>>>(fc1_w, wtf1, DIM, 1024);
    wtrans<<<(262144 + 255) / 256, 256, 0, stream>>>(fc2_w, wtf2, 1024, DIM);

    // ---- token mixer ----
    ln_fast<<<NPOS / 4, 256, 0, stream>>>(x, ln1_g, ln1_b, y16);
    gemm_mfma<3, 1><<<(NPOS / 128) * (MED / 128), 256, 0, stream>>>(
            y16, wt1, nullptr, h16, nullptr, act1_s, act1_b, NPOS, MED, DIM);

    for (int b0 = 0; b0 < 8; b0 += CB) {
        ushort* hchunk = h16 + (size_t)b0 * (SZ * SZ * MED);
        // K1: rfft along W (B = bf16 h) -> tA
        gemm_dft<0, 1, 0><<<CB * 100 * 4, 256, 0, stream>>>(
                A1m, 128, hchunk, 1, 51200, 0, 512, 100, 0, 100, 2,
                tA, 100, PERB2, HROW, 512, 51, PL, 102, 4, 1);
        // K2: forward DFT along H: tA -> tB
        gemm_dft<0, 0, 0><<<CB * 408, 256, 0, stream>>>(
                A2m, 256, tA, 1, PERB2, 0, HROW, 100, PL, 200, 4,
                tB, 1, PERB2, 0, HROW, 100, PL, 200, 204, 2);
        // bmm layer 1: F2 -> G1 (=tA)
        gemm_bmm<0><<<CB * 320, 256, 0, stream>>>(
                tB, tA, Wc1, b1, actr_s, actr_b, acti_s, acti_b);
        // bmm layer 2: G1, x F2 -> F2 in place
        gemm_bmm<1><<<CB * 320, 256, 0, stream>>>(
                tB, tA, Wc2, b2, nullptr, nullptr, nullptr, nullptr);
        // K4: inverse DFT along H: tB -> tA
        gemm_dft<0, 0, 0><<<CB * 408, 256, 0, stream>>>(
                A4m, 256, tB, 1, PERB2, 0, HROW, 100, PL, 200, 4,
                tA, 1, PERB2, 0, HROW, 100, PL, 200, 204, 2);
        // K5: irfft along W + skip accumulate into bf16 h
        gemm_dft<1, 0, 1><<<CB * 100 * 4, 256, 0, stream>>>(
                A5m, 128, tA, 100, PERB2, HROW, 512, 51, PL, 102, 2,
                hchunk, 1, 51200, 0, 512, 100, 0, 100, 4, 1);
    }

    gemm_mfma<2, 1><<<(NPOS / 128) * (DIM / 128), 256, 0, stream>>>(
            h16, wt2, out, nullptr, x, nullptr, nullptr, NPOS, DIM, MED);

    // ---- MLP branch ----
    ln_fast<<<NPOS / 4, 256, 0, stream>>>(out, ln2_g, ln2_b, y2);
    for (int ch = 0; ch < 5; ++ch) {
        const ushort* yc = y2 + (size_t)ch * 16000 * DIM;
        float* oc = out + (size_t)ch * 16000 * DIM;
        gemm_mfma<3, 1><<<(16000 / 128) * (1024 / 128), 256, 0, stream>>>(
                yc, wtf1, nullptr, m1h, nullptr, mlp_s, mlp_b, 16000, 1024, DIM);
        gemm_mfma<2, 1><<<(16000 / 128) * (DIM / 128), 256, 0, stream>>>(
                m1h, wtf2, oc, nullptr, oc, nullptr, nullptr, 16000, DIM, 1024);
    }
}

// Round 6
// 790.198 us; speedup vs baseline: 7.4914x; 1.3172x over previous
//
#include <hip/hip_runtime.h>
#include <math.h>

#define SZ    100
#define FILT  51
#define DIM   256
#define MED   512
#define NPOS  80000

#define PERB2 5222400ll          // 2*100*51*512 elems per batch (stacked R/I)
#define PL    2611200ll          // plane stride (100*51*512)
#define HROW  26112              // 51*512

typedef __attribute__((ext_vector_type(8))) short short8v;
typedef __attribute__((ext_vector_type(4))) float f32x4;

__device__ __forceinline__ ushort f2b(float f) {
    union { float f; unsigned u; } x; x.f = f;
    unsigned r = (x.u + 0x7fffu + ((x.u >> 16) & 1u)) >> 16;
    return (ushort)r;
}
__device__ __forceinline__ float b2f(ushort u) {
    union { float f; unsigned u; } x; x.u = ((unsigned)u) << 16;
    return x.f;
}

#define DPI 3.14159265358979323846

// ================= builders =================
__global__ void build_A1(ushort* __restrict__ A) {          // [128][128]
    const int id = blockIdx.x * 256 + threadIdx.x;
    const int rho = id >> 7, w = id & 127;
    float v = 0.f;
    if (w < SZ) {
        if (rho < FILT)          { int m = (rho * w) % SZ;          v =  0.01f * (float)cos(2.0 * DPI * m / SZ); }
        else if (rho < 2 * FILT) { int m = ((rho - FILT) * w) % SZ; v = -0.01f * (float)sin(2.0 * DPI * m / SZ); }
    }
    A[id] = f2b(v);
}

template<int INV>
__global__ void build_A2(ushort* __restrict__ A) {          // [256][256]
    const int id = blockIdx.x * 256 + threadIdx.x;
    const int rho = id >> 8, kk = id & 255;
    float v = 0.f;
    const double sgn = INV ? -1.0 : 1.0;
    if (rho < SZ) {
        if (kk < SZ)           { int m = (rho * kk) % SZ;        v = (float)cos(2.0 * DPI * m / SZ); }
        else if (kk < 2 * SZ)  { int m = (rho * (kk - SZ)) % SZ; v = (float)(sgn * sin(2.0 * DPI * m / SZ)); }
    } else if (rho < 2 * SZ) {
        const int i = rho - SZ;
        if (kk < SZ)           { int m = (i * kk) % SZ;          v = (float)(-sgn * sin(2.0 * DPI * m / SZ)); }
        else if (kk < 2 * SZ)  { int m = (i * (kk - SZ)) % SZ;   v = (float)cos(2.0 * DPI * m / SZ); }
    }
    A[id] = f2b(v);
}

__global__ void build_A5(ushort* __restrict__ A) {          // [128][128]
    const int id = blockIdx.x * 256 + threadIdx.x;
    const int w = id >> 7, kk = id & 127;
    float v = 0.f;
    if (w < SZ) {
        if (kk < FILT) {
            const float wgt = (kk == 0 || kk == FILT - 1) ? 0.01f : 0.02f;
            int m = (w * kk) % SZ; v = wgt * (float)cos(2.0 * DPI * m / SZ);
        } else if (kk < 2 * FILT) {
            const int f = kk - FILT;
            const float wgt = (f == 0 || f == FILT - 1) ? 0.01f : 0.02f;
            int m = (w * f) % SZ; v = -wgt * (float)sin(2.0 * DPI * m / SZ);
        }
    }
    A[id] = f2b(v);
}

// combined block weights, out-major: Wc[n][j(out 0..127)][i(in 0..127)]
__global__ void build_wc(const float* __restrict__ wA, const float* __restrict__ wB,
                         ushort* __restrict__ Wc) {
    const int id = blockIdx.x * 256 + threadIdx.x;          // 131072
    const int n = id >> 14, j = (id >> 7) & 127, i = id & 127;
    float v;
    if (j < 64) v = (i < 64) ? wA[((0 * 8 + n) * 64 + i) * 64 + j]
                             : wA[((1 * 8 + n) * 64 + (i - 64)) * 64 + j];
    else {
        const int jp = j - 64;
        v = (i < 64) ? wB[((1 * 8 + n) * 64 + i) * 64 + jp]
                     : wB[((0 * 8 + n) * 64 + (i - 64)) * 64 + jp];
    }
    Wc[id] = f2b(v);
}

__global__ void wtrans(const float* __restrict__ W, ushort* __restrict__ Wt, int K, int N) {
    const int idx = blockIdx.x * 256 + threadIdx.x;
    if (idx < N * K) {
        const int n = idx / K, k = idx % K;
        Wt[idx] = f2b(W[(size_t)k * N + n]);
    }
}

// ================= fast LayerNorm: one wave per 256-elem row =================
__global__ __launch_bounds__(256) void ln_fast(const float* __restrict__ x,
        const float* __restrict__ g, const float* __restrict__ b, ushort* __restrict__ y)
{
    const int row = blockIdx.x * 4 + (threadIdx.x >> 6);
    const int lane = threadIdx.x & 63;
    const float4 v = *(const float4*)(x + (size_t)row * DIM + lane * 4);
    float s  = v.x + v.y + v.z + v.w;
    float s2 = v.x * v.x + v.y * v.y + v.z * v.z + v.w * v.w;
    #pragma unroll
    for (int off = 32; off > 0; off >>= 1) {
        s  += __shfl_xor(s, off, 64);
        s2 += __shfl_xor(s2, off, 64);
    }
    const float mu  = s * (1.0f / DIM);
    const float var = s2 * (1.0f / DIM) - mu * mu;
    const float rs  = rsqrtf(var + 1e-5f);
    const float4 gv = *(const float4*)(g + lane * 4);
    const float4 bv = *(const float4*)(b + lane * 4);
    ushort4 o;
    o.x = f2b((v.x - mu) * rs * gv.x + bv.x);
    o.y = f2b((v.y - mu) * rs * gv.y + bv.y);
    o.z = f2b((v.z - mu) * rs * gv.z + bv.z);
    o.w = f2b((v.w - mu) * rs * gv.w + bv.w);
    *(ushort4*)(y + (size_t)row * DIM + lane * 4) = o;
}

// ================= dense bf16 MFMA GEMM =================
// EPI: 1 star_relu -> fp32, 2 +R -> fp32, 3 star_relu -> bf16
template<int EPI, int ABF16>
__global__ __launch_bounds__(256) void gemm_mfma(
        const void* __restrict__ Av, const ushort* __restrict__ Bt,
        float* __restrict__ Cf, ushort* __restrict__ Cb,
        const float* __restrict__ R, const float* __restrict__ sp, const float* __restrict__ bp,
        int M, int N, int K)
{
    __shared__ ushort As[128][72];
    __shared__ ushort Bs[128][72];
    const int t = threadIdx.x;
    const int nwg = gridDim.x;
    const int orig = blockIdx.x;
    const int q = nwg >> 3, rr8 = nwg & 7;
    const int xcd = orig & 7, lo = orig >> 3;
    const int wg = (xcd < rr8 ? xcd * (q + 1) : rr8 * (q + 1) + (xcd - rr8) * q) + lo;
    const int NX = N >> 7;
    const int by = wg / NX, bx = wg % NX;
    const int m0 = by * 128, n0 = bx * 128;

    const ushort* A16 = (const ushort*)Av;
    const float*  A32 = (const float*)Av;
    const int lane = t & 63;
    const int wid = t >> 6;
    const int wr = (wid >> 1) * 64, wc = (wid & 1) * 64;
    const int fr = lane & 15, fg = lane >> 4;

    f32x4 acc[4][4];
    #pragma unroll
    for (int i = 0; i < 4; ++i)
        #pragma unroll
        for (int j = 0; j < 4; ++j) acc[i][j] = (f32x4){0.f, 0.f, 0.f, 0.f};

    for (int k0 = 0; k0 < K; k0 += 64) {
        #pragma unroll
        for (int i = 0; i < 4; ++i) {
            const int seg = t + 256 * i;
            const int row = seg >> 3, off = (seg & 7) * 8;
            if (ABF16) {
                *(short8v*)&As[row][off] = *(const short8v*)(A16 + (size_t)(m0 + row) * K + k0 + off);
            } else {
                const float* src = A32 + (size_t)(m0 + row) * K + k0 + off;
                const float4 f0 = *(const float4*)(src);
                const float4 f1 = *(const float4*)(src + 4);
                short8v v;
                v[0] = (short)f2b(f0.x); v[1] = (short)f2b(f0.y);
                v[2] = (short)f2b(f0.z); v[3] = (short)f2b(f0.w);
                v[4] = (short)f2b(f1.x); v[5] = (short)f2b(f1.y);
                v[6] = (short)f2b(f1.z); v[7] = (short)f2b(f1.w);
                *(short8v*)&As[row][off] = v;
            }
            *(short8v*)&Bs[row][off] = *(const short8v*)(Bt + (size_t)(n0 + row) * K + k0 + off);
        }
        __syncthreads();
        #pragma unroll
        for (int ks = 0; ks < 2; ++ks) {
            const int koff = ks * 32 + fg * 8;
            short8v a[4], b[4];
            #pragma unroll
            for (int mi = 0; mi < 4; ++mi) a[mi] = *(const short8v*)&As[wr + mi * 16 + fr][koff];
            #pragma unroll
            for (int ni = 0; ni < 4; ++ni) b[ni] = *(const short8v*)&Bs[wc + ni * 16 + fr][koff];
            #pragma unroll
            for (int mi = 0; mi < 4; ++mi)
                #pragma unroll
                for (int ni = 0; ni < 4; ++ni)
                    acc[mi][ni] = __builtin_amdgcn_mfma_f32_16x16x32_bf16(
                            a[mi], b[ni], acc[mi][ni], 0, 0, 0);
        }
        __syncthreads();
    }
    float s = 0.f, bb = 0.f;
    if (EPI == 1 || EPI == 3) { s = sp[0]; bb = bp[0]; }
    #pragma unroll
    for (int mi = 0; mi < 4; ++mi) {
        #pragma unroll
        for (int r = 0; r < 4; ++r) {
            const int row = m0 + wr + mi * 16 + fg * 4 + r;
            #pragma unroll
            for (int ni = 0; ni < 4; ++ni) {
                const int col = n0 + wc + ni * 16 + fr;
                float v = acc[mi][ni][r];
                const size_t off = (size_t)row * N + col;
                if (EPI == 1) {
                    const float rl = fmaxf(v, 0.f);
                    Cf[off] = s * rl * rl + bb;
                } else if (EPI == 2) {
                    Cf[off] = v + R[off];
                } else {
                    const float rl = fmaxf(v, 0.f);
                    Cb[off] = f2b(s * rl * rl + bb);
                }
            }
        }
    }
}

// ================= small-A MFMA GEMM for DFT stages (bf16 in/out) =================
// C[rho][n] = sum_k A[rho][k] * B[k][n]; EPI: 0 write, 1 accumulate into C (bf16 RMW)
template<int EPI>
__global__ __launch_bounds__(256) void gemm_dft(
        const ushort* __restrict__ Ag, int Apitch,
        const ushort* __restrict__ Bv, int BzDiv, long BzA, long BzB, int Brs,
        int Bsplit, long BplOff, int Kreal, int Ksteps,
        ushort* __restrict__ Cv, int CzDiv, long CzA, long CzB, int Crs,
        int Csplit, long CplOff, int Climit, int ntiles, int mtiles)
{
    __shared__ ushort As[128][72];
    __shared__ ushort Bs[128][72];
    const int t = threadIdx.x;
    const int per_z = ntiles * mtiles;
    const int z = blockIdx.x / per_z;
    const int rem = blockIdx.x % per_z;
    const int mt = rem % mtiles;
    const int nt = rem / mtiles;
    const int col0 = nt * 128;
    const long Bzbase = (long)(z / BzDiv) * BzA + (long)(z % BzDiv) * BzB;
    const long Czbase = (long)(z / CzDiv) * CzA + (long)(z % CzDiv) * CzB;
    const int lane = t & 63, wid = t >> 6;
    const int wr = (wid >> 1) * 64, wc = (wid & 1) * 64;
    const int fr = lane & 15, fg = lane >> 4;

    f32x4 acc[4][4];
    #pragma unroll
    for (int i = 0; i < 4; ++i)
        #pragma unroll
        for (int j = 0; j < 4; ++j) acc[i][j] = (f32x4){0.f, 0.f, 0.f, 0.f};

    for (int step = 0; step < Ksteps; ++step) {
        const int k0 = step * 64;
        #pragma unroll
        for (int i = 0; i < 4; ++i) {
            const int id = t + 256 * i;
            const int r = id >> 3, j = (id & 7) * 8;
            *(short8v*)&As[r][j] = *(const short8v*)(Ag + (size_t)(mt * 128 + r) * Apitch + k0 + j);
        }
        // stage B slice transposed into Bs[n][k], kblk XOR-swizzled by (n>>3)&7
        #pragma unroll
        for (int i = 0; i < 2; ++i) {
            const int kp = (t >> 4) + 16 * i;     // k-pair 0..31
            const int np = t & 15;                // n-chunk (8 cols)
            const int kg0 = k0 + 2 * kp;
            ushort u0[8] = {0,0,0,0,0,0,0,0}, u1[8] = {0,0,0,0,0,0,0,0};
            if (kg0 < Kreal) {
                const long roff = Bzbase
                        + (kg0 < Bsplit ? (long)kg0 * Brs : BplOff + (long)(kg0 - Bsplit) * Brs)
                        + col0 + np * 8;
                const short8v tv = *(const short8v*)(Bv + roff);
                #pragma unroll
                for (int jj = 0; jj < 8; ++jj) u0[jj] = (ushort)tv[jj];
            }
            if (kg0 + 1 < Kreal) {
                const int kg1 = kg0 + 1;
                const long roff = Bzbase
                        + (kg1 < Bsplit ? (long)kg1 * Brs : BplOff + (long)(kg1 - Bsplit) * Brs)
                        + col0 + np * 8;
                const short8v tv = *(const short8v*)(Bv + roff);
                #pragma unroll
                for (int jj = 0; jj < 8; ++jj) u1[jj] = (ushort)tv[jj];
            }
            const int blk = (kp >> 2) ^ (np & 7);
            #pragma unroll
            for (int jj = 0; jj < 8; ++jj) {
                const int n = np * 8 + jj;
                ushort2 pr; pr.x = u0[jj]; pr.y = u1[jj];
                *(ushort2*)&Bs[n][blk * 8 + ((2 * kp) & 7)] = pr;
            }
        }
        __syncthreads();
        #pragma unroll
        for (int ks = 0; ks < 2; ++ks) {
            const int koff = ks * 32 + fg * 8;
            short8v a[4], b[4];
            #pragma unroll
            for (int mi = 0; mi < 4; ++mi) a[mi] = *(const short8v*)&As[wr + mi * 16 + fr][koff];
            #pragma unroll
            for (int ni = 0; ni < 4; ++ni) {
                const int n = wc + ni * 16 + fr;
                const int blk = (koff >> 3) ^ ((n >> 3) & 7);
                b[ni] = *(const short8v*)&Bs[n][blk * 8];
            }
            #pragma unroll
            for (int mi = 0; mi < 4; ++mi)
                #pragma unroll
                for (int ni = 0; ni < 4; ++ni)
                    acc[mi][ni] = __builtin_amdgcn_mfma_f32_16x16x32_bf16(
                            a[mi], b[ni], acc[mi][ni], 0, 0, 0);
        }
        __syncthreads();
    }
    #pragma unroll
    for (int mi = 0; mi < 4; ++mi) {
        #pragma unroll
        for (int rq = 0; rq < 4; ++rq) {
            const int rho = mt * 128 + wr + mi * 16 + fg * 4 + rq;
            if (rho >= Climit) continue;
            const long rbase = Czbase
                    + (rho < Csplit ? (long)rho * Crs : CplOff + (long)(rho - Csplit) * Crs);
            #pragma unroll
            for (int ni = 0; ni < 4; ++ni) {
                const long caddr = rbase + col0 + wc + ni * 16 + fr;
                float v = acc[mi][ni][rq];
                if (EPI == 1) v += b2f(Cv[caddr]);
                Cv[caddr] = f2b(v);
            }
        }
    }
}

// ================= block-diagonal complex MLP via MFMA (bf16 in/out) =================
template<int SECOND>
__global__ __launch_bounds__(256) void gemm_bmm(
        ushort* __restrict__ F2, ushort* __restrict__ G1,
        const ushort* __restrict__ Wc, const float* __restrict__ bias,
        const float* __restrict__ s0p, const float* __restrict__ b0p,
        const float* __restrict__ s1p, const float* __restrict__ b1p)
{
    const int MT = 40;
    const int wg = blockIdx.x;
    const int mt = wg % MT;
    const int n  = (wg / MT) & 7;
    const int bl = wg / (MT * 8);
    const long FB = (long)bl * PERB2;
    const long GB = ((long)(bl * 8 + n)) * 5100 * 128;
    const int r0 = mt * 128;
    __shared__ ushort As[128][72];
    __shared__ ushort Ws[128][72];
    const int t = threadIdx.x;
    const int lane = t & 63, wid = t >> 6;
    const int wr = (wid >> 1) * 64, wc = (wid & 1) * 64;
    const int fr = lane & 15, fg = lane >> 4;

    f32x4 acc[4][4];
    #pragma unroll
    for (int i = 0; i < 4; ++i)
        #pragma unroll
        for (int j = 0; j < 4; ++j) acc[i][j] = (f32x4){0.f, 0.f, 0.f, 0.f};

    for (int step = 0; step < 2; ++step) {
        #pragma unroll
        for (int i = 0; i < 4; ++i) {
            const int id = t + 256 * i;
            const int r = id >> 3, j = (id & 7) * 8;
            short8v v = {0,0,0,0,0,0,0,0};
            if (r0 + r < 5100) {
                const ushort* src = SECOND
                    ? (G1 + GB + (long)(r0 + r) * 128 + step * 64 + j)
                    : (F2 + FB + (step ? PL : 0) + (long)(r0 + r) * 512 + n * 64 + j);
                v = *(const short8v*)src;
            }
            *(short8v*)&As[r][j] = v;
        }
        #pragma unroll
        for (int i = 0; i < 4; ++i) {
            const int id = t + 256 * i;
            const int r = id >> 3, j = (id & 7) * 8;
            *(short8v*)&Ws[r][j] = *(const short8v*)(Wc + ((long)n << 14) + r * 128 + step * 64 + j);
        }
        __syncthreads();
        #pragma unroll
        for (int ks = 0; ks < 2; ++ks) {
            const int koff = ks * 32 + fg * 8;
            short8v a[4], b[4];
            #pragma unroll
            for (int mi = 0; mi < 4; ++mi) a[mi] = *(const short8v*)&As[wr + mi * 16 + fr][koff];
            #pragma unroll
            for (int ni = 0; ni < 4; ++ni) b[ni] = *(const short8v*)&Ws[wc + ni * 16 + fr][koff];
            #pragma unroll
            for (int mi = 0; mi < 4; ++mi)
                #pragma unroll
                for (int ni = 0; ni < 4; ++ni)
                    acc[mi][ni] = __builtin_amdgcn_mfma_f32_16x16x32_bf16(
                            a[mi], b[ni], acc[mi][ni], 0, 0, 0);
        }
        __syncthreads();
    }
    #pragma unroll
    for (int mi = 0; mi < 4; ++mi) {
        #pragma unroll
        for (int rq = 0; rq < 4; ++rq) {
            const int r = r0 + wr + mi * 16 + fg * 4 + rq;
            if (r >= 5100) continue;
            #pragma unroll
            for (int ni = 0; ni < 4; ++ni) {
                const int j = wc + ni * 16 + fr;
                float u = acc[mi][ni][rq] + bias[(j < 64 ? 0 : 512) + n * 64 + (j & 63)];
                if (!SECOND) {
                    const float s  = (j < 64) ? s0p[0] : s1p[0];
                    const float bb = (j < 64) ? b0p[0] : b1p[0];
                    const float rl = fmaxf(u, 0.f);
                    G1[GB + (long)r * 128 + j] = f2b(s * rl * rl + bb);
                } else {
                    const long ma = FB + (j < 64 ? 0 : PL) + (long)r * 512 + n * 64 + (j & 63);
                    F2[ma] = f2b(u * b2f(F2[ma]));
                }
            }
        }
    }
}

// ================= launcher =================
extern "C" void kernel_launch(void* const* d_in, const int* in_sizes, int n_in,
                              void* d_out, int out_size, void* d_ws, size_t ws_size,
                              hipStream_t stream) {
    (void)in_sizes; (void)n_in; (void)out_size;
    const float* x        = (const float*)d_in[0];
    const float* ln1_g    = (const float*)d_in[1];
    const float* ln1_b    = (const float*)d_in[2];
    const float* pw1_w    = (const float*)d_in[3];
    const float* act1_s   = (const float*)d_in[4];
    const float* act1_b   = (const float*)d_in[5];
    const float* w1       = (const float*)d_in[6];
    const float* w11      = (const float*)d_in[7];
    const float* b1       = (const float*)d_in[8];
    const float* w2       = (const float*)d_in[9];
    const float* w22      = (const float*)d_in[10];
    const float* b2       = (const float*)d_in[11];
    const float* actr_s   = (const float*)d_in[12];
    const float* actr_b   = (const float*)d_in[13];
    const float* acti_s   = (const float*)d_in[14];
    const float* acti_b   = (const float*)d_in[15];
    const float* pw2_w    = (const float*)d_in[16];
    const float* ln2_g    = (const float*)d_in[17];
    const float* ln2_b    = (const float*)d_in[18];
    const float* fc1_w    = (const float*)d_in[19];
    const float* mlp_s    = (const float*)d_in[20];
    const float* mlp_b    = (const float*)d_in[21];
    const float* fc2_w    = (const float*)d_in[22];
    float* out = (float*)d_out;
    float* ws  = (float*)d_ws;

    const size_t HBUF_F = 40960000ull;          // h16 region (bf16 uses half)
    const size_t MATS_F = 610000ull;
    const size_t ws_floats = ws_size / 4;
    // bf16 temps: tA+tB together = CB*PERB2 floats worth of bytes
    int CB = 4;
    while (CB > 1 && HBUF_F + (size_t)CB * (size_t)PERB2 + MATS_F > ws_floats) CB >>= 1;

    float* hbuf = ws;
    ushort* h16 = (ushort*)hbuf;                 // [80000][512] bf16
    ushort* tA16 = (ushort*)(ws + HBUF_F);       // CB*PERB2 ushorts
    ushort* tB16 = tA16 + (size_t)CB * PERB2;
    ushort* mats = tB16 + (size_t)CB * PERB2;
    ushort* A1m  = mats;
    ushort* A2m  = A1m + 16384;
    ushort* A4m  = A2m + 65536;
    ushort* A5m  = A4m + 65536;
    ushort* Wc1  = A5m + 16384;
    ushort* Wc2  = Wc1 + 131072;
    ushort* wt1  = Wc2 + 131072;
    ushort* wt2  = wt1 + 131072;
    ushort* wtf1 = wt2 + 131072;
    ushort* wtf2 = wtf1 + 262144;

    ushort* y16 = (ushort*)out;                          // LN1 out (scratch until pw2)
    ushort* y2  = (ushort*)hbuf;                         // LN2 out (h16 dead after pw2)
    ushort* m1h = (ushort*)(hbuf + 10240000ull);         // MLP hidden chunk

    build_A1<<<64, 256, 0, stream>>>(A1m);
    build_A2<0><<<256, 256, 0, stream>>>(A2m);
    build_A2<1><<<256, 256, 0, stream>>>(A4m);
    build_A5<<<64, 256, 0, stream>>>(A5m);
    build_wc<<<512, 256, 0, stream>>>(w1, w11, Wc1);
    build_wc<<<512, 256, 0, stream>>>(w2, w22, Wc2);
    wtrans<<<(131072 + 255) / 256, 256, 0, stream>>>(pw1_w, wt1, DIM, MED);
    wtrans<<<(131072 + 255) / 256, 256, 0, stream>>>(pw2_w, wt2, MED, DIM);
    wtrans<<<(262144 + 255) / 256, 256, 0, stream>>>(fc1_w, wtf1, DIM, 1024);
    wtrans<<<(262144 + 255) / 256, 256, 0, stream>>>(fc2_w, wtf2, 1024, DIM);

    // ---- token mixer ----
    ln_fast<<<NPOS / 4, 256, 0, stream>>>(x, ln1_g, ln1_b, y16);
    gemm_mfma<3, 1><<<(NPOS / 128) * (MED / 128), 256, 0, stream>>>(
            y16, wt1, nullptr, h16, nullptr, act1_s, act1_b, NPOS, MED, DIM);

    for (int b0 = 0; b0 < 8; b0 += CB) {
        ushort* hchunk = h16 + (size_t)b0 * (SZ * SZ * MED);
        // K1: rfft along W -> tA
        gemm_dft<0><<<CB * 100 * 4, 256, 0, stream>>>(
                A1m, 128, hchunk, 1, 51200, 0, 512, 100, 0, 100, 2,
                tA16, 100, PERB2, HROW, 512, 51, PL, 102, 4, 1);
        // K2: forward DFT along H: tA -> tB
        gemm_dft<0><<<CB * 408, 256, 0, stream>>>(
                A2m, 256, tA16, 1, PERB2, 0, HROW, 100, PL, 200, 4,
                tB16, 1, PERB2, 0, HROW, 100, PL, 200, 204, 2);
        // bmm layer 1: F2 -> G1 (=tA)
        gemm_bmm<0><<<CB * 320, 256, 0, stream>>>(
                tB16, tA16, Wc1, b1, actr_s, actr_b, acti_s, acti_b);
        // bmm layer 2: G1, x F2 -> F2 in place
        gemm_bmm<1><<<CB * 320, 256, 0, stream>>>(
                tB16, tA16, Wc2, b2, nullptr, nullptr, nullptr, nullptr);
        // K4: inverse DFT along H: tB -> tA
        gemm_dft<0><<<CB * 408, 256, 0, stream>>>(
                A4m, 256, tB16, 1, PERB2, 0, HROW, 100, PL, 200, 4,
                tA16, 1, PERB2, 0, HROW, 100, PL, 200, 204, 2);
        // K5: irfft along W + skip accumulate into bf16 h
        gemm_dft<1><<<CB * 100 * 4, 256, 0, stream>>>(
                A5m, 128, tA16, 100, PERB2, HROW, 512, 51, PL, 102, 2,
                hchunk, 1, 51200, 0, 512, 100, 0, 100, 4, 1);
    }

    gemm_mfma<2, 1><<<(NPOS / 128) * (DIM / 128), 256, 0, stream>>>(
            h16, wt2, out, nullptr, x, nullptr, nullptr, NPOS, DIM, MED);

    // ---- MLP branch ----
    ln_fast<<<NPOS / 4, 256, 0, stream>>>(out, ln2_g, ln2_b, y2);
    for (int ch = 0; ch < 5; ++ch) {
        const ushort* yc = y2 + (size_t)ch * 16000 * DIM;
        float* oc = out + (size_t)ch * 16000 * DIM;
        gemm_mfma<3, 1><<<(16000 / 128) * (1024 / 128), 256, 0, stream>>>(
                yc, wtf1, nullptr, m1h, nullptr, mlp_s, mlp_b, 16000, 1024, DIM);
        gemm_mfma<2, 1><<<(16000 / 128) * (DIM / 128), 256, 0, stream>>>(
                m1h, wtf2, oc, nullptr, oc, nullptr, nullptr, 16000, DIM, 1024);
    }
}

// Round 7
// 777.086 us; speedup vs baseline: 7.6178x; 1.0169x over previous
//
#include <hip/hip_runtime.h>
#include <math.h>

#define SZ    100
#define FILT  51
#define DIM   256
#define MED   512
#define NPOS  80000

#define PERB2 5222400ll          // 2*100*51*512 elems per batch (stacked R/I)
#define PL    2611200ll          // plane stride (100*51*512)
#define HROW  26112              // 51*512

typedef __attribute__((ext_vector_type(8))) short short8v;
typedef __attribute__((ext_vector_type(4))) float f32x4;

__device__ __forceinline__ ushort f2b(float f) {
    union { float f; unsigned u; } x; x.f = f;
    unsigned r = (x.u + 0x7fffu + ((x.u >> 16) & 1u)) >> 16;
    return (ushort)r;
}
__device__ __forceinline__ float b2f(ushort u) {
    union { float f; unsigned u; } x; x.u = ((unsigned)u) << 16;
    return x.f;
}

// direct global->LDS, 16B per lane; dst must be wave-uniform base (lane*16 implied)
__device__ __forceinline__ void gload16(const ushort* g, ushort* l) {
    __builtin_amdgcn_global_load_lds(
        (const __attribute__((address_space(1))) void*)g,
        (__attribute__((address_space(3))) void*)l, 16, 0, 0);
}

#define DPI 3.14159265358979323846

// ================= builders =================
__global__ void build_A1(ushort* __restrict__ A) {          // [128][128]
    const int id = blockIdx.x * 256 + threadIdx.x;
    const int rho = id >> 7, w = id & 127;
    float v = 0.f;
    if (w < SZ) {
        if (rho < FILT)          { int m = (rho * w) % SZ;          v =  0.01f * (float)cos(2.0 * DPI * m / SZ); }
        else if (rho < 2 * FILT) { int m = ((rho - FILT) * w) % SZ; v = -0.01f * (float)sin(2.0 * DPI * m / SZ); }
    }
    A[id] = f2b(v);
}

template<int INV>
__global__ void build_A2(ushort* __restrict__ A) {          // [256][256]
    const int id = blockIdx.x * 256 + threadIdx.x;
    const int rho = id >> 8, kk = id & 255;
    float v = 0.f;
    const double sgn = INV ? -1.0 : 1.0;
    if (rho < SZ) {
        if (kk < SZ)           { int m = (rho * kk) % SZ;        v = (float)cos(2.0 * DPI * m / SZ); }
        else if (kk < 2 * SZ)  { int m = (rho * (kk - SZ)) % SZ; v = (float)(sgn * sin(2.0 * DPI * m / SZ)); }
    } else if (rho < 2 * SZ) {
        const int i = rho - SZ;
        if (kk < SZ)           { int m = (i * kk) % SZ;          v = (float)(-sgn * sin(2.0 * DPI * m / SZ)); }
        else if (kk < 2 * SZ)  { int m = (i * (kk - SZ)) % SZ;   v = (float)cos(2.0 * DPI * m / SZ); }
    }
    A[id] = f2b(v);
}

__global__ void build_A5(ushort* __restrict__ A) {          // [128][128]
    const int id = blockIdx.x * 256 + threadIdx.x;
    const int w = id >> 7, kk = id & 127;
    float v = 0.f;
    if (w < SZ) {
        if (kk < FILT) {
            const float wgt = (kk == 0 || kk == FILT - 1) ? 0.01f : 0.02f;
            int m = (w * kk) % SZ; v = wgt * (float)cos(2.0 * DPI * m / SZ);
        } else if (kk < 2 * FILT) {
            const int f = kk - FILT;
            const float wgt = (f == 0 || f == FILT - 1) ? 0.01f : 0.02f;
            int m = (w * f) % SZ; v = -wgt * (float)sin(2.0 * DPI * m / SZ);
        }
    }
    A[id] = f2b(v);
}

// combined block weights, out-major: Wc[n][j(out 0..127)][i(in 0..127)]
__global__ void build_wc(const float* __restrict__ wA, const float* __restrict__ wB,
                         ushort* __restrict__ Wc) {
    const int id = blockIdx.x * 256 + threadIdx.x;          // 131072
    const int n = id >> 14, j = (id >> 7) & 127, i = id & 127;
    float v;
    if (j < 64) v = (i < 64) ? wA[((0 * 8 + n) * 64 + i) * 64 + j]
                             : wA[((1 * 8 + n) * 64 + (i - 64)) * 64 + j];
    else {
        const int jp = j - 64;
        v = (i < 64) ? wB[((1 * 8 + n) * 64 + i) * 64 + jp]
                     : wB[((0 * 8 + n) * 64 + (i - 64)) * 64 + jp];
    }
    Wc[id] = f2b(v);
}

__global__ void wtrans(const float* __restrict__ W, ushort* __restrict__ Wt, int K, int N) {
    const int idx = blockIdx.x * 256 + threadIdx.x;
    if (idx < N * K) {
        const int n = idx / K, k = idx % K;
        Wt[idx] = f2b(W[(size_t)k * N + n]);
    }
}

// ================= fast LayerNorm: one wave per 256-elem row =================
__global__ __launch_bounds__(256) void ln_fast(const float* __restrict__ x,
        const float* __restrict__ g, const float* __restrict__ b, ushort* __restrict__ y)
{
    const int row = blockIdx.x * 4 + (threadIdx.x >> 6);
    const int lane = threadIdx.x & 63;
    const float4 v = *(const float4*)(x + (size_t)row * DIM + lane * 4);
    float s  = v.x + v.y + v.z + v.w;
    float s2 = v.x * v.x + v.y * v.y + v.z * v.z + v.w * v.w;
    #pragma unroll
    for (int off = 32; off > 0; off >>= 1) {
        s  += __shfl_xor(s, off, 64);
        s2 += __shfl_xor(s2, off, 64);
    }
    const float mu  = s * (1.0f / DIM);
    const float var = s2 * (1.0f / DIM) - mu * mu;
    const float rs  = rsqrtf(var + 1e-5f);
    const float4 gv = *(const float4*)(g + lane * 4);
    const float4 bv = *(const float4*)(b + lane * 4);
    ushort4 o;
    o.x = f2b((v.x - mu) * rs * gv.x + bv.x);
    o.y = f2b((v.y - mu) * rs * gv.y + bv.y);
    o.z = f2b((v.z - mu) * rs * gv.z + bv.z);
    o.w = f2b((v.w - mu) * rs * gv.w + bv.w);
    *(ushort4*)(y + (size_t)row * DIM + lane * 4) = o;
}

// ================= dense bf16 MFMA GEMM, global_load_lds + XOR-swizzled LDS =================
// A bf16 [M][K], Bt bf16 [N][K]; EPI: 1 star_relu->fp32, 2 +R->fp32, 3 star_relu->bf16
template<int EPI>
__global__ __launch_bounds__(256) void gemm_mfma(
        const ushort* __restrict__ A16, const ushort* __restrict__ Bt,
        float* __restrict__ Cf, ushort* __restrict__ Cb,
        const float* __restrict__ R, const float* __restrict__ sp, const float* __restrict__ bp,
        int M, int N, int K)
{
    __shared__ ushort As[128][64];   // linear rows (128B); data pre-swizzled at source
    __shared__ ushort Bs[128][64];
    const int t = threadIdx.x;
    const int nwg = gridDim.x;
    const int orig = blockIdx.x;
    const int q = nwg >> 3, rr8 = nwg & 7;
    const int xcd = orig & 7, lo = orig >> 3;
    const int wg = (xcd < rr8 ? xcd * (q + 1) : rr8 * (q + 1) + (xcd - rr8) * q) + lo;
    const int NX = N >> 7;
    const int by = wg / NX, bx = wg % NX;
    const int m0 = by * 128, n0 = bx * 128;

    const int lane = t & 63;
    const int wid = t >> 6;
    const int wr = (wid >> 1) * 64, wc = (wid & 1) * 64;
    const int fr = lane & 15, fg = lane >> 4;
    const int lr = lane >> 3;                          // row-in-segment 0..7
    const int swz = ((lane & 7) ^ lr) * 8;             // inverse-swizzled source col (elems)

    f32x4 acc[4][4];
    #pragma unroll
    for (int i = 0; i < 4; ++i)
        #pragma unroll
        for (int j = 0; j < 4; ++j) acc[i][j] = (f32x4){0.f, 0.f, 0.f, 0.f};

    for (int k0 = 0; k0 < K; k0 += 64) {
        #pragma unroll
        for (int i = 0; i < 4; ++i) {
            const int seg = wid * 4 + i;
            const int row = seg * 8 + lr;
            gload16(A16 + (size_t)(m0 + row) * K + k0 + swz, &As[seg * 8][0]);
            gload16(Bt  + (size_t)(n0 + row) * K + k0 + swz, &Bs[seg * 8][0]);
        }
        __syncthreads();
        #pragma unroll
        for (int ks = 0; ks < 2; ++ks) {
            const int bc = (ks * 64 + fg * 16) ^ ((fr & 7) << 4);   // swizzled byte col
            short8v a[4], b[4];
            #pragma unroll
            for (int mi = 0; mi < 4; ++mi) {
                const int row = wr + mi * 16 + fr;
                a[mi] = *(const short8v*)((const char*)&As[0][0] + row * 128 + bc);
            }
            #pragma unroll
            for (int ni = 0; ni < 4; ++ni) {
                const int row = wc + ni * 16 + fr;
                b[ni] = *(const short8v*)((const char*)&Bs[0][0] + row * 128 + bc);
            }
            #pragma unroll
            for (int mi = 0; mi < 4; ++mi)
                #pragma unroll
                for (int ni = 0; ni < 4; ++ni)
                    acc[mi][ni] = __builtin_amdgcn_mfma_f32_16x16x32_bf16(
                            a[mi], b[ni], acc[mi][ni], 0, 0, 0);
        }
        __syncthreads();
    }
    float s = 0.f, bb = 0.f;
    if (EPI == 1 || EPI == 3) { s = sp[0]; bb = bp[0]; }
    #pragma unroll
    for (int mi = 0; mi < 4; ++mi) {
        #pragma unroll
        for (int r = 0; r < 4; ++r) {
            const int row = m0 + wr + mi * 16 + fg * 4 + r;
            #pragma unroll
            for (int ni = 0; ni < 4; ++ni) {
                const int col = n0 + wc + ni * 16 + fr;
                float v = acc[mi][ni][r];
                const size_t off = (size_t)row * N + col;
                if (EPI == 1) {
                    const float rl = fmaxf(v, 0.f);
                    Cf[off] = s * rl * rl + bb;
                } else if (EPI == 2) {
                    Cf[off] = v + R[off];
                } else {
                    const float rl = fmaxf(v, 0.f);
                    Cb[off] = f2b(s * rl * rl + bb);
                }
            }
        }
    }
}

// ================= small-A MFMA GEMM for DFT stages (bf16 in/out) =================
// C[rho][n] = sum_k A[rho][k] * B[k][n]; EPI: 0 write, 1 accumulate into C (bf16 RMW)
template<int EPI>
__global__ __launch_bounds__(256) void gemm_dft(
        const ushort* __restrict__ Ag, int Apitch,
        const ushort* __restrict__ Bv, int BzDiv, long BzA, long BzB, int Brs,
        int Bsplit, long BplOff, int Kreal, int Ksteps,
        ushort* __restrict__ Cv, int CzDiv, long CzA, long CzB, int Crs,
        int Csplit, long CplOff, int Climit, int ntiles, int mtiles)
{
    __shared__ ushort As[128][72];
    __shared__ ushort Bs[128][72];
    const int t = threadIdx.x;
    const int per_z = ntiles * mtiles;
    const int z = blockIdx.x / per_z;
    const int rem = blockIdx.x % per_z;
    const int mt = rem % mtiles;
    const int nt = rem / mtiles;
    const int col0 = nt * 128;
    const long Bzbase = (long)(z / BzDiv) * BzA + (long)(z % BzDiv) * BzB;
    const long Czbase = (long)(z / CzDiv) * CzA + (long)(z % CzDiv) * CzB;
    const int lane = t & 63, wid = t >> 6;
    const int wr = (wid >> 1) * 64, wc = (wid & 1) * 64;
    const int fr = lane & 15, fg = lane >> 4;

    f32x4 acc[4][4];
    #pragma unroll
    for (int i = 0; i < 4; ++i)
        #pragma unroll
        for (int j = 0; j < 4; ++j) acc[i][j] = (f32x4){0.f, 0.f, 0.f, 0.f};

    for (int step = 0; step < Ksteps; ++step) {
        const int k0 = step * 64;
        #pragma unroll
        for (int i = 0; i < 4; ++i) {
            const int id = t + 256 * i;
            const int r = id >> 3, j = (id & 7) * 8;
            *(short8v*)&As[r][j] = *(const short8v*)(Ag + (size_t)(mt * 128 + r) * Apitch + k0 + j);
        }
        // stage B slice transposed into Bs[n][k], kblk XOR-swizzled by (n>>3)&7
        #pragma unroll
        for (int i = 0; i < 2; ++i) {
            const int kp = (t >> 4) + 16 * i;     // k-pair 0..31
            const int np = t & 15;                // n-chunk (8 cols)
            const int kg0 = k0 + 2 * kp;
            ushort u0[8] = {0,0,0,0,0,0,0,0}, u1[8] = {0,0,0,0,0,0,0,0};
            if (kg0 < Kreal) {
                const long roff = Bzbase
                        + (kg0 < Bsplit ? (long)kg0 * Brs : BplOff + (long)(kg0 - Bsplit) * Brs)
                        + col0 + np * 8;
                const short8v tv = *(const short8v*)(Bv + roff);
                #pragma unroll
                for (int jj = 0; jj < 8; ++jj) u0[jj] = (ushort)tv[jj];
            }
            if (kg0 + 1 < Kreal) {
                const int kg1 = kg0 + 1;
                const long roff = Bzbase
                        + (kg1 < Bsplit ? (long)kg1 * Brs : BplOff + (long)(kg1 - Bsplit) * Brs)
                        + col0 + np * 8;
                const short8v tv = *(const short8v*)(Bv + roff);
                #pragma unroll
                for (int jj = 0; jj < 8; ++jj) u1[jj] = (ushort)tv[jj];
            }
            const int blk = (kp >> 2) ^ (np & 7);
            #pragma unroll
            for (int jj = 0; jj < 8; ++jj) {
                const int n = np * 8 + jj;
                ushort2 pr; pr.x = u0[jj]; pr.y = u1[jj];
                *(ushort2*)&Bs[n][blk * 8 + ((2 * kp) & 7)] = pr;
            }
        }
        __syncthreads();
        #pragma unroll
        for (int ks = 0; ks < 2; ++ks) {
            const int koff = ks * 32 + fg * 8;
            short8v a[4], b[4];
            #pragma unroll
            for (int mi = 0; mi < 4; ++mi) a[mi] = *(const short8v*)&As[wr + mi * 16 + fr][koff];
            #pragma unroll
            for (int ni = 0; ni < 4; ++ni) {
                const int n = wc + ni * 16 + fr;
                const int blk = (koff >> 3) ^ ((n >> 3) & 7);
                b[ni] = *(const short8v*)&Bs[n][blk * 8];
            }
            #pragma unroll
            for (int mi = 0; mi < 4; ++mi)
                #pragma unroll
                for (int ni = 0; ni < 4; ++ni)
                    acc[mi][ni] = __builtin_amdgcn_mfma_f32_16x16x32_bf16(
                            a[mi], b[ni], acc[mi][ni], 0, 0, 0);
        }
        __syncthreads();
    }
    #pragma unroll
    for (int mi = 0; mi < 4; ++mi) {
        #pragma unroll
        for (int rq = 0; rq < 4; ++rq) {
            const int rho = mt * 128 + wr + mi * 16 + fg * 4 + rq;
            if (rho >= Climit) continue;
            const long rbase = Czbase
                    + (rho < Csplit ? (long)rho * Crs : CplOff + (long)(rho - Csplit) * Crs);
            #pragma unroll
            for (int ni = 0; ni < 4; ++ni) {
                const long caddr = rbase + col0 + wc + ni * 16 + fr;
                float v = acc[mi][ni][rq];
                if (EPI == 1) v += b2f(Cv[caddr]);
                Cv[caddr] = f2b(v);
            }
        }
    }
}

// ================= block-diagonal complex MLP via MFMA (gload_lds staged) =================
template<int SECOND>
__global__ __launch_bounds__(256) void gemm_bmm(
        ushort* __restrict__ F2, ushort* __restrict__ G1,
        const ushort* __restrict__ Wc, const float* __restrict__ bias,
        const float* __restrict__ s0p, const float* __restrict__ b0p,
        const float* __restrict__ s1p, const float* __restrict__ b1p)
{
    const int MT = 40;
    const int wg = blockIdx.x;
    const int mt = wg % MT;
    const int n  = (wg / MT) & 7;
    const int bl = wg / (MT * 8);
    const long FB = (long)bl * PERB2;
    const long GB = ((long)(bl * 8 + n)) * 5100 * 128;
    const int r0 = mt * 128;
    __shared__ ushort As[128][64];
    __shared__ ushort Ws[128][64];
    const int t = threadIdx.x;
    const int lane = t & 63, wid = t >> 6;
    const int wr = (wid >> 1) * 64, wc = (wid & 1) * 64;
    const int fr = lane & 15, fg = lane >> 4;
    const int lr = lane >> 3;
    const int swz = ((lane & 7) ^ lr) * 8;

    f32x4 acc[4][4];
    #pragma unroll
    for (int i = 0; i < 4; ++i)
        #pragma unroll
        for (int j = 0; j < 4; ++j) acc[i][j] = (f32x4){0.f, 0.f, 0.f, 0.f};

    for (int step = 0; step < 2; ++step) {
        // rows beyond 5100 load garbage (within allocated ws); epilogue guards writes
        #pragma unroll
        for (int i = 0; i < 4; ++i) {
            const int seg = wid * 4 + i;
            const int row = seg * 8 + lr;
            const long r = r0 + row;
            const ushort* srcA = SECOND
                ? (G1 + GB + r * 128 + step * 64 + swz)
                : (F2 + FB + (step ? PL : 0) + r * 512 + n * 64 + swz);
            gload16(srcA, &As[seg * 8][0]);
            gload16(Wc + ((long)n << 14) + (long)row * 128 + step * 64 + swz, &Ws[seg * 8][0]);
        }
        __syncthreads();
        #pragma unroll
        for (int ks = 0; ks < 2; ++ks) {
            const int bc = (ks * 64 + fg * 16) ^ ((fr & 7) << 4);
            short8v a[4], b[4];
            #pragma unroll
            for (int mi = 0; mi < 4; ++mi) {
                const int row = wr + mi * 16 + fr;
                a[mi] = *(const short8v*)((const char*)&As[0][0] + row * 128 + bc);
            }
            #pragma unroll
            for (int ni = 0; ni < 4; ++ni) {
                const int row = wc + ni * 16 + fr;
                b[ni] = *(const short8v*)((const char*)&Ws[0][0] + row * 128 + bc);
            }
            #pragma unroll
            for (int mi = 0; mi < 4; ++mi)
                #pragma unroll
                for (int ni = 0; ni < 4; ++ni)
                    acc[mi][ni] = __builtin_amdgcn_mfma_f32_16x16x32_bf16(
                            a[mi], b[ni], acc[mi][ni], 0, 0, 0);
        }
        __syncthreads();
    }
    #pragma unroll
    for (int mi = 0; mi < 4; ++mi) {
        #pragma unroll
        for (int rq = 0; rq < 4; ++rq) {
            const int r = r0 + wr + mi * 16 + fg * 4 + rq;
            if (r >= 5100) continue;
            #pragma unroll
            for (int ni = 0; ni < 4; ++ni) {
                const int j = wc + ni * 16 + fr;
                float u = acc[mi][ni][rq] + bias[(j < 64 ? 0 : 512) + n * 64 + (j & 63)];
                if (!SECOND) {
                    const float s  = (j < 64) ? s0p[0] : s1p[0];
                    const float bb = (j < 64) ? b0p[0] : b1p[0];
                    const float rl = fmaxf(u, 0.f);
                    G1[GB + (long)r * 128 + j] = f2b(s * rl * rl + bb);
                } else {
                    const long ma = FB + (j < 64 ? 0 : PL) + (long)r * 512 + n * 64 + (j & 63);
                    F2[ma] = f2b(u * b2f(F2[ma]));
                }
            }
        }
    }
}

// ================= launcher =================
extern "C" void kernel_launch(void* const* d_in, const int* in_sizes, int n_in,
                              void* d_out, int out_size, void* d_ws, size_t ws_size,
                              hipStream_t stream) {
    (void)in_sizes; (void)n_in; (void)out_size;
    const float* x        = (const float*)d_in[0];
    const float* ln1_g    = (const float*)d_in[1];
    const float* ln1_b    = (const float*)d_in[2];
    const float* pw1_w    = (const float*)d_in[3];
    const float* act1_s   = (const float*)d_in[4];
    const float* act1_b   = (const float*)d_in[5];
    const float* w1       = (const float*)d_in[6];
    const float* w11      = (const float*)d_in[7];
    const float* b1       = (const float*)d_in[8];
    const float* w2       = (const float*)d_in[9];
    const float* w22      = (const float*)d_in[10];
    const float* b2       = (const float*)d_in[11];
    const float* actr_s   = (const float*)d_in[12];
    const float* actr_b   = (const float*)d_in[13];
    const float* acti_s   = (const float*)d_in[14];
    const float* acti_b   = (const float*)d_in[15];
    const float* pw2_w    = (const float*)d_in[16];
    const float* ln2_g    = (const float*)d_in[17];
    const float* ln2_b    = (const float*)d_in[18];
    const float* fc1_w    = (const float*)d_in[19];
    const float* mlp_s    = (const float*)d_in[20];
    const float* mlp_b    = (const float*)d_in[21];
    const float* fc2_w    = (const float*)d_in[22];
    float* out = (float*)d_out;
    float* ws  = (float*)d_ws;

    const size_t HBUF_F = 40960000ull;          // h16 region (bf16 uses half)
    const size_t MATS_F = 610000ull;
    const size_t ws_floats = ws_size / 4;
    int CB = 4;                                 // keep temps (CB*PERB2*2B) L3-resident
    while (CB > 1 && HBUF_F + (size_t)CB * (size_t)PERB2 + MATS_F > ws_floats) CB >>= 1;

    float* hbuf = ws;
    ushort* h16 = (ushort*)hbuf;                 // [80000][512] bf16
    ushort* tA16 = (ushort*)(ws + HBUF_F);       // CB*PERB2 ushorts
    ushort* tB16 = tA16 + (size_t)CB * PERB2;
    ushort* mats = tB16 + (size_t)CB * PERB2;
    ushort* A1m  = mats;
    ushort* A2m  = A1m + 16384;
    ushort* A4m  = A2m + 65536;
    ushort* A5m  = A4m + 65536;
    ushort* Wc1  = A5m + 16384;
    ushort* Wc2  = Wc1 + 131072;
    ushort* wt1  = Wc2 + 131072;
    ushort* wt2  = wt1 + 131072;
    ushort* wtf1 = wt2 + 131072;
    ushort* wtf2 = wtf1 + 262144;

    ushort* y16 = (ushort*)out;                          // LN1 out (scratch until pw2)
    ushort* y2  = (ushort*)hbuf;                         // LN2 out (h16 dead after pw2)
    ushort* m1h = (ushort*)(hbuf + 10240000ull);         // MLP hidden chunk

    build_A1<<<64, 256, 0, stream>>>(A1m);
    build_A2<0><<<256, 256, 0, stream>>>(A2m);
    build_A2<1><<<256, 256, 0, stream>>>(A4m);
    build_A5<<<64, 256, 0, stream>>>(A5m);
    build_wc<<<512, 256, 0, stream>>>(w1, w11, Wc1);
    build_wc<<<512, 256, 0, stream>>>(w2, w22, Wc2);
    wtrans<<<(131072 + 255) / 256, 256, 0, stream>>>(pw1_w, wt1, DIM, MED);
    wtrans<<<(131072 + 255) / 256, 256, 0, stream>>>(pw2_w, wt2, MED, DIM);
    wtrans<<<(262144 + 255) / 256, 256, 0, stream>>>(fc1_w, wtf1, DIM, 1024);
    wtrans<<<(262144 + 255) / 256, 256, 0, stream>>>(fc2_w, wtf2, 1024, DIM);

    // ---- token mixer ----
    ln_fast<<<NPOS / 4, 256, 0, stream>>>(x, ln1_g, ln1_b, y16);
    gemm_mfma<3><<<(NPOS / 128) * (MED / 128), 256, 0, stream>>>(
            y16, wt1, nullptr, h16, nullptr, act1_s, act1_b, NPOS, MED, DIM);

    for (int b0 = 0; b0 < 8; b0 += CB) {
        ushort* hchunk = h16 + (size_t)b0 * (SZ * SZ * MED);
        // K1: rfft along W -> tA
        gemm_dft<0><<<CB * 100 * 4, 256, 0, stream>>>(
                A1m, 128, hchunk, 1, 51200, 0, 512, 100, 0, 100, 2,
                tA16, 100, PERB2, HROW, 512, 51, PL, 102, 4, 1);
        // K2: forward DFT along H: tA -> tB
        gemm_dft<0><<<CB * 408, 256, 0, stream>>>(
                A2m, 256, tA16, 1, PERB2, 0, HROW, 100, PL, 200, 4,
                tB16, 1, PERB2, 0, HROW, 100, PL, 200, 204, 2);
        // bmm layer 1: F2 -> G1 (=tA)
        gemm_bmm<0><<<CB * 320, 256, 0, stream>>>(
                tB16, tA16, Wc1, b1, actr_s, actr_b, acti_s, acti_b);
        // bmm layer 2: G1, x F2 -> F2 in place
        gemm_bmm<1><<<CB * 320, 256, 0, stream>>>(
                tB16, tA16, Wc2, b2, nullptr, nullptr, nullptr, nullptr);
        // K4: inverse DFT along H: tB -> tA
        gemm_dft<0><<<CB * 408, 256, 0, stream>>>(
                A4m, 256, tB16, 1, PERB2, 0, HROW, 100, PL, 200, 4,
                tA16, 1, PERB2, 0, HROW, 100, PL, 200, 204, 2);
        // K5: irfft along W + skip accumulate into bf16 h
        gemm_dft<1><<<CB * 100 * 4, 256, 0, stream>>>(
                A5m, 128, tA16, 100, PERB2, HROW, 512, 51, PL, 102, 2,
                hchunk, 1, 51200, 0, 512, 100, 0, 100, 4, 1);
    }

    gemm_mfma<2><<<(NPOS / 128) * (DIM / 128), 256, 0, stream>>>(
            h16, wt2, out, nullptr, x, nullptr, nullptr, NPOS, DIM, MED);

    // ---- MLP branch ----
    ln_fast<<<NPOS / 4, 256, 0, stream>>>(out, ln2_g, ln2_b, y2);
    for (int ch = 0; ch < 5; ++ch) {
        const ushort* yc = y2 + (size_t)ch * 16000 * DIM;
        float* oc = out + (size_t)ch * 16000 * DIM;
        gemm_mfma<3><<<(16000 / 128) * (1024 / 128), 256, 0, stream>>>(
                yc, wtf1, nullptr, m1h, nullptr, mlp_s, mlp_b, 16000, 1024, DIM);
        gemm_mfma<2><<<(16000 / 128) * (DIM / 128), 256, 0, stream>>>(
                m1h, wtf2, oc, nullptr, oc, nullptr, nullptr, 16000, DIM, 1024);
    }
}

// Round 8
// 772.263 us; speedup vs baseline: 7.6654x; 1.0062x over previous
//
#include <hip/hip_runtime.h>
#include <math.h>

#define SZ    100
#define FILT  51
#define DIM   256
#define MED   512
#define NPOS  80000

#define PERB2 5222400ll          // 2*100*51*512 elems per batch (stacked R/I)
#define PL    2611200ll          // plane stride (100*51*512)
#define HROW  26112              // 51*512

typedef __attribute__((ext_vector_type(8))) short short8v;
typedef __attribute__((ext_vector_type(4))) float f32x4;

__device__ __forceinline__ ushort f2b(float f) {
    union { float f; unsigned u; } x; x.f = f;
    unsigned r = (x.u + 0x7fffu + ((x.u >> 16) & 1u)) >> 16;
    return (ushort)r;
}
__device__ __forceinline__ float b2f(ushort u) {
    union { float f; unsigned u; } x; x.u = ((unsigned)u) << 16;
    return x.f;
}

// direct global->LDS, 16B per lane; dst must be wave-uniform base (lane*16 implied)
__device__ __forceinline__ void gload16(const ushort* g, ushort* l) {
    __builtin_amdgcn_global_load_lds(
        (const __attribute__((address_space(1))) void*)g,
        (__attribute__((address_space(3))) void*)l, 16, 0, 0);
}

#define DPI 3.14159265358979323846

// ================= builders =================
__global__ void build_A1(ushort* __restrict__ A) {          // [128][128]
    const int id = blockIdx.x * 256 + threadIdx.x;
    const int rho = id >> 7, w = id & 127;
    float v = 0.f;
    if (w < SZ) {
        if (rho < FILT)          { int m = (rho * w) % SZ;          v =  0.01f * (float)cos(2.0 * DPI * m / SZ); }
        else if (rho < 2 * FILT) { int m = ((rho - FILT) * w) % SZ; v = -0.01f * (float)sin(2.0 * DPI * m / SZ); }
    }
    A[id] = f2b(v);
}

template<int INV>
__global__ void build_A2(ushort* __restrict__ A) {          // [256][256]
    const int id = blockIdx.x * 256 + threadIdx.x;
    const int rho = id >> 8, kk = id & 255;
    float v = 0.f;
    const double sgn = INV ? -1.0 : 1.0;
    if (rho < SZ) {
        if (kk < SZ)           { int m = (rho * kk) % SZ;        v = (float)cos(2.0 * DPI * m / SZ); }
        else if (kk < 2 * SZ)  { int m = (rho * (kk - SZ)) % SZ; v = (float)(sgn * sin(2.0 * DPI * m / SZ)); }
    } else if (rho < 2 * SZ) {
        const int i = rho - SZ;
        if (kk < SZ)           { int m = (i * kk) % SZ;          v = (float)(-sgn * sin(2.0 * DPI * m / SZ)); }
        else if (kk < 2 * SZ)  { int m = (i * (kk - SZ)) % SZ;   v = (float)cos(2.0 * DPI * m / SZ); }
    }
    A[id] = f2b(v);
}

__global__ void build_A5(ushort* __restrict__ A) {          // [128][128]
    const int id = blockIdx.x * 256 + threadIdx.x;
    const int w = id >> 7, kk = id & 127;
    float v = 0.f;
    if (w < SZ) {
        if (kk < FILT) {
            const float wgt = (kk == 0 || kk == FILT - 1) ? 0.01f : 0.02f;
            int m = (w * kk) % SZ; v = wgt * (float)cos(2.0 * DPI * m / SZ);
        } else if (kk < 2 * FILT) {
            const int f = kk - FILT;
            const float wgt = (f == 0 || f == FILT - 1) ? 0.01f : 0.02f;
            int m = (w * f) % SZ; v = -wgt * (float)sin(2.0 * DPI * m / SZ);
        }
    }
    A[id] = f2b(v);
}

// combined block weights, out-major: Wc[n][j(out 0..127)][i(in 0..127)]
__global__ void build_wc(const float* __restrict__ wA, const float* __restrict__ wB,
                         ushort* __restrict__ Wc) {
    const int id = blockIdx.x * 256 + threadIdx.x;          // 131072
    const int n = id >> 14, j = (id >> 7) & 127, i = id & 127;
    float v;
    if (j < 64) v = (i < 64) ? wA[((0 * 8 + n) * 64 + i) * 64 + j]
                             : wA[((1 * 8 + n) * 64 + (i - 64)) * 64 + j];
    else {
        const int jp = j - 64;
        v = (i < 64) ? wB[((1 * 8 + n) * 64 + i) * 64 + jp]
                     : wB[((0 * 8 + n) * 64 + (i - 64)) * 64 + jp];
    }
    Wc[id] = f2b(v);
}

__global__ void wtrans(const float* __restrict__ W, ushort* __restrict__ Wt, int K, int N) {
    const int idx = blockIdx.x * 256 + threadIdx.x;
    if (idx < N * K) {
        const int n = idx / K, k = idx % K;
        Wt[idx] = f2b(W[(size_t)k * N + n]);
    }
}

// ================= fast LayerNorm: one wave per 256-elem row =================
__global__ __launch_bounds__(256) void ln_fast(const float* __restrict__ x,
        const float* __restrict__ g, const float* __restrict__ b, ushort* __restrict__ y)
{
    const int row = blockIdx.x * 4 + (threadIdx.x >> 6);
    const int lane = threadIdx.x & 63;
    const float4 v = *(const float4*)(x + (size_t)row * DIM + lane * 4);
    float s  = v.x + v.y + v.z + v.w;
    float s2 = v.x * v.x + v.y * v.y + v.z * v.z + v.w * v.w;
    #pragma unroll
    for (int off = 32; off > 0; off >>= 1) {
        s  += __shfl_xor(s, off, 64);
        s2 += __shfl_xor(s2, off, 64);
    }
    const float mu  = s * (1.0f / DIM);
    const float var = s2 * (1.0f / DIM) - mu * mu;
    const float rs  = rsqrtf(var + 1e-5f);
    const float4 gv = *(const float4*)(g + lane * 4);
    const float4 bv = *(const float4*)(b + lane * 4);
    ushort4 o;
    o.x = f2b((v.x - mu) * rs * gv.x + bv.x);
    o.y = f2b((v.y - mu) * rs * gv.y + bv.y);
    o.z = f2b((v.z - mu) * rs * gv.z + bv.z);
    o.w = f2b((v.w - mu) * rs * gv.w + bv.w);
    *(ushort4*)(y + (size_t)row * DIM + lane * 4) = o;
}

// ================= dense bf16 MFMA GEMM, global_load_lds + XOR-swizzled LDS =================
// A bf16 [M][K], Bt bf16 [N][K]; EPI: 1 star_relu->fp32, 2 +R->fp32, 3 star_relu->bf16
template<int EPI>
__global__ __launch_bounds__(256) void gemm_mfma(
        const ushort* __restrict__ A16, const ushort* __restrict__ Bt,
        float* __restrict__ Cf, ushort* __restrict__ Cb,
        const float* __restrict__ R, const float* __restrict__ sp, const float* __restrict__ bp,
        int M, int N, int K)
{
    __shared__ ushort As[128][64];   // linear rows (128B); data pre-swizzled at source
    __shared__ ushort Bs[128][64];
    const int t = threadIdx.x;
    const int nwg = gridDim.x;
    const int orig = blockIdx.x;
    const int q = nwg >> 3, rr8 = nwg & 7;
    const int xcd = orig & 7, lo = orig >> 3;
    const int wg = (xcd < rr8 ? xcd * (q + 1) : rr8 * (q + 1) + (xcd - rr8) * q) + lo;
    const int NX = N >> 7;
    const int by = wg / NX, bx = wg % NX;
    const int m0 = by * 128, n0 = bx * 128;

    const int lane = t & 63;
    const int wid = t >> 6;
    const int wr = (wid >> 1) * 64, wc = (wid & 1) * 64;
    const int fr = lane & 15, fg = lane >> 4;
    const int lr = lane >> 3;                          // row-in-segment 0..7
    const int swz = ((lane & 7) ^ lr) * 8;             // inverse-swizzled source col (elems)

    f32x4 acc[4][4];
    #pragma unroll
    for (int i = 0; i < 4; ++i)
        #pragma unroll
        for (int j = 0; j < 4; ++j) acc[i][j] = (f32x4){0.f, 0.f, 0.f, 0.f};

    for (int k0 = 0; k0 < K; k0 += 64) {
        #pragma unroll
        for (int i = 0; i < 4; ++i) {
            const int seg = wid * 4 + i;
            const int row = seg * 8 + lr;
            gload16(A16 + (size_t)(m0 + row) * K + k0 + swz, &As[seg * 8][0]);
            gload16(Bt  + (size_t)(n0 + row) * K + k0 + swz, &Bs[seg * 8][0]);
        }
        __syncthreads();
        #pragma unroll
        for (int ks = 0; ks < 2; ++ks) {
            const int bc = (ks * 64 + fg * 16) ^ ((fr & 7) << 4);   // swizzled byte col
            short8v a[4], b[4];
            #pragma unroll
            for (int mi = 0; mi < 4; ++mi) {
                const int row = wr + mi * 16 + fr;
                a[mi] = *(const short8v*)((const char*)&As[0][0] + row * 128 + bc);
            }
            #pragma unroll
            for (int ni = 0; ni < 4; ++ni) {
                const int row = wc + ni * 16 + fr;
                b[ni] = *(const short8v*)((const char*)&Bs[0][0] + row * 128 + bc);
            }
            #pragma unroll
            for (int mi = 0; mi < 4; ++mi)
                #pragma unroll
                for (int ni = 0; ni < 4; ++ni)
                    acc[mi][ni] = __builtin_amdgcn_mfma_f32_16x16x32_bf16(
                            a[mi], b[ni], acc[mi][ni], 0, 0, 0);
        }
        __syncthreads();
    }
    float s = 0.f, bb = 0.f;
    if (EPI == 1 || EPI == 3) { s = sp[0]; bb = bp[0]; }
    #pragma unroll
    for (int mi = 0; mi < 4; ++mi) {
        #pragma unroll
        for (int r = 0; r < 4; ++r) {
            const int row = m0 + wr + mi * 16 + fg * 4 + r;
            #pragma unroll
            for (int ni = 0; ni < 4; ++ni) {
                const int col = n0 + wc + ni * 16 + fr;
                float v = acc[mi][ni][r];
                const size_t off = (size_t)row * N + col;
                if (EPI == 1) {
                    const float rl = fmaxf(v, 0.f);
                    Cf[off] = s * rl * rl + bb;
                } else if (EPI == 2) {
                    Cf[off] = v + R[off];
                } else {
                    const float rl = fmaxf(v, 0.f);
                    Cb[off] = f2b(s * rl * rl + bb);
                }
            }
        }
    }
}

// ================= fused MLP: out += fc2(star_relu(fc1(y2))) =================
// y2 [80000][256] bf16; W1 = wtf1 [1024][256]; W2 = wtf2 [256][1024]; out fp32 (+=)
// 512 thr = 8 waves (2M x 4N of 64x32); 128-row tile; 8 hidden chunks of 128.
__global__ __launch_bounds__(512, 2) void mlp_fused(
        const ushort* __restrict__ y2, const ushort* __restrict__ W1,
        const ushort* __restrict__ W2, float* __restrict__ out,
        const float* __restrict__ sp, const float* __restrict__ bp)
{
    __shared__ ushort As[128][64];    // y2 k-slice (staged per GEMM1 step)
    __shared__ ushort Bs[128][64];    // W1/W2 slice (staged per step)
    __shared__ ushort Ms[128][128];   // hidden chunk bf16, swizzled within 128B sub-rows
    const int t = threadIdx.x;
    const int lane = t & 63, wid = t >> 6;
    const int m0 = blockIdx.x * 128;
    const int wr = (wid >> 2) * 64;          // wave row base
    const int wn = (wid & 3) * 32;           // wave col base (within 128)
    const int fr = lane & 15, fg = lane >> 4;
    const int lr = lane >> 3;
    const int swz = ((lane & 7) ^ lr) * 8;
    const float s = sp[0], bb = bp[0];

    f32x4 oacc[2][4][2];
    #pragma unroll
    for (int nh = 0; nh < 2; ++nh)
        #pragma unroll
        for (int mi = 0; mi < 4; ++mi)
            #pragma unroll
            for (int ni = 0; ni < 2; ++ni) oacc[nh][mi][ni] = (f32x4){0.f, 0.f, 0.f, 0.f};

    for (int hk = 0; hk < 8; ++hk) {
        // ---- GEMM1: mchunk[128x128] = y2tile[128x256] @ W1[hk*128..][256]^T ----
        f32x4 acc1[4][2];
        #pragma unroll
        for (int mi = 0; mi < 4; ++mi)
            #pragma unroll
            for (int ni = 0; ni < 2; ++ni) acc1[mi][ni] = (f32x4){0.f, 0.f, 0.f, 0.f};
        for (int step = 0; step < 4; ++step) {
            const int k0 = step * 64;
            #pragma unroll
            for (int i = 0; i < 2; ++i) {
                const int seg = wid * 2 + i;
                const int row = seg * 8 + lr;
                gload16(y2 + (size_t)(m0 + row) * 256 + k0 + swz, &As[seg * 8][0]);
                gload16(W1 + (size_t)(hk * 128 + row) * 256 + k0 + swz, &Bs[seg * 8][0]);
            }
            __syncthreads();
            #pragma unroll
            for (int ks = 0; ks < 2; ++ks) {
                const int bc = (ks * 64 + fg * 16) ^ ((fr & 7) << 4);
                short8v a[4], b[2];
                #pragma unroll
                for (int mi = 0; mi < 4; ++mi) {
                    const int row = wr + mi * 16 + fr;
                    a[mi] = *(const short8v*)((const char*)&As[0][0] + row * 128 + bc);
                }
                #pragma unroll
                for (int ni = 0; ni < 2; ++ni) {
                    const int row = wn + ni * 16 + fr;
                    b[ni] = *(const short8v*)((const char*)&Bs[0][0] + row * 128 + bc);
                }
                #pragma unroll
                for (int mi = 0; mi < 4; ++mi)
                    #pragma unroll
                    for (int ni = 0; ni < 2; ++ni)
                        acc1[mi][ni] = __builtin_amdgcn_mfma_f32_16x16x32_bf16(
                                a[mi], b[ni], acc1[mi][ni], 0, 0, 0);
            }
            __syncthreads();
        }
        // ---- star_relu -> Ms (bf16, swizzled: slot ^= row&7 within each 128B chunk) ----
        #pragma unroll
        for (int mi = 0; mi < 4; ++mi)
            #pragma unroll
            for (int ni = 0; ni < 2; ++ni)
                #pragma unroll
                for (int rq = 0; rq < 4; ++rq) {
                    const int row = wr + mi * 16 + fg * 4 + rq;
                    const int col = wn + ni * 16 + fr;
                    const float rl = fmaxf(acc1[mi][ni][rq], 0.f);
                    const int byte = row * 256 + ((col >> 6) << 7)
                            + ((((col >> 3) & 7) ^ (row & 7)) << 4) + (col & 7) * 2;
                    *(ushort*)((char*)&Ms[0][0] + byte) = f2b(s * rl * rl + bb);
                }
        // ---- GEMM2: oacc += Ms[128x128] @ W2[nh*128..][hk*128..] ----
        #pragma unroll
        for (int nh = 0; nh < 2; ++nh) {
            for (int step = 0; step < 2; ++step) {
                #pragma unroll
                for (int i = 0; i < 2; ++i) {
                    const int seg = wid * 2 + i;
                    const int row = seg * 8 + lr;
                    gload16(W2 + (size_t)(nh * 128 + row) * 1024 + hk * 128 + step * 64 + swz,
                            &Bs[seg * 8][0]);
                }
                __syncthreads();   // covers Ms writes (first iter) and Bs staging
                #pragma unroll
                for (int ks = 0; ks < 2; ++ks) {
                    const int bc = (ks * 64 + fg * 16) ^ ((fr & 7) << 4);
                    const int kloc2 = (step * 64 + ks * 32 + fg * 8) * 2;   // byte k within chunk
                    short8v a[4], b[2];
                    #pragma unroll
                    for (int mi = 0; mi < 4; ++mi) {
                        const int row = wr + mi * 16 + fr;
                        const int mb = row * 256 + (kloc2 & 128)
                                + ((((kloc2 >> 4) & 7) ^ (row & 7)) << 4);
                        a[mi] = *(const short8v*)((const char*)&Ms[0][0] + mb);
                    }
                    #pragma unroll
                    for (int ni = 0; ni < 2; ++ni) {
                        const int row = wn + ni * 16 + fr;
                        b[ni] = *(const short8v*)((const char*)&Bs[0][0] + row * 128 + bc);
                    }
                    #pragma unroll
                    for (int mi = 0; mi < 4; ++mi)
                        #pragma unroll
                        for (int ni = 0; ni < 2; ++ni)
                            oacc[nh][mi][ni] = __builtin_amdgcn_mfma_f32_16x16x32_bf16(
                                    a[mi], b[ni], oacc[nh][mi][ni], 0, 0, 0);
                }
                __syncthreads();
            }
        }
    }
    // ---- epilogue: out += oacc ----
    #pragma unroll
    for (int nh = 0; nh < 2; ++nh)
        #pragma unroll
        for (int mi = 0; mi < 4; ++mi)
            #pragma unroll
            for (int rq = 0; rq < 4; ++rq) {
                const int row = m0 + wr + mi * 16 + fg * 4 + rq;
                #pragma unroll
                for (int ni = 0; ni < 2; ++ni) {
                    const int col = nh * 128 + wn + ni * 16 + fr;
                    const size_t off = (size_t)row * 256 + col;
                    out[off] = oacc[nh][mi][ni][rq] + out[off];
                }
            }
}

// ================= small-A MFMA GEMM for DFT stages (bf16 in/out) =================
// C[rho][n] = sum_k A[rho][k] * B[k][n]; EPI: 0 write, 1 accumulate into C (bf16 RMW)
template<int EPI>
__global__ __launch_bounds__(256) void gemm_dft(
        const ushort* __restrict__ Ag, int Apitch,
        const ushort* __restrict__ Bv, int BzDiv, long BzA, long BzB, int Brs,
        int Bsplit, long BplOff, int Kreal, int Ksteps,
        ushort* __restrict__ Cv, int CzDiv, long CzA, long CzB, int Crs,
        int Csplit, long CplOff, int Climit, int ntiles, int mtiles)
{
    __shared__ ushort As[128][72];
    __shared__ ushort Bs[128][72];
    const int t = threadIdx.x;
    const int per_z = ntiles * mtiles;
    const int z = blockIdx.x / per_z;
    const int rem = blockIdx.x % per_z;
    const int mt = rem % mtiles;
    const int nt = rem / mtiles;
    const int col0 = nt * 128;
    const long Bzbase = (long)(z / BzDiv) * BzA + (long)(z % BzDiv) * BzB;
    const long Czbase = (long)(z / CzDiv) * CzA + (long)(z % CzDiv) * CzB;
    const int lane = t & 63, wid = t >> 6;
    const int wr = (wid >> 1) * 64, wc = (wid & 1) * 64;
    const int fr = lane & 15, fg = lane >> 4;

    f32x4 acc[4][4];
    #pragma unroll
    for (int i = 0; i < 4; ++i)
        #pragma unroll
        for (int j = 0; j < 4; ++j) acc[i][j] = (f32x4){0.f, 0.f, 0.f, 0.f};

    for (int step = 0; step < Ksteps; ++step) {
        const int k0 = step * 64;
        #pragma unroll
        for (int i = 0; i < 4; ++i) {
            const int id = t + 256 * i;
            const int r = id >> 3, j = (id & 7) * 8;
            *(short8v*)&As[r][j] = *(const short8v*)(Ag + (size_t)(mt * 128 + r) * Apitch + k0 + j);
        }
        // stage B slice transposed into Bs[n][k], kblk XOR-swizzled by (n>>3)&7
        #pragma unroll
        for (int i = 0; i < 2; ++i) {
            const int kp = (t >> 4) + 16 * i;     // k-pair 0..31
            const int np = t & 15;                // n-chunk (8 cols)
            const int kg0 = k0 + 2 * kp;
            ushort u0[8] = {0,0,0,0,0,0,0,0}, u1[8] = {0,0,0,0,0,0,0,0};
            if (kg0 < Kreal) {
                const long roff = Bzbase
                        + (kg0 < Bsplit ? (long)kg0 * Brs : BplOff + (long)(kg0 - Bsplit) * Brs)
                        + col0 + np * 8;
                const short8v tv = *(const short8v*)(Bv + roff);
                #pragma unroll
                for (int jj = 0; jj < 8; ++jj) u0[jj] = (ushort)tv[jj];
            }
            if (kg0 + 1 < Kreal) {
                const int kg1 = kg0 + 1;
                const long roff = Bzbase
                        + (kg1 < Bsplit ? (long)kg1 * Brs : BplOff + (long)(kg1 - Bsplit) * Brs)
                        + col0 + np * 8;
                const short8v tv = *(const short8v*)(Bv + roff);
                #pragma unroll
                for (int jj = 0; jj < 8; ++jj) u1[jj] = (ushort)tv[jj];
            }
            const int blk = (kp >> 2) ^ (np & 7);
            #pragma unroll
            for (int jj = 0; jj < 8; ++jj) {
                const int n = np * 8 + jj;
                ushort2 pr; pr.x = u0[jj]; pr.y = u1[jj];
                *(ushort2*)&Bs[n][blk * 8 + ((2 * kp) & 7)] = pr;
            }
        }
        __syncthreads();
        #pragma unroll
        for (int ks = 0; ks < 2; ++ks) {
            const int koff = ks * 32 + fg * 8;
            short8v a[4], b[4];
            #pragma unroll
            for (int mi = 0; mi < 4; ++mi) a[mi] = *(const short8v*)&As[wr + mi * 16 + fr][koff];
            #pragma unroll
            for (int ni = 0; ni < 4; ++ni) {
                const int n = wc + ni * 16 + fr;
                const int blk = (koff >> 3) ^ ((n >> 3) & 7);
                b[ni] = *(const short8v*)&Bs[n][blk * 8];
            }
            #pragma unroll
            for (int mi = 0; mi < 4; ++mi)
                #pragma unroll
                for (int ni = 0; ni < 4; ++ni)
                    acc[mi][ni] = __builtin_amdgcn_mfma_f32_16x16x32_bf16(
                            a[mi], b[ni], acc[mi][ni], 0, 0, 0);
        }
        __syncthreads();
    }
    #pragma unroll
    for (int mi = 0; mi < 4; ++mi) {
        #pragma unroll
        for (int rq = 0; rq < 4; ++rq) {
            const int rho = mt * 128 + wr + mi * 16 + fg * 4 + rq;
            if (rho >= Climit) continue;
            const long rbase = Czbase
                    + (rho < Csplit ? (long)rho * Crs : CplOff + (long)(rho - Csplit) * Crs);
            #pragma unroll
            for (int ni = 0; ni < 4; ++ni) {
                const long caddr = rbase + col0 + wc + ni * 16 + fr;
                float v = acc[mi][ni][rq];
                if (EPI == 1) v += b2f(Cv[caddr]);
                Cv[caddr] = f2b(v);
            }
        }
    }
}

// ================= block-diagonal complex MLP via MFMA (gload_lds staged) =================
template<int SECOND>
__global__ __launch_bounds__(256) void gemm_bmm(
        ushort* __restrict__ F2, ushort* __restrict__ G1,
        const ushort* __restrict__ Wc, const float* __restrict__ bias,
        const float* __restrict__ s0p, const float* __restrict__ b0p,
        const float* __restrict__ s1p, const float* __restrict__ b1p)
{
    const int MT = 40;
    const int wg = blockIdx.x;
    const int mt = wg % MT;
    const int n  = (wg / MT) & 7;
    const int bl = wg / (MT * 8);
    const long FB = (long)bl * PERB2;
    const long GB = ((long)(bl * 8 + n)) * 5100 * 128;
    const int r0 = mt * 128;
    __shared__ ushort As[128][64];
    __shared__ ushort Ws[128][64];
    const int t = threadIdx.x;
    const int lane = t & 63, wid = t >> 6;
    const int wr = (wid >> 1) * 64, wc = (wid & 1) * 64;
    const int fr = lane & 15, fg = lane >> 4;
    const int lr = lane >> 3;
    const int swz = ((lane & 7) ^ lr) * 8;

    f32x4 acc[4][4];
    #pragma unroll
    for (int i = 0; i < 4; ++i)
        #pragma unroll
        for (int j = 0; j < 4; ++j) acc[i][j] = (f32x4){0.f, 0.f, 0.f, 0.f};

    for (int step = 0; step < 2; ++step) {
        // rows beyond 5100 load garbage (within allocated ws); epilogue guards writes
        #pragma unroll
        for (int i = 0; i < 4; ++i) {
            const int seg = wid * 4 + i;
            const int row = seg * 8 + lr;
            const long r = r0 + row;
            const ushort* srcA = SECOND
                ? (G1 + GB + r * 128 + step * 64 + swz)
                : (F2 + FB + (step ? PL : 0) + r * 512 + n * 64 + swz);
            gload16(srcA, &As[seg * 8][0]);
            gload16(Wc + ((long)n << 14) + (long)row * 128 + step * 64 + swz, &Ws[seg * 8][0]);
        }
        __syncthreads();
        #pragma unroll
        for (int ks = 0; ks < 2; ++ks) {
            const int bc = (ks * 64 + fg * 16) ^ ((fr & 7) << 4);
            short8v a[4], b[4];
            #pragma unroll
            for (int mi = 0; mi < 4; ++mi) {
                const int row = wr + mi * 16 + fr;
                a[mi] = *(const short8v*)((const char*)&As[0][0] + row * 128 + bc);
            }
            #pragma unroll
            for (int ni = 0; ni < 4; ++ni) {
                const int row = wc + ni * 16 + fr;
                b[ni] = *(const short8v*)((const char*)&Ws[0][0] + row * 128 + bc);
            }
            #pragma unroll
            for (int mi = 0; mi < 4; ++mi)
                #pragma unroll
                for (int ni = 0; ni < 4; ++ni)
                    acc[mi][ni] = __builtin_amdgcn_mfma_f32_16x16x32_bf16(
                            a[mi], b[ni], acc[mi][ni], 0, 0, 0);
        }
        __syncthreads();
    }
    #pragma unroll
    for (int mi = 0; mi < 4; ++mi) {
        #pragma unroll
        for (int rq = 0; rq < 4; ++rq) {
            const int r = r0 + wr + mi * 16 + fg * 4 + rq;
            if (r >= 5100) continue;
            #pragma unroll
            for (int ni = 0; ni < 4; ++ni) {
                const int j = wc + ni * 16 + fr;
                float u = acc[mi][ni][rq] + bias[(j < 64 ? 0 : 512) + n * 64 + (j & 63)];
                if (!SECOND) {
                    const float s  = (j < 64) ? s0p[0] : s1p[0];
                    const float bb = (j < 64) ? b0p[0] : b1p[0];
                    const float rl = fmaxf(u, 0.f);
                    G1[GB + (long)r * 128 + j] = f2b(s * rl * rl + bb);
                } else {
                    const long ma = FB + (j < 64 ? 0 : PL) + (long)r * 512 + n * 64 + (j & 63);
                    F2[ma] = f2b(u * b2f(F2[ma]));
                }
            }
        }
    }
}

// ================= launcher =================
extern "C" void kernel_launch(void* const* d_in, const int* in_sizes, int n_in,
                              void* d_out, int out_size, void* d_ws, size_t ws_size,
                              hipStream_t stream) {
    (void)in_sizes; (void)n_in; (void)out_size;
    const float* x        = (const float*)d_in[0];
    const float* ln1_g    = (const float*)d_in[1];
    const float* ln1_b    = (const float*)d_in[2];
    const float* pw1_w    = (const float*)d_in[3];
    const float* act1_s   = (const float*)d_in[4];
    const float* act1_b   = (const float*)d_in[5];
    const float* w1       = (const float*)d_in[6];
    const float* w11      = (const float*)d_in[7];
    const float* b1       = (const float*)d_in[8];
    const float* w2       = (const float*)d_in[9];
    const float* w22      = (const float*)d_in[10];
    const float* b2       = (const float*)d_in[11];
    const float* actr_s   = (const float*)d_in[12];
    const float* actr_b   = (const float*)d_in[13];
    const float* acti_s   = (const float*)d_in[14];
    const float* acti_b   = (const float*)d_in[15];
    const float* pw2_w    = (const float*)d_in[16];
    const float* ln2_g    = (const float*)d_in[17];
    const float* ln2_b    = (const float*)d_in[18];
    const float* fc1_w    = (const float*)d_in[19];
    const float* mlp_s    = (const float*)d_in[20];
    const float* mlp_b    = (const float*)d_in[21];
    const float* fc2_w    = (const float*)d_in[22];
    float* out = (float*)d_out;
    float* ws  = (float*)d_ws;

    const size_t HBUF_F = 40960000ull;          // h16 region (bf16 uses half)
    const size_t MATS_F = 610000ull;
    const size_t ws_floats = ws_size / 4;
    int CB = 4;                                 // keep temps (CB*PERB2*2B) L3-resident
    while (CB > 1 && HBUF_F + (size_t)CB * (size_t)PERB2 + MATS_F > ws_floats) CB >>= 1;

    float* hbuf = ws;
    ushort* h16 = (ushort*)hbuf;                 // [80000][512] bf16
    ushort* tA16 = (ushort*)(ws + HBUF_F);       // CB*PERB2 ushorts
    ushort* tB16 = tA16 + (size_t)CB * PERB2;
    ushort* mats = tB16 + (size_t)CB * PERB2;
    ushort* A1m  = mats;
    ushort* A2m  = A1m + 16384;
    ushort* A4m  = A2m + 65536;
    ushort* A5m  = A4m + 65536;
    ushort* Wc1  = A5m + 16384;
    ushort* Wc2  = Wc1 + 131072;
    ushort* wt1  = Wc2 + 131072;
    ushort* wt2  = wt1 + 131072;
    ushort* wtf1 = wt2 + 131072;
    ushort* wtf2 = wtf1 + 262144;

    ushort* y16 = (ushort*)out;                          // LN1 out (scratch until pw2)
    ushort* y2  = (ushort*)hbuf;                         // LN2 out (h16 dead after pw2)

    build_A1<<<64, 256, 0, stream>>>(A1m);
    build_A2<0><<<256, 256, 0, stream>>>(A2m);
    build_A2<1><<<256, 256, 0, stream>>>(A4m);
    build_A5<<<64, 256, 0, stream>>>(A5m);
    build_wc<<<512, 256, 0, stream>>>(w1, w11, Wc1);
    build_wc<<<512, 256, 0, stream>>>(w2, w22, Wc2);
    wtrans<<<(131072 + 255) / 256, 256, 0, stream>>>(pw1_w, wt1, DIM, MED);
    wtrans<<<(131072 + 255) / 256, 256, 0, stream>>>(pw2_w, wt2, MED, DIM);
    wtrans<<<(262144 + 255) / 256, 256, 0, stream>>>(fc1_w, wtf1, DIM, 1024);
    wtrans<<<(262144 + 255) / 256, 256, 0, stream>>>(fc2_w, wtf2, 1024, DIM);

    // ---- token mixer ----
    ln_fast<<<NPOS / 4, 256, 0, stream>>>(x, ln1_g, ln1_b, y16);
    gemm_mfma<3><<<(NPOS / 128) * (MED / 128), 256, 0, stream>>>(
            y16, wt1, nullptr, h16, nullptr, act1_s, act1_b, NPOS, MED, DIM);

    for (int b0 = 0; b0 < 8; b0 += CB) {
        ushort* hchunk = h16 + (size_t)b0 * (SZ * SZ * MED);
        // K1: rfft along W -> tA
        gemm_dft<0><<<CB * 100 * 4, 256, 0, stream>>>(
                A1m, 128, hchunk, 1, 51200, 0, 512, 100, 0, 100, 2,
                tA16, 100, PERB2, HROW, 512, 51, PL, 102, 4, 1);
        // K2: forward DFT along H: tA -> tB
        gemm_dft<0><<<CB * 408, 256, 0, stream>>>(
                A2m, 256, tA16, 1, PERB2, 0, HROW, 100, PL, 200, 4,
                tB16, 1, PERB2, 0, HROW, 100, PL, 200, 204, 2);
        // bmm layer 1: F2 -> G1 (=tA)
        gemm_bmm<0><<<CB * 320, 256, 0, stream>>>(
                tB16, tA16, Wc1, b1, actr_s, actr_b, acti_s, acti_b);
        // bmm layer 2: G1, x F2 -> F2 in place
        gemm_bmm<1><<<CB * 320, 256, 0, stream>>>(
                tB16, tA16, Wc2, b2, nullptr, nullptr, nullptr, nullptr);
        // K4: inverse DFT along H: tB -> tA
        gemm_dft<0><<<CB * 408, 256, 0, stream>>>(
                A4m, 256, tB16, 1, PERB2, 0, HROW, 100, PL, 200, 4,
                tA16, 1, PERB2, 0, HROW, 100, PL, 200, 204, 2);
        // K5: irfft along W + skip accumulate into bf16 h
        gemm_dft<1><<<CB * 100 * 4, 256, 0, stream>>>(
                A5m, 128, tA16, 100, PERB2, HROW, 512, 51, PL, 102, 2,
                hchunk, 1, 51200, 0, 512, 100, 0, 100, 4, 1);
    }

    gemm_mfma<2><<<(NPOS / 128) * (DIM / 128), 256, 0, stream>>>(
            h16, wt2, out, nullptr, x, nullptr, nullptr, NPOS, DIM, MED);

    // ---- MLP branch: LN2 + fully-fused MLP (no hidden round-trip) ----
    ln_fast<<<NPOS / 4, 256, 0, stream>>>(out, ln2_g, ln2_b, y2);
    mlp_fused<<<NPOS / 128, 512, 0, stream>>>(y2, wtf1, wtf2, out, mlp_s, mlp_b);
}

// Round 9
// 731.378 us; speedup vs baseline: 8.0939x; 1.0559x over previous
//
#include <hip/hip_runtime.h>
#include <math.h>

#define SZ    100
#define FILT  51
#define DIM   256
#define MED   512
#define NPOS  80000

#define PERB2 5222400ll          // 2*100*51*512 elems per batch (stacked R/I)
#define PL    2611200ll          // plane stride (100*51*512)
#define HROW  26112              // 51*512

typedef __attribute__((ext_vector_type(8))) short short8v;
typedef __attribute__((ext_vector_type(4))) float f32x4;

__device__ __forceinline__ ushort f2b(float f) {
    union { float f; unsigned u; } x; x.f = f;
    unsigned r = (x.u + 0x7fffu + ((x.u >> 16) & 1u)) >> 16;
    return (ushort)r;
}
__device__ __forceinline__ float b2f(ushort u) {
    union { float f; unsigned u; } x; x.u = ((unsigned)u) << 16;
    return x.f;
}

// direct global->LDS, 16B per lane; dst must be wave-uniform base (lane*16 implied)
__device__ __forceinline__ void gload16(const ushort* g, ushort* l) {
    __builtin_amdgcn_global_load_lds(
        (const __attribute__((address_space(1))) void*)g,
        (__attribute__((address_space(3))) void*)l, 16, 0, 0);
}

#define DPI 3.14159265358979323846

// ================= builders =================
__global__ void build_A1(ushort* __restrict__ A) {          // [128][128]
    const int id = blockIdx.x * 256 + threadIdx.x;
    const int rho = id >> 7, w = id & 127;
    float v = 0.f;
    if (w < SZ) {
        if (rho < FILT)          { int m = (rho * w) % SZ;          v =  0.01f * (float)cos(2.0 * DPI * m / SZ); }
        else if (rho < 2 * FILT) { int m = ((rho - FILT) * w) % SZ; v = -0.01f * (float)sin(2.0 * DPI * m / SZ); }
    }
    A[id] = f2b(v);
}

template<int INV>
__global__ void build_A2(ushort* __restrict__ A) {          // [256][256]
    const int id = blockIdx.x * 256 + threadIdx.x;
    const int rho = id >> 8, kk = id & 255;
    float v = 0.f;
    const double sgn = INV ? -1.0 : 1.0;
    if (rho < SZ) {
        if (kk < SZ)           { int m = (rho * kk) % SZ;        v = (float)cos(2.0 * DPI * m / SZ); }
        else if (kk < 2 * SZ)  { int m = (rho * (kk - SZ)) % SZ; v = (float)(sgn * sin(2.0 * DPI * m / SZ)); }
    } else if (rho < 2 * SZ) {
        const int i = rho - SZ;
        if (kk < SZ)           { int m = (i * kk) % SZ;          v = (float)(-sgn * sin(2.0 * DPI * m / SZ)); }
        else if (kk < 2 * SZ)  { int m = (i * (kk - SZ)) % SZ;   v = (float)cos(2.0 * DPI * m / SZ); }
    }
    A[id] = f2b(v);
}

__global__ void build_A5(ushort* __restrict__ A) {          // [128][128]
    const int id = blockIdx.x * 256 + threadIdx.x;
    const int w = id >> 7, kk = id & 127;
    float v = 0.f;
    if (w < SZ) {
        if (kk < FILT) {
            const float wgt = (kk == 0 || kk == FILT - 1) ? 0.01f : 0.02f;
            int m = (w * kk) % SZ; v = wgt * (float)cos(2.0 * DPI * m / SZ);
        } else if (kk < 2 * FILT) {
            const int f = kk - FILT;
            const float wgt = (f == 0 || f == FILT - 1) ? 0.01f : 0.02f;
            int m = (w * f) % SZ; v = -wgt * (float)sin(2.0 * DPI * m / SZ);
        }
    }
    A[id] = f2b(v);
}

// combined block weights, out-major: Wc[n][j(out 0..127)][i(in 0..127)]
__global__ void build_wc(const float* __restrict__ wA, const float* __restrict__ wB,
                         ushort* __restrict__ Wc) {
    const int id = blockIdx.x * 256 + threadIdx.x;          // 131072
    const int n = id >> 14, j = (id >> 7) & 127, i = id & 127;
    float v;
    if (j < 64) v = (i < 64) ? wA[((0 * 8 + n) * 64 + i) * 64 + j]
                             : wA[((1 * 8 + n) * 64 + (i - 64)) * 64 + j];
    else {
        const int jp = j - 64;
        v = (i < 64) ? wB[((1 * 8 + n) * 64 + i) * 64 + jp]
                     : wB[((0 * 8 + n) * 64 + (i - 64)) * 64 + jp];
    }
    Wc[id] = f2b(v);
}

__global__ void wtrans(const float* __restrict__ W, ushort* __restrict__ Wt, int K, int N) {
    const int idx = blockIdx.x * 256 + threadIdx.x;
    if (idx < N * K) {
        const int n = idx / K, k = idx % K;
        Wt[idx] = f2b(W[(size_t)k * N + n]);
    }
}

// ================= fast LayerNorm: one wave per 256-elem row =================
__global__ __launch_bounds__(256) void ln_fast(const float* __restrict__ x,
        const float* __restrict__ g, const float* __restrict__ b, ushort* __restrict__ y)
{
    const int row = blockIdx.x * 4 + (threadIdx.x >> 6);
    const int lane = threadIdx.x & 63;
    const float4 v = *(const float4*)(x + (size_t)row * DIM + lane * 4);
    float s  = v.x + v.y + v.z + v.w;
    float s2 = v.x * v.x + v.y * v.y + v.z * v.z + v.w * v.w;
    #pragma unroll
    for (int off = 32; off > 0; off >>= 1) {
        s  += __shfl_xor(s, off, 64);
        s2 += __shfl_xor(s2, off, 64);
    }
    const float mu  = s * (1.0f / DIM);
    const float var = s2 * (1.0f / DIM) - mu * mu;
    const float rs  = rsqrtf(var + 1e-5f);
    const float4 gv = *(const float4*)(g + lane * 4);
    const float4 bv = *(const float4*)(b + lane * 4);
    ushort4 o;
    o.x = f2b((v.x - mu) * rs * gv.x + bv.x);
    o.y = f2b((v.y - mu) * rs * gv.y + bv.y);
    o.z = f2b((v.z - mu) * rs * gv.z + bv.z);
    o.w = f2b((v.w - mu) * rs * gv.w + bv.w);
    *(ushort4*)(y + (size_t)row * DIM + lane * 4) = o;
}

// ================= dense bf16 MFMA GEMM, global_load_lds + XOR-swizzled LDS =================
// A bf16 [M][K], Bt bf16 [N][K]; EPI: 1 star_relu->fp32, 2 +R->fp32, 3 star_relu->bf16
template<int EPI>
__global__ __launch_bounds__(256) void gemm_mfma(
        const ushort* __restrict__ A16, const ushort* __restrict__ Bt,
        float* __restrict__ Cf, ushort* __restrict__ Cb,
        const float* __restrict__ R, const float* __restrict__ sp, const float* __restrict__ bp,
        int M, int N, int K)
{
    __shared__ ushort As[128][64];   // linear rows (128B); data pre-swizzled at source
    __shared__ ushort Bs[128][64];
    const int t = threadIdx.x;
    const int nwg = gridDim.x;
    const int orig = blockIdx.x;
    const int q = nwg >> 3, rr8 = nwg & 7;
    const int xcd = orig & 7, lo = orig >> 3;
    const int wg = (xcd < rr8 ? xcd * (q + 1) : rr8 * (q + 1) + (xcd - rr8) * q) + lo;
    const int NX = N >> 7;
    const int by = wg / NX, bx = wg % NX;
    const int m0 = by * 128, n0 = bx * 128;

    const int lane = t & 63;
    const int wid = t >> 6;
    const int wr = (wid >> 1) * 64, wc = (wid & 1) * 64;
    const int fr = lane & 15, fg = lane >> 4;
    const int lr = lane >> 3;                          // row-in-segment 0..7
    const int swz = ((lane & 7) ^ lr) * 8;             // inverse-swizzled source col (elems)

    f32x4 acc[4][4];
    #pragma unroll
    for (int i = 0; i < 4; ++i)
        #pragma unroll
        for (int j = 0; j < 4; ++j) acc[i][j] = (f32x4){0.f, 0.f, 0.f, 0.f};

    for (int k0 = 0; k0 < K; k0 += 64) {
        #pragma unroll
        for (int i = 0; i < 4; ++i) {
            const int seg = wid * 4 + i;
            const int row = seg * 8 + lr;
            gload16(A16 + (size_t)(m0 + row) * K + k0 + swz, &As[seg * 8][0]);
            gload16(Bt  + (size_t)(n0 + row) * K + k0 + swz, &Bs[seg * 8][0]);
        }
        __syncthreads();
        #pragma unroll
        for (int ks = 0; ks < 2; ++ks) {
            const int bc = (ks * 64 + fg * 16) ^ ((fr & 7) << 4);   // swizzled byte col
            short8v a[4], b[4];
            #pragma unroll
            for (int mi = 0; mi < 4; ++mi) {
                const int row = wr + mi * 16 + fr;
                a[mi] = *(const short8v*)((const char*)&As[0][0] + row * 128 + bc);
            }
            #pragma unroll
            for (int ni = 0; ni < 4; ++ni) {
                const int row = wc + ni * 16 + fr;
                b[ni] = *(const short8v*)((const char*)&Bs[0][0] + row * 128 + bc);
            }
            #pragma unroll
            for (int mi = 0; mi < 4; ++mi)
                #pragma unroll
                for (int ni = 0; ni < 4; ++ni)
                    acc[mi][ni] = __builtin_amdgcn_mfma_f32_16x16x32_bf16(
                            a[mi], b[ni], acc[mi][ni], 0, 0, 0);
        }
        __syncthreads();
    }
    float s = 0.f, bb = 0.f;
    if (EPI == 1 || EPI == 3) { s = sp[0]; bb = bp[0]; }
    #pragma unroll
    for (int mi = 0; mi < 4; ++mi) {
        #pragma unroll
        for (int r = 0; r < 4; ++r) {
            const int row = m0 + wr + mi * 16 + fg * 4 + r;
            #pragma unroll
            for (int ni = 0; ni < 4; ++ni) {
                const int col = n0 + wc + ni * 16 + fr;
                float v = acc[mi][ni][r];
                const size_t off = (size_t)row * N + col;
                if (EPI == 1) {
                    const float rl = fmaxf(v, 0.f);
                    Cf[off] = s * rl * rl + bb;
                } else if (EPI == 2) {
                    Cf[off] = v + R[off];
                } else {
                    const float rl = fmaxf(v, 0.f);
                    Cb[off] = f2b(s * rl * rl + bb);
                }
            }
        }
    }
}

// ================= fused MLP v2: out += fc2(star_relu(fc1(y2))) =================
// 64-row tile, 256 thr / 4 waves. y2 tile held in REGISTERS (loaded once).
// Per hidden chunk (64 wide, 16 chunks): 3 barriers around 64 MFMAs.
// GEMM1: waves split hidden cols (h = wid*16+fr); GEMM2: waves split out cols (wc=wid*64).
__global__ __launch_bounds__(256, 2) void mlp_fused(
        const ushort* __restrict__ y2, const ushort* __restrict__ W1,
        const ushort* __restrict__ W2, float* __restrict__ out,
        const float* __restrict__ sp, const float* __restrict__ bp)
{
    __shared__ ushort W1c[64][256];   // 32 KB, rows = 4x128B sub-chunks, source-swizzled
    __shared__ ushort W2c[256][64];   // 32 KB, rows = 128B, source-swizzled
    __shared__ ushort Ms[64][72];     // 9 KB hidden chunk, padded rows (no swizzle)
    const int t = threadIdx.x;
    const int lane = t & 63, wid = t >> 6;
    const int m0 = blockIdx.x * 64;
    const int fr = lane & 15, fg = lane >> 4;
    const int wc = wid * 64;
    const float s = sp[0], bb = bp[0];

    // ---- y2 tile -> registers: a_y[mi][ks] covers row m0+mi*16+fr, k = ks*32+fg*8 ----
    short8v a_y[4][8];
    #pragma unroll
    for (int mi = 0; mi < 4; ++mi)
        #pragma unroll
        for (int ks = 0; ks < 8; ++ks)
            a_y[mi][ks] = *(const short8v*)(y2 + (size_t)(m0 + mi * 16 + fr) * 256 + ks * 32 + fg * 8);

    f32x4 oacc[4][4];
    #pragma unroll
    for (int mi = 0; mi < 4; ++mi)
        #pragma unroll
        for (int ni = 0; ni < 4; ++ni) oacc[mi][ni] = (f32x4){0.f, 0.f, 0.f, 0.f};

    for (int hk = 0; hk < 16; ++hk) {
        if (hk) __syncthreads();                 // prev GEMM2 done before overwrite
        // ---- stage W1 chunk [64][256] and W2 chunk [256][64] (8 gload rounds each) ----
        #pragma unroll
        for (int r = 0; r < 8; ++r) {
            const int g = r * 4 + wid;
            {   // W1c: gload g covers rows g*2, g*2+1
                const int row = g * 2 + (lane >> 5);
                const int sub = (lane >> 3) & 3;
                const int src = ((lane & 7) ^ (row & 7)) * 8;
                gload16(W1 + (size_t)(hk * 64 + row) * 256 + sub * 64 + src,
                        (ushort*)((char*)&W1c[0][0] + g * 1024));
            }
            {   // W2c: gload g covers rows g*8 .. g*8+7
                const int row = g * 8 + (lane >> 3);
                const int src = ((lane & 7) ^ (row & 7)) * 8;
                gload16(W2 + (size_t)row * 1024 + hk * 64 + src,
                        (ushort*)((char*)&W2c[0][0] + g * 1024));
            }
        }
        __syncthreads();                         // drain vmcnt; W1c/W2c ready
        // ---- GEMM1: acc1[mi] = y2tile(rows) x W1c(h = wid*16+fr), K=256 ----
        f32x4 acc1[4];
        #pragma unroll
        for (int mi = 0; mi < 4; ++mi) acc1[mi] = (f32x4){0.f, 0.f, 0.f, 0.f};
        const int h = wid * 16 + fr;
        #pragma unroll
        for (int ks = 0; ks < 8; ++ks) {
            const int within = (((ks & 1) * 64 + fg * 16) ^ ((h & 7) << 4));
            const short8v b = *(const short8v*)((const char*)&W1c[0][0]
                    + h * 512 + (ks >> 1) * 128 + within);
            #pragma unroll
            for (int mi = 0; mi < 4; ++mi)
                acc1[mi] = __builtin_amdgcn_mfma_f32_16x16x32_bf16(a_y[mi][ks], b, acc1[mi], 0, 0, 0);
        }
        // ---- star_relu -> Ms[row][h] (padded 72) ----
        #pragma unroll
        for (int mi = 0; mi < 4; ++mi)
            #pragma unroll
            for (int rq = 0; rq < 4; ++rq) {
                const int row = mi * 16 + fg * 4 + rq;
                const float rl = fmaxf(acc1[mi][rq], 0.f);
                Ms[row][h] = f2b(s * rl * rl + bb);
            }
        __syncthreads();                         // Ms visible
        // ---- GEMM2: oacc += Ms[64 rows][64 h] x W2c(o = wc+ni*16+fr), K=64 ----
        #pragma unroll
        for (int ks2 = 0; ks2 < 2; ++ks2) {
            short8v a[4], b[4];
            #pragma unroll
            for (int mi = 0; mi < 4; ++mi)
                a[mi] = *(const short8v*)((const char*)&Ms[0][0]
                        + (mi * 16 + fr) * 144 + ks2 * 64 + fg * 16);
            #pragma unroll
            for (int ni = 0; ni < 4; ++ni) {
                const int o = wc + ni * 16 + fr;
                b[ni] = *(const short8v*)((const char*)&W2c[0][0]
                        + o * 128 + ((ks2 * 64 + fg * 16) ^ ((o & 7) << 4)));
            }
            #pragma unroll
            for (int mi = 0; mi < 4; ++mi)
                #pragma unroll
                for (int ni = 0; ni < 4; ++ni)
                    oacc[mi][ni] = __builtin_amdgcn_mfma_f32_16x16x32_bf16(
                            a[mi], b[ni], oacc[mi][ni], 0, 0, 0);
        }
    }
    // ---- epilogue: out += oacc ----
    #pragma unroll
    for (int mi = 0; mi < 4; ++mi)
        #pragma unroll
        for (int rq = 0; rq < 4; ++rq) {
            const int row = m0 + mi * 16 + fg * 4 + rq;
            #pragma unroll
            for (int ni = 0; ni < 4; ++ni) {
                const int col = wc + ni * 16 + fr;
                const size_t off = (size_t)row * 256 + col;
                out[off] = oacc[mi][ni][rq] + out[off];
            }
        }
}

// ================= small-A MFMA GEMM for DFT stages (bf16 in/out) =================
// C[rho][n] = sum_k A[rho][k] * B[k][n]; EPI: 0 write, 1 accumulate into C (bf16 RMW)
template<int EPI>
__global__ __launch_bounds__(256) void gemm_dft(
        const ushort* __restrict__ Ag, int Apitch,
        const ushort* __restrict__ Bv, int BzDiv, long BzA, long BzB, int Brs,
        int Bsplit, long BplOff, int Kreal, int Ksteps,
        ushort* __restrict__ Cv, int CzDiv, long CzA, long CzB, int Crs,
        int Csplit, long CplOff, int Climit, int ntiles, int mtiles)
{
    __shared__ ushort As[128][72];
    __shared__ ushort Bs[128][72];
    const int t = threadIdx.x;
    const int per_z = ntiles * mtiles;
    const int z = blockIdx.x / per_z;
    const int rem = blockIdx.x % per_z;
    const int mt = rem % mtiles;
    const int nt = rem / mtiles;
    const int col0 = nt * 128;
    const long Bzbase = (long)(z / BzDiv) * BzA + (long)(z % BzDiv) * BzB;
    const long Czbase = (long)(z / CzDiv) * CzA + (long)(z % CzDiv) * CzB;
    const int lane = t & 63, wid = t >> 6;
    const int wr = (wid >> 1) * 64, wc = (wid & 1) * 64;
    const int fr = lane & 15, fg = lane >> 4;

    f32x4 acc[4][4];
    #pragma unroll
    for (int i = 0; i < 4; ++i)
        #pragma unroll
        for (int j = 0; j < 4; ++j) acc[i][j] = (f32x4){0.f, 0.f, 0.f, 0.f};

    for (int step = 0; step < Ksteps; ++step) {
        const int k0 = step * 64;
        #pragma unroll
        for (int i = 0; i < 4; ++i) {
            const int id = t + 256 * i;
            const int r = id >> 3, j = (id & 7) * 8;
            *(short8v*)&As[r][j] = *(const short8v*)(Ag + (size_t)(mt * 128 + r) * Apitch + k0 + j);
        }
        // stage B slice transposed into Bs[n][k], kblk XOR-swizzled by (n>>3)&7
        #pragma unroll
        for (int i = 0; i < 2; ++i) {
            const int kp = (t >> 4) + 16 * i;     // k-pair 0..31
            const int np = t & 15;                // n-chunk (8 cols)
            const int kg0 = k0 + 2 * kp;
            ushort u0[8] = {0,0,0,0,0,0,0,0}, u1[8] = {0,0,0,0,0,0,0,0};
            if (kg0 < Kreal) {
                const long roff = Bzbase
                        + (kg0 < Bsplit ? (long)kg0 * Brs : BplOff + (long)(kg0 - Bsplit) * Brs)
                        + col0 + np * 8;
                const short8v tv = *(const short8v*)(Bv + roff);
                #pragma unroll
                for (int jj = 0; jj < 8; ++jj) u0[jj] = (ushort)tv[jj];
            }
            if (kg0 + 1 < Kreal) {
                const int kg1 = kg0 + 1;
                const long roff = Bzbase
                        + (kg1 < Bsplit ? (long)kg1 * Brs : BplOff + (long)(kg1 - Bsplit) * Brs)
                        + col0 + np * 8;
                const short8v tv = *(const short8v*)(Bv + roff);
                #pragma unroll
                for (int jj = 0; jj < 8; ++jj) u1[jj] = (ushort)tv[jj];
            }
            const int blk = (kp >> 2) ^ (np & 7);
            #pragma unroll
            for (int jj = 0; jj < 8; ++jj) {
                const int n = np * 8 + jj;
                ushort2 pr; pr.x = u0[jj]; pr.y = u1[jj];
                *(ushort2*)&Bs[n][blk * 8 + ((2 * kp) & 7)] = pr;
            }
        }
        __syncthreads();
        #pragma unroll
        for (int ks = 0; ks < 2; ++ks) {
            const int koff = ks * 32 + fg * 8;
            short8v a[4], b[4];
            #pragma unroll
            for (int mi = 0; mi < 4; ++mi) a[mi] = *(const short8v*)&As[wr + mi * 16 + fr][koff];
            #pragma unroll
            for (int ni = 0; ni < 4; ++ni) {
                const int n = wc + ni * 16 + fr;
                const int blk = (koff >> 3) ^ ((n >> 3) & 7);
                b[ni] = *(const short8v*)&Bs[n][blk * 8];
            }
            #pragma unroll
            for (int mi = 0; mi < 4; ++mi)
                #pragma unroll
                for (int ni = 0; ni < 4; ++ni)
                    acc[mi][ni] = __builtin_amdgcn_mfma_f32_16x16x32_bf16(
                            a[mi], b[ni], acc[mi][ni], 0, 0, 0);
        }
        __syncthreads();
    }
    #pragma unroll
    for (int mi = 0; mi < 4; ++mi) {
        #pragma unroll
        for (int rq = 0; rq < 4; ++rq) {
            const int rho = mt * 128 + wr + mi * 16 + fg * 4 + rq;
            if (rho >= Climit) continue;
            const long rbase = Czbase
                    + (rho < Csplit ? (long)rho * Crs : CplOff + (long)(rho - Csplit) * Crs);
            #pragma unroll
            for (int ni = 0; ni < 4; ++ni) {
                const long caddr = rbase + col0 + wc + ni * 16 + fr;
                float v = acc[mi][ni][rq];
                if (EPI == 1) v += b2f(Cv[caddr]);
                Cv[caddr] = f2b(v);
            }
        }
    }
}

// ================= block-diagonal complex MLP via MFMA (gload_lds staged) =================
template<int SECOND>
__global__ __launch_bounds__(256) void gemm_bmm(
        ushort* __restrict__ F2, ushort* __restrict__ G1,
        const ushort* __restrict__ Wc, const float* __restrict__ bias,
        const float* __restrict__ s0p, const float* __restrict__ b0p,
        const float* __restrict__ s1p, const float* __restrict__ b1p)
{
    const int MT = 40;
    const int wg = blockIdx.x;
    const int mt = wg % MT;
    const int n  = (wg / MT) & 7;
    const int bl = wg / (MT * 8);
    const long FB = (long)bl * PERB2;
    const long GB = ((long)(bl * 8 + n)) * 5100 * 128;
    const int r0 = mt * 128;
    __shared__ ushort As[128][64];
    __shared__ ushort Ws[128][64];
    const int t = threadIdx.x;
    const int lane = t & 63, wid = t >> 6;
    const int wr = (wid >> 1) * 64, wc = (wid & 1) * 64;
    const int fr = lane & 15, fg = lane >> 4;
    const int lr = lane >> 3;
    const int swz = ((lane & 7) ^ lr) * 8;

    f32x4 acc[4][4];
    #pragma unroll
    for (int i = 0; i < 4; ++i)
        #pragma unroll
        for (int j = 0; j < 4; ++j) acc[i][j] = (f32x4){0.f, 0.f, 0.f, 0.f};

    for (int step = 0; step < 2; ++step) {
        // rows beyond 5100 load garbage (within allocated ws); epilogue guards writes
        #pragma unroll
        for (int i = 0; i < 4; ++i) {
            const int seg = wid * 4 + i;
            const int row = seg * 8 + lr;
            const long r = r0 + row;
            const ushort* srcA = SECOND
                ? (G1 + GB + r * 128 + step * 64 + swz)
                : (F2 + FB + (step ? PL : 0) + r * 512 + n * 64 + swz);
            gload16(srcA, &As[seg * 8][0]);
            gload16(Wc + ((long)n << 14) + (long)row * 128 + step * 64 + swz, &Ws[seg * 8][0]);
        }
        __syncthreads();
        #pragma unroll
        for (int ks = 0; ks < 2; ++ks) {
            const int bc = (ks * 64 + fg * 16) ^ ((fr & 7) << 4);
            short8v a[4], b[4];
            #pragma unroll
            for (int mi = 0; mi < 4; ++mi) {
                const int row = wr + mi * 16 + fr;
                a[mi] = *(const short8v*)((const char*)&As[0][0] + row * 128 + bc);
            }
            #pragma unroll
            for (int ni = 0; ni < 4; ++ni) {
                const int row = wc + ni * 16 + fr;
                b[ni] = *(const short8v*)((const char*)&Ws[0][0] + row * 128 + bc);
            }
            #pragma unroll
            for (int mi = 0; mi < 4; ++mi)
                #pragma unroll
                for (int ni = 0; ni < 4; ++ni)
                    acc[mi][ni] = __builtin_amdgcn_mfma_f32_16x16x32_bf16(
                            a[mi], b[ni], acc[mi][ni], 0, 0, 0);
        }
        __syncthreads();
    }
    #pragma unroll
    for (int mi = 0; mi < 4; ++mi) {
        #pragma unroll
        for (int rq = 0; rq < 4; ++rq) {
            const int r = r0 + wr + mi * 16 + fg * 4 + rq;
            if (r >= 5100) continue;
            #pragma unroll
            for (int ni = 0; ni < 4; ++ni) {
                const int j = wc + ni * 16 + fr;
                float u = acc[mi][ni][rq] + bias[(j < 64 ? 0 : 512) + n * 64 + (j & 63)];
                if (!SECOND) {
                    const float s  = (j < 64) ? s0p[0] : s1p[0];
                    const float bb = (j < 64) ? b0p[0] : b1p[0];
                    const float rl = fmaxf(u, 0.f);
                    G1[GB + (long)r * 128 + j] = f2b(s * rl * rl + bb);
                } else {
                    const long ma = FB + (j < 64 ? 0 : PL) + (long)r * 512 + n * 64 + (j & 63);
                    F2[ma] = f2b(u * b2f(F2[ma]));
                }
            }
        }
    }
}

// ================= launcher =================
extern "C" void kernel_launch(void* const* d_in, const int* in_sizes, int n_in,
                              void* d_out, int out_size, void* d_ws, size_t ws_size,
                              hipStream_t stream) {
    (void)in_sizes; (void)n_in; (void)out_size;
    const float* x        = (const float*)d_in[0];
    const float* ln1_g    = (const float*)d_in[1];
    const float* ln1_b    = (const float*)d_in[2];
    const float* pw1_w    = (const float*)d_in[3];
    const float* act1_s   = (const float*)d_in[4];
    const float* act1_b   = (const float*)d_in[5];
    const float* w1       = (const float*)d_in[6];
    const float* w11      = (const float*)d_in[7];
    const float* b1       = (const float*)d_in[8];
    const float* w2       = (const float*)d_in[9];
    const float* w22      = (const float*)d_in[10];
    const float* b2       = (const float*)d_in[11];
    const float* actr_s   = (const float*)d_in[12];
    const float* actr_b   = (const float*)d_in[13];
    const float* acti_s   = (const float*)d_in[14];
    const float* acti_b   = (const float*)d_in[15];
    const float* pw2_w    = (const float*)d_in[16];
    const float* ln2_g    = (const float*)d_in[17];
    const float* ln2_b    = (const float*)d_in[18];
    const float* fc1_w    = (const float*)d_in[19];
    const float* mlp_s    = (const float*)d_in[20];
    const float* mlp_b    = (const float*)d_in[21];
    const float* fc2_w    = (const float*)d_in[22];
    float* out = (float*)d_out;
    float* ws  = (float*)d_ws;

    const size_t HBUF_F = 40960000ull;          // h16 region (bf16 uses half)
    const size_t MATS_F = 610000ull;
    const size_t ws_floats = ws_size / 4;
    int CB = 4;                                 // keep temps (CB*PERB2*2B) L3-resident
    while (CB > 1 && HBUF_F + (size_t)CB * (size_t)PERB2 + MATS_F > ws_floats) CB >>= 1;

    float* hbuf = ws;
    ushort* h16 = (ushort*)hbuf;                 // [80000][512] bf16
    ushort* tA16 = (ushort*)(ws + HBUF_F);       // CB*PERB2 ushorts
    ushort* tB16 = tA16 + (size_t)CB * PERB2;
    ushort* mats = tB16 + (size_t)CB * PERB2;
    ushort* A1m  = mats;
    ushort* A2m  = A1m + 16384;
    ushort* A4m  = A2m + 65536;
    ushort* A5m  = A4m + 65536;
    ushort* Wc1  = A5m + 16384;
    ushort* Wc2  = Wc1 + 131072;
    ushort* wt1  = Wc2 + 131072;
    ushort* wt2  = wt1 + 131072;
    ushort* wtf1 = wt2 + 131072;
    ushort* wtf2 = wtf1 + 262144;

    ushort* y16 = (ushort*)out;                          // LN1 out (scratch until pw2)
    ushort* y2  = (ushort*)hbuf;                         // LN2 out (h16 dead after pw2)

    build_A1<<<64, 256, 0, stream>>>(A1m);
    build_A2<0><<<256, 256, 0, stream>>>(A2m);
    build_A2<1><<<256, 256, 0, stream>>>(A4m);
    build_A5<<<64, 256, 0, stream>>>(A5m);
    build_wc<<<512, 256, 0, stream>>>(w1, w11, Wc1);
    build_wc<<<512, 256, 0, stream>>>(w2, w22, Wc2);
    wtrans<<<(131072 + 255) / 256, 256, 0, stream>>>(pw1_w, wt1, DIM, MED);
    wtrans<<<(131072 + 255) / 256, 256, 0, stream>>>(pw2_w, wt2, MED, DIM);
    wtrans<<<(262144 + 255) / 256, 256, 0, stream>>>(fc1_w, wtf1, DIM, 1024);
    wtrans<<<(262144 + 255) / 256, 256, 0, stream>>>(fc2_w, wtf2, 1024, DIM);

    // ---- token mixer ----
    ln_fast<<<NPOS / 4, 256, 0, stream>>>(x, ln1_g, ln1_b, y16);
    gemm_mfma<3><<<(NPOS / 128) * (MED / 128), 256, 0, stream>>>(
            y16, wt1, nullptr, h16, nullptr, act1_s, act1_b, NPOS, MED, DIM);

    for (int b0 = 0; b0 < 8; b0 += CB) {
        ushort* hchunk = h16 + (size_t)b0 * (SZ * SZ * MED);
        // K1: rfft along W -> tA
        gemm_dft<0><<<CB * 100 * 4, 256, 0, stream>>>(
                A1m, 128, hchunk, 1, 51200, 0, 512, 100, 0, 100, 2,
                tA16, 100, PERB2, HROW, 512, 51, PL, 102, 4, 1);
        // K2: forward DFT along H: tA -> tB
        gemm_dft<0><<<CB * 408, 256, 0, stream>>>(
                A2m, 256, tA16, 1, PERB2, 0, HROW, 100, PL, 200, 4,
                tB16, 1, PERB2, 0, HROW, 100, PL, 200, 204, 2);
        // bmm layer 1: F2 -> G1 (=tA)
        gemm_bmm<0><<<CB * 320, 256, 0, stream>>>(
                tB16, tA16, Wc1, b1, actr_s, actr_b, acti_s, acti_b);
        // bmm layer 2: G1, x F2 -> F2 in place
        gemm_bmm<1><<<CB * 320, 256, 0, stream>>>(
                tB16, tA16, Wc2, b2, nullptr, nullptr, nullptr, nullptr);
        // K4: inverse DFT along H: tB -> tA
        gemm_dft<0><<<CB * 408, 256, 0, stream>>>(
                A4m, 256, tB16, 1, PERB2, 0, HROW, 100, PL, 200, 4,
                tA16, 1, PERB2, 0, HROW, 100, PL, 200, 204, 2);
        // K5: irfft along W + skip accumulate into bf16 h
        gemm_dft<1><<<CB * 100 * 4, 256, 0, stream>>>(
                A5m, 128, tA16, 100, PERB2, HROW, 512, 51, PL, 102, 2,
                hchunk, 1, 51200, 0, 512, 100, 0, 100, 4, 1);
    }

    gemm_mfma<2><<<(NPOS / 128) * (DIM / 128), 256, 0, stream>>>(
            h16, wt2, out, nullptr, x, nullptr, nullptr, NPOS, DIM, MED);

    // ---- MLP branch: LN2 + fused MLP v2 (y2-in-registers, 3 barriers/chunk) ----
    ln_fast<<<NPOS / 4, 256, 0, stream>>>(out, ln2_g, ln2_b, y2);
    mlp_fused<<<NPOS / 64, 256, 0, stream>>>(y2, wtf1, wtf2, out, mlp_s, mlp_b);
}